// Round 13
// baseline (131.551 us; speedup 1.0000x reference)
//
#include <hip/hip_runtime.h>
#include <hip/hip_bf16.h>
#include <math.h>

#define BB 4
#define CC 64
#define NN 4096
#define HD 64
#define HID 256
#define EPSV 1e-5f
#define CNT (CC*NN)
#define NCH 8            // KV split chunks

typedef float f32x4 __attribute__((ext_vector_type(4)));
typedef short bf16x8 __attribute__((ext_vector_type(8)));
typedef short bf16x4 __attribute__((ext_vector_type(4)));
#define MFMA16(a, b, c) __builtin_amdgcn_mfma_f32_16x16x32_bf16(a, b, c, 0, 0, 0)

__device__ __forceinline__ float gelu_exact(float x) {
    return 0.5f * x * (1.0f + erff(x * 0.70710678118654752f));
}
__device__ __forceinline__ ushort f2bf(float f) {
    unsigned u = __float_as_uint(f);
    unsigned r = (u + 0x7FFFu + ((u >> 16) & 1u)) >> 16;
    return (ushort)r;
}
__device__ __forceinline__ float bf2f(ushort u) {
    return __uint_as_float(((unsigned)u) << 16);
}
__device__ __forceinline__ unsigned cvtpk(float lo, float hi) {
    unsigned r;
    asm("v_cvt_pk_bf16_f32 %0, %1, %2" : "=v"(r) : "v"(lo), "v"(hi));
    return r;
}
__device__ __forceinline__ void unpack2(unsigned u, float& lo, float& hi) {
    lo = __uint_as_float(u << 16);
    hi = __uint_as_float(u & 0xffff0000u);
}

// ---------------- weight prep: fp32 -> bf16 (fc1, fc2, qw, kvw) ----------------
__global__ __launch_bounds__(256) void wprep_kernel(const float* __restrict__ fc1w,
                                                    const float* __restrict__ fc2w,
                                                    const float* __restrict__ qw,
                                                    const float* __restrict__ kvw,
                                                    ushort* __restrict__ fc1wb,
                                                    ushort* __restrict__ fc2wb,
                                                    ushort* __restrict__ qwb,
                                                    ushort* __restrict__ kvwb) {
    int i = blockIdx.x * 256 + threadIdx.x;   // 45056
    if (i < 16384) fc1wb[i] = f2bf(fc1w[i]);
    else if (i < 32768) fc2wb[i - 16384] = f2bf(fc2w[i - 16384]);
    else if (i < 36864) qwb[i - 32768] = f2bf(qw[i - 32768]);
    else if (i < 45056) kvwb[i - 36864] = f2bf(kvw[i - 36864]);
}

// ---------------- fused stats stage 1 for x and cnn ----------------
__global__ __launch_bounds__(256) void stats_pair_kernel(const float* __restrict__ x,
                                                         const float* __restrict__ cnn,
                                                         float* __restrict__ part) {
    int b = blockIdx.y;
    int blk = blockIdx.x;
    const float4* p0 = (const float4*)(x + (size_t)b * CNT);
    const float4* p1 = (const float4*)(cnn + (size_t)b * CNT);
    float s0 = 0.f, s20 = 0.f, s1 = 0.f, s21 = 0.f;
    #pragma unroll
    for (int k = 0; k < 4; ++k) {
        float4 v = p0[blk * 1024 + k * 256 + threadIdx.x];
        s0  += v.x + v.y + v.z + v.w;
        s20 += v.x * v.x + v.y * v.y + v.z * v.z + v.w * v.w;
        float4 u = p1[blk * 1024 + k * 256 + threadIdx.x];
        s1  += u.x + u.y + u.z + u.w;
        s21 += u.x * u.x + u.y * u.y + u.z * u.z + u.w * u.w;
    }
    #pragma unroll
    for (int off = 32; off > 0; off >>= 1) {
        s0  += __shfl_xor(s0, off);
        s20 += __shfl_xor(s20, off);
        s1  += __shfl_xor(s1, off);
        s21 += __shfl_xor(s21, off);
    }
    __shared__ float sh[4][4];
    int wid = threadIdx.x >> 6, lane = threadIdx.x & 63;
    if (lane == 0) { sh[wid][0] = s0; sh[wid][1] = s20; sh[wid][2] = s1; sh[wid][3] = s21; }
    __syncthreads();
    if (threadIdx.x == 0) {
        float a0 = sh[0][0] + sh[1][0] + sh[2][0] + sh[3][0];
        float a1 = sh[0][1] + sh[1][1] + sh[2][1] + sh[3][1];
        float a2 = sh[0][2] + sh[1][2] + sh[2][2] + sh[3][2];
        float a3 = sh[0][3] + sh[1][3] + sh[2][3] + sh[3][3];
        part[((0 * 4 + b) * 64 + blk) * 2]     = a0;
        part[((0 * 4 + b) * 64 + blk) * 2 + 1] = a1;
        part[((1 * 4 + b) * 64 + blk) * 2]     = a2;
        part[((1 * 4 + b) * 64 + blk) * 2 + 1] = a3;
    }
}

// ---------------- stats finalize (both slots) ----------------
__global__ __launch_bounds__(64) void stats_fin_kernel(const float* __restrict__ part,
                                                       float* __restrict__ stats) {
    int sb_ = blockIdx.x;    // slot*4 + b
    int lane = threadIdx.x;
    float s = part[(sb_ * 64 + lane) * 2];
    float s2 = part[(sb_ * 64 + lane) * 2 + 1];
    #pragma unroll
    for (int off = 32; off > 0; off >>= 1) {
        s  += __shfl_xor(s, off);
        s2 += __shfl_xor(s2, off);
    }
    if (lane == 0) {
        int slot = sb_ >> 2, b = sb_ & 3;
        float mu = s / (float)CNT;
        float var = s2 / (float)CNT - mu * mu;
        stats[slot * 8 + b] = mu;
        stats[slot * 8 + 4 + b] = rsqrtf(var + EPSV);
    }
}

// ---------------- stats stage 2b (256 partials, slot 2) ----------------
__global__ __launch_bounds__(256) void stats2b_kernel(const float* __restrict__ part2,
                                                      float* __restrict__ stats, int slot) {
    int b = blockIdx.x;
    int t = threadIdx.x;
    float s = part2[(b * 256 + t) * 2];
    float s2 = part2[(b * 256 + t) * 2 + 1];
    #pragma unroll
    for (int off = 32; off > 0; off >>= 1) {
        s  += __shfl_xor(s, off);
        s2 += __shfl_xor(s2, off);
    }
    __shared__ float shs[4], shs2[4];
    int wid = t >> 6, lane = t & 63;
    if (lane == 0) { shs[wid] = s; shs2[wid] = s2; }
    __syncthreads();
    if (t == 0) {
        float S = shs[0] + shs[1] + shs[2] + shs[3];
        float S2 = shs2[0] + shs2[1] + shs2[2] + shs2[3];
        float mu = S / (float)CNT;
        float var = S2 / (float)CNT - mu * mu;
        stats[slot * 8 + b] = mu;
        stats[slot * 8 + 4 + b] = rsqrtf(var + EPSV);
    }
}

// ---------------- qkv_fused: gn(cnn)+dw3+res (LDS) -> KV MFMA; gn(x) -> Q MFMA ----------------
// grid dim3(64, B): y = image row; tokens y*64 .. y*64+63
__global__ __launch_bounds__(256) void qkv_fused(const float* __restrict__ x,
                                                 const float* __restrict__ n1g,
                                                 const float* __restrict__ n1b,
                                                 const ushort* __restrict__ qwb,
                                                 const float* __restrict__ qb,
                                                 const float* __restrict__ cnn,
                                                 const float* __restrict__ n3g,
                                                 const float* __restrict__ n3b,
                                                 const float* __restrict__ lcw,
                                                 const float* __restrict__ lcb,
                                                 const ushort* __restrict__ kvwb,
                                                 const float* __restrict__ kvb,
                                                 const float* __restrict__ stats,
                                                 ushort* __restrict__ qr,
                                                 ushort* __restrict__ kr,
                                                 ushort* __restrict__ vt) {
    int y = blockIdx.x;
    int b = blockIdx.y;
    int tid = threadIdx.x;
    int tok0 = y * 64;
    __shared__ float cs[3][64][66];    // gn'd cnn rows y-1..y+1, x-padded (50.7 KB)
    __shared__ ushort Xt[64][64];      // kv_in bf16, swizzled (8 KB)
    float* csf = &cs[0][0][0];
    for (int i = tid; i < 3 * 64 * 66; i += 256) csf[i] = 0.f;
    __syncthreads();
    {
        float mu = stats[1 * 8 + b];
        float rs = stats[1 * 8 + 4 + b];
        for (int e = tid; e < 12288; e += 256) {
            int ry = e >> 12;
            int c = (e >> 6) & 63;
            int xx = e & 63;
            int yy = y + ry - 1;
            if (yy >= 0 && yy < 64)
                cs[ry][c][xx + 1] =
                    (cnn[((size_t)(b * 64 + c)) * NN + yy * 64 + xx] - mu) * rs * n3g[c] + n3b[c];
        }
    }
    __syncthreads();
    // dw3 + bias + residual -> Xt (bf16, swizzled); thread: c = tid>>2, 16 px
    {
        int c = tid >> 2;
        int x0 = (tid & 3) * 16;
        float w9[9];
        #pragma unroll
        for (int i = 0; i < 9; ++i) w9[i] = lcw[c * 9 + i];
        float b0 = lcb[c];
        #pragma unroll
        for (int px = 0; px < 16; ++px) {
            int xg = x0 + px;
            float acc = b0;
            #pragma unroll
            for (int dy = 0; dy < 3; ++dy) {
                const float* row = cs[dy][c];
                acc += w9[dy * 3]     * row[xg];
                acc += w9[dy * 3 + 1] * row[xg + 1];
                acc += w9[dy * 3 + 2] * row[xg + 2];
            }
            acc += cs[1][c][xg + 1];
            Xt[xg][((c >> 3) ^ (xg & 7)) * 8 + (c & 7)] = f2bf(acc);
        }
    }
    __syncthreads();

    int w = tid >> 6;
    int lr = tid & 15;
    int lg = (tid & 63) >> 4;
    int brow = w * 16 + lr;
    // ---- KV MFMA ----
    {
        bf16x8 bf0 = *(const bf16x8*)&Xt[brow][((0 + lg) ^ (lr & 7)) * 8];
        bf16x8 bf1 = *(const bf16x8*)&Xt[brow][((4 + lg) ^ (lr & 7)) * 8];
        f32x4 acc[8];
        #pragma unroll
        for (int mt = 0; mt < 8; ++mt) acc[mt] = (f32x4){0.f, 0.f, 0.f, 0.f};
        #pragma unroll
        for (int mt = 0; mt < 8; ++mt) {
            bf16x8 a0 = *(const bf16x8*)&kvwb[(mt * 16 + lr) * 64 + lg * 8];
            bf16x8 a1 = *(const bf16x8*)&kvwb[(mt * 16 + lr) * 64 + 32 + lg * 8];
            acc[mt] = MFMA16(a0, bf0, acc[mt]);
            acc[mt] = MFMA16(a1, bf1, acc[mt]);
        }
        int tl = w * 16 + lr;
        int tok = tok0 + tl;
        int hh = tok >> 6, ww2 = tok & 63;
        int permk = (lr >> 2) * 16 + w * 4 + (lr & 3);
        ushort* krow = kr + ((size_t)b * NN + tok) * 64;
        #pragma unroll
        for (int mt = 0; mt < 4; ++mt) {      // K half, with RoPE
            #pragma unroll
            for (int pr = 0; pr < 2; ++pr) {
                int o = mt * 16 + lg * 4 + pr * 2;
                float a0 = acc[mt][pr * 2]     + kvb[o];
                float a1 = acc[mt][pr * 2 + 1] + kvb[o + 1];
                int j = (o & 31) >> 1;
                float freq = exp2f(-0.88584749f * (float)j);
                float pos = (o < 32) ? (float)hh : (float)ww2;
                float st, ct;
                __sincosf(pos * freq, &st, &ct);
                krow[o]     = f2bf(a0 * ct - a1 * st);
                krow[o + 1] = f2bf(a1 * ct + a0 * st);
            }
        }
        #pragma unroll
        for (int mt = 4; mt < 8; ++mt) {      // V half, key-permuted transpose store
            #pragma unroll
            for (int r = 0; r < 4; ++r) {
                int o = mt * 16 + lg * 4 + r;
                float a0 = acc[mt][r] + kvb[o];
                vt[((size_t)b * 64 + (o - 64)) * NN + tok0 + permk] = f2bf(a0);
            }
        }
    }
    // ---- Q staging into recycled halo space ----
    ushort* Xq = (ushort*)csf;
    {
        float mu = stats[0 * 8 + b];
        float rs = stats[0 * 8 + 4 + b];
        for (int e = tid; e < 4096; e += 256) {
            int c = e >> 6, t = e & 63;
            float v = (x[((size_t)(b * 64 + c)) * NN + tok0 + t] - mu) * rs * n1g[c] + n1b[c];
            Xq[t * 64 + ((c >> 3) ^ (t & 7)) * 8 + (c & 7)] = f2bf(v);
        }
    }
    __syncthreads();
    // ---- Q MFMA ----
    {
        bf16x8 bf0 = *(const bf16x8*)&Xq[brow * 64 + ((0 + lg) ^ (lr & 7)) * 8];
        bf16x8 bf1 = *(const bf16x8*)&Xq[brow * 64 + ((4 + lg) ^ (lr & 7)) * 8];
        f32x4 acc[4];
        #pragma unroll
        for (int mt = 0; mt < 4; ++mt) acc[mt] = (f32x4){0.f, 0.f, 0.f, 0.f};
        #pragma unroll
        for (int mt = 0; mt < 4; ++mt) {
            bf16x8 a0 = *(const bf16x8*)&qwb[(mt * 16 + lr) * 64 + lg * 8];
            bf16x8 a1 = *(const bf16x8*)&qwb[(mt * 16 + lr) * 64 + 32 + lg * 8];
            acc[mt] = MFMA16(a0, bf0, acc[mt]);
            acc[mt] = MFMA16(a1, bf1, acc[mt]);
        }
        int tok = tok0 + w * 16 + lr;
        int hh = tok >> 6, ww2 = tok & 63;
        ushort* qrow = qr + ((size_t)b * NN + tok) * 64;
        #pragma unroll
        for (int mt = 0; mt < 4; ++mt) {
            #pragma unroll
            for (int pr = 0; pr < 2; ++pr) {
                int o = mt * 16 + lg * 4 + pr * 2;
                float a0 = acc[mt][pr * 2]     + qb[o];
                float a1 = acc[mt][pr * 2 + 1] + qb[o + 1];
                int j = (o & 31) >> 1;
                float freq = exp2f(-0.88584749f * (float)j);
                float pos = (o < 32) ? (float)hh : (float)ww2;
                float st, ct;
                __sincosf(pos * freq, &st, &ct);
                qrow[o]     = f2bf(a0 * ct - a1 * st);
                qrow[o + 1] = f2bf(a1 * ct + a0 * st);
            }
        }
    }
}

// ---------------- MFMA flash attention v4: swapped QK^T, in-reg P, b128 PV ----------------
// grid dim3(64, B, NCH), 256 thr = 4 waves x 16 q-rows; KV tile 64; chunk = 512 keys
__global__ __launch_bounds__(256) void attn_kernel(const ushort* __restrict__ qr,
                                                   const ushort* __restrict__ kr,
                                                   const ushort* __restrict__ vt,
                                                   ushort* __restrict__ Opart,
                                                   float* __restrict__ ml) {
    int b = blockIdx.y;
    int q0 = blockIdx.x * 64;
    int chunk = blockIdx.z;
    int tid = threadIdx.x;
    int w = tid >> 6;
    int lane = tid & 63;
    int lr = lane & 15;
    int lg = lane >> 4;
    const float SCL2 = 0.125f * 1.44269504f;   // HD^-0.5 * log2(e)

    __shared__ ushort Kl[64 * 64];
    __shared__ ushort Vl[64 * 64];

    bf16x8 qf[2];
    {
        const ushort* qp = qr + ((size_t)b * NN + q0 + w * 16 + lr) * 64;
        qf[0] = *(const bf16x8*)(qp + lg * 8);
        qf[1] = *(const bf16x8*)(qp + 32 + lg * 8);
    }

    f32x4 oacc[4];
    #pragma unroll
    for (int t = 0; t < 4; ++t) oacc[t] = (f32x4){0.f, 0.f, 0.f, 0.f};
    float m_ = -INFINITY, l_ = 0.f;     // scalar state for q-row = q0+w*16+lr

    const size_t kbase = ((size_t)b * NN) * 64;
    const int t0 = chunk * 8, tend = t0 + 8;

    for (int t = t0; t < tend; ++t) {
        int k0 = t * 64;
        __syncthreads();
        #pragma unroll
        for (int it = 0; it < 2; ++it) {
            int e = tid + it * 256;
            int row = e >> 3, cib = e & 7;
            int sw = cib ^ (row & 7);
            *(bf16x8*)(Kl + row * 64 + sw * 8) =
                *(const bf16x8*)(kr + kbase + (size_t)(k0 + row) * 64 + cib * 8);
            *(bf16x8*)(Vl + row * 64 + sw * 8) =
                *(const bf16x8*)(vt + ((size_t)b * 64 + row) * NN + k0 + cib * 8);
        }
        __syncthreads();

        // S^T = K Q : lane holds q=lr, keys kt*16 + lg*4 + r
        f32x4 sacc[4];
        #pragma unroll
        for (int kt = 0; kt < 4; ++kt) {
            int row = kt * 16 + lr;
            bf16x8 k0f = *(const bf16x8*)(Kl + row * 64 + ((0 * 4 + lg) ^ (lr & 7)) * 8);
            bf16x8 k1f = *(const bf16x8*)(Kl + row * 64 + ((1 * 4 + lg) ^ (lr & 7)) * 8);
            f32x4 z = {0.f, 0.f, 0.f, 0.f};
            z = MFMA16(k0f, qf[0], z);
            sacc[kt] = MFMA16(k1f, qf[1], z);
        }

        float vmax = fmaxf(fmaxf(fmaxf(sacc[0][0], sacc[0][1]), fmaxf(sacc[0][2], sacc[0][3])),
                           fmaxf(fmaxf(sacc[1][0], sacc[1][1]), fmaxf(sacc[1][2], sacc[1][3])));
        vmax = fmaxf(vmax, fmaxf(fmaxf(fmaxf(sacc[2][0], sacc[2][1]), fmaxf(sacc[2][2], sacc[2][3])),
                                 fmaxf(fmaxf(sacc[3][0], sacc[3][1]), fmaxf(sacc[3][2], sacc[3][3]))));
        vmax = fmaxf(vmax, __shfl_xor(vmax, 16));
        vmax = fmaxf(vmax, __shfl_xor(vmax, 32));
        float mx = vmax * SCL2;
        if (__any(mx - m_ > 8.f)) {          // defer-max
            float mn = fmaxf(m_, mx);
            float cr = exp2f(m_ - mn);
            l_ *= cr;
            m_ = mn;
            float crq[4];
            #pragma unroll
            for (int r = 0; r < 4; ++r) crq[r] = __shfl(cr, lg * 4 + r);
            #pragma unroll
            for (int ht = 0; ht < 4; ++ht)
                #pragma unroll
                for (int r = 0; r < 4; ++r) oacc[ht][r] *= crq[r];
        }

        unsigned u[8];
        float lsum = 0.f;
        #pragma unroll
        for (int kt = 0; kt < 4; ++kt) {
            float p0 = exp2f(sacc[kt][0] * SCL2 - m_);
            float p1 = exp2f(sacc[kt][1] * SCL2 - m_);
            float p2 = exp2f(sacc[kt][2] * SCL2 - m_);
            float p3 = exp2f(sacc[kt][3] * SCL2 - m_);
            lsum += (p0 + p1) + (p2 + p3);
            u[kt * 2]     = cvtpk(p0, p1);
            u[kt * 2 + 1] = cvtpk(p2, p3);
        }
        lsum += __shfl_xor(lsum, 16);
        lsum += __shfl_xor(lsum, 32);
        l_ += lsum;

        uint4 t0v = {u[0], u[1], u[2], u[3]};   // keys {lg*4+r, 16+lg*4+r}
        uint4 t1v = {u[4], u[5], u[6], u[7]};   // keys {32+lg*4+r, 48+lg*4+r}
        bf16x8 pa0 = __builtin_bit_cast(bf16x8, t0v);
        bf16x8 pa1 = __builtin_bit_cast(bf16x8, t1v);
        // PV: V stored key-permuted so lane's keys are contiguous chunks lg*2, lg*2+1
        #pragma unroll
        for (int ht = 0; ht < 4; ++ht) {
            int row = ht * 16 + lr;
            bf16x8 vf0 = *(const bf16x8*)(Vl + row * 64 + ((lg * 2) ^ (row & 7)) * 8);
            bf16x8 vf1 = *(const bf16x8*)(Vl + row * 64 + ((lg * 2 + 1) ^ (row & 7)) * 8);
            oacc[ht] = MFMA16(pa0, vf0, oacc[ht]);
            oacc[ht] = MFMA16(pa1, vf1, oacc[ht]);
        }
    }

    int n0 = q0 + w * 16 + lg * 4;
    #pragma unroll
    for (int ht = 0; ht < 4; ++ht) {
        int hd = ht * 16 + lr;
        ushort4 o4;
        o4.x = f2bf(oacc[ht][0]);
        o4.y = f2bf(oacc[ht][1]);
        o4.z = f2bf(oacc[ht][2]);
        o4.w = f2bf(oacc[ht][3]);
        *(ushort4*)&Opart[(((size_t)chunk * BB + b) * 64 + hd) * NN + n0] = o4;
    }
    if (lg == 0) {
        int n = q0 + w * 16 + lr;
        ml[((size_t)b * NN + n) * 16 + chunk * 2]     = m_;
        ml[((size_t)b * NN + n) * 16 + chunk * 2 + 1] = l_;
    }
}

// ---------------- combine: x2 = sum_c O_c*w_c + x; fused stats partials ----------------
__global__ __launch_bounds__(256) void combine_kernel(const ushort* __restrict__ Opart,
                                                      const float* __restrict__ ml,
                                                      const float* __restrict__ x,
                                                      float* __restrict__ x2,
                                                      float* __restrict__ part2) {
    int i = blockIdx.x * 256 + threadIdx.x;   // 262144
    int n4 = i & 1023;
    int hd = (i >> 10) & 63;
    int b = i >> 16;
    int n0 = n4 << 2;
    float wgt[4][NCH];
    const float* mlp = ml + ((size_t)b * NN + n0) * 16;
    #pragma unroll
    for (int tk = 0; tk < 4; ++tk) {
        float m[NCH], l[NCH];
        const float4* p4 = (const float4*)(mlp + tk * 16);
        #pragma unroll
        for (int q = 0; q < 4; ++q) {
            float4 v = p4[q];
            m[q * 2] = v.x; l[q * 2] = v.y; m[q * 2 + 1] = v.z; l[q * 2 + 1] = v.w;
        }
        float M = m[0];
        #pragma unroll
        for (int c = 1; c < NCH; ++c) M = fmaxf(M, m[c]);
        float e[NCH], L = 0.f;
        #pragma unroll
        for (int c = 0; c < NCH; ++c) { e[c] = exp2f(m[c] - M); L += l[c] * e[c]; }
        float inv = 1.f / L;
        #pragma unroll
        for (int c = 0; c < NCH; ++c) wgt[tk][c] = e[c] * inv;
    }
    float4 acc = {0.f, 0.f, 0.f, 0.f};
    #pragma unroll
    for (int c = 0; c < NCH; ++c) {
        ushort4 o4 = *(const ushort4*)&Opart[(((size_t)c * BB + b) * 64 + hd) * NN + n0];
        acc.x += bf2f(o4.x) * wgt[0][c];
        acc.y += bf2f(o4.y) * wgt[1][c];
        acc.z += bf2f(o4.z) * wgt[2][c];
        acc.w += bf2f(o4.w) * wgt[3][c];
    }
    size_t off = ((size_t)b * 64 + hd) * NN + n0;
    float4 xv = *(const float4*)&x[off];
    acc.x += xv.x; acc.y += xv.y; acc.z += xv.z; acc.w += xv.w;
    *(float4*)&x2[off] = acc;

    float s = acc.x + acc.y + acc.z + acc.w;
    float s2 = acc.x * acc.x + acc.y * acc.y + acc.z * acc.z + acc.w * acc.w;
    #pragma unroll
    for (int off2 = 32; off2 > 0; off2 >>= 1) {
        s  += __shfl_xor(s, off2);
        s2 += __shfl_xor(s2, off2);
    }
    __shared__ float shs[4], shs2[4];
    int wid = threadIdx.x >> 6, lane = threadIdx.x & 63;
    if (lane == 0) { shs[wid] = s; shs2[wid] = s2; }
    __syncthreads();
    if (threadIdx.x == 0) {
        part2[blockIdx.x * 2]     = shs[0] + shs[1] + shs[2] + shs[3];
        part2[blockIdx.x * 2 + 1] = shs2[0] + shs2[1] + shs2[2] + shs2[3];
    }
}

// ---------------- fc1 MFMA: h1 = gelu(bn1(fc1w @ gn2(x2))) -> bf16 ----------------
__global__ __launch_bounds__(256) void fc1_mfma(const float* __restrict__ x2,
                                                const ushort* __restrict__ fc1wb,
                                                const float* __restrict__ n2g,
                                                const float* __restrict__ n2b,
                                                const float* __restrict__ bn1g,
                                                const float* __restrict__ bn1b,
                                                const float* __restrict__ stats,
                                                ushort* __restrict__ h1) {
    int b = blockIdx.y;
    int tok0 = (blockIdx.x >> 1) * 64;
    int half = blockIdx.x & 1;
    int tid = threadIdx.x;
    int w = tid >> 6;
    int lr = tid & 15;
    int lg = (tid & 63) >> 4;
    float mu = stats[2 * 8 + b];
    float rs = stats[2 * 8 + 4 + b];
    __shared__ ushort Xt[64][64];     // [tok][chan], chunk-swizzled
    for (int k = 0; k < 16; ++k) {
        int e = tid + k * 256;
        int c = e >> 6, t = e & 63;
        float v = (x2[((size_t)(b * 64 + c)) * NN + tok0 + t] - mu) * rs * n2g[c] + n2b[c];
        Xt[t][((c >> 3) ^ (t & 7)) * 8 + (c & 7)] = f2bf(v);
    }
    __syncthreads();
    int brow = w * 16 + lr;
    bf16x8 bf0 = *(const bf16x8*)&Xt[brow][((0 + lg) ^ (lr & 7)) * 8];
    bf16x8 bf1 = *(const bf16x8*)&Xt[brow][((4 + lg) ^ (lr & 7)) * 8];
    f32x4 acc[8];
    #pragma unroll
    for (int mt = 0; mt < 8; ++mt) acc[mt] = (f32x4){0.f, 0.f, 0.f, 0.f};
    const ushort* wb = fc1wb + (size_t)(half * 128) * 64;
    #pragma unroll
    for (int mt = 0; mt < 8; ++mt) {
        bf16x8 a0 = *(const bf16x8*)&wb[(mt * 16 + lr) * 64 + lg * 8];
        bf16x8 a1 = *(const bf16x8*)&wb[(mt * 16 + lr) * 64 + 32 + lg * 8];
        acc[mt] = MFMA16(a0, bf0, acc[mt]);
        acc[mt] = MFMA16(a1, bf1, acc[mt]);
    }
    const float sb = rsqrtf(1.f + EPSV);
    int tok = tok0 + w * 16 + lr;
    #pragma unroll
    for (int mt = 0; mt < 8; ++mt) {
        #pragma unroll
        for (int r = 0; r < 4; ++r) {
            int o = half * 128 + mt * 16 + lg * 4 + r;
            float vv = acc[mt][r] * bn1g[o] * sb + bn1b[o];
            h1[((size_t)b * HID + o) * NN + tok] = f2bf(gelu_exact(vv));
        }
    }
}

// ---------------- mixer v2: register sliding-window; 32-row half planes ----------------
__global__ __launch_bounds__(256) void mixer_kernel(const ushort* __restrict__ h1,
                                                    const float* __restrict__ dw1w, const float* __restrict__ dw1b,
                                                    const float* __restrict__ dw3w, const float* __restrict__ dw3b,
                                                    const float* __restrict__ dw5w, const float* __restrict__ dw5b,
                                                    const float* __restrict__ dw7w, const float* __restrict__ dw7b,
                                                    const float* __restrict__ fftw,
                                                    const float* __restrict__ bnmg, const float* __restrict__ bnmb,
                                                    ushort* __restrict__ h2) {
    int c = blockIdx.x >> 1;
    int r0 = (blockIdx.x & 1) * 32;
    int b = blockIdx.y;
    int tid = threadIdx.x;
    __shared__ ushort ls[38][80];      // 6080 B
    uint* lz = (uint*)&ls[0][0];
    #pragma unroll
    for (int k = 0; k < 6; ++k) {
        int i = tid + k * 256;
        if (i < 1520) lz[i] = 0;
    }
    __syncthreads();
    const ushort* plane = h1 + (((size_t)b * HID + c) << 12);
    for (int e = tid; e < 304; e += 256) {
        int i = e >> 3, xc = e & 7;
        int gr = r0 + i - 3;
        if (gr >= 0 && gr < 64) {
            bf16x8 v = *(const bf16x8*)&plane[(gr << 6) + xc * 8];
            bf16x4 lo = {v[0], v[1], v[2], v[3]};
            bf16x4 hi = {v[4], v[5], v[6], v[7]};
            *(bf16x4*)&ls[i][xc * 8 + 4] = lo;
            *(bf16x4*)&ls[i][xc * 8 + 8] = hi;
        }
    }
    __syncthreads();

    int yy = tid >> 3;
    int x0 = (tid & 7) * 8;
    const float sb = rsqrtf(1.f + EPSV);
    float fw = fftw[c];
    float bg = bnmg[c] * sb, bb2 = bnmb[c];
    float acc[8], ctr[8];
    #pragma unroll
    for (int j = 0; j < 8; ++j) acc[j] = 0.f;

    if (c < 64) {
        float w0 = dw1w[c], b0 = dw1b[c];
        uint4 ua = *(const uint4*)&ls[yy + 3][x0];
        uint4 ub = *(const uint4*)&ls[yy + 3][x0 + 8];
        float wv[16];
        unpack2(ua.x, wv[0], wv[1]); unpack2(ua.y, wv[2], wv[3]);
        unpack2(ua.z, wv[4], wv[5]); unpack2(ua.w, wv[6], wv[7]);
        unpack2(ub.x, wv[8], wv[9]); unpack2(ub.y, wv[10], wv[11]);
        unpack2(ub.z, wv[12], wv[13]); unpack2(ub.w, wv[14], wv[15]);
        #pragma unroll
        for (int j = 0; j < 8; ++j) { ctr[j] = wv[j + 4]; acc[j] = w0 * ctr[j] + b0; }
    } else if (c < 128) {
        int lc = c - 64;
        float b0 = dw3b[lc];
        #pragma unroll
        for (int j = 0; j < 8; ++j) acc[j] = b0;
        #pragma unroll
        for (int dy = 0; dy < 3; ++dy) {
            int i = yy + dy + 2;
            uint4 ua = *(const uint4*)&ls[i][x0];
            uint4 ub = *(const uint4*)&ls[i][x0 + 8];
            float wv[16];
            unpack2(ua.x, wv[0], wv[1]); unpack2(ua.y, wv[2], wv[3]);
            unpack2(ua.z, wv[4], wv[5]); unpack2(ua.w, wv[6], wv[7]);
            unpack2(ub.x, wv[8], wv[9]); unpack2(ub.y, wv[10], wv[11]);
            unpack2(ub.z, wv[12], wv[13]); unpack2(ub.w, wv[14], wv[15]);
            if (dy == 1) {
                #pragma unroll
                for (int j = 0; j < 8; ++j) ctr[j] = wv[j + 4];
            }
            #pragma unroll
            for (int dx = 0; dx < 3; ++dx) {
                float wt = dw3w[lc * 9 + dy * 3 + dx];
                #pragma unroll
                for (int j = 0; j < 8; ++j) acc[j] += wt * wv[j + dx + 3];
            }
        }
    } else if (c < 192) {
        int lc = c - 128;
        float b0 = dw5b[lc];
        #pragma unroll
        for (int j = 0; j < 8; ++j) acc[j] = b0;
        #pragma unroll
        for (int dy = 0; dy < 5; ++dy) {
            int i = yy + dy + 1;
            uint4 ua = *(const uint4*)&ls[i][x0];
            uint4 ub = *(const uint4*)&ls[i][x0 + 8];
            float wv[16];
            unpack2(ua.x, wv[0], wv[1]); unpack2(ua.y, wv[2], wv[3]);
            unpack2(ua.z, wv[4], wv[5]); unpack2(ua.w, wv[6], wv[7]);
            unpack2(ub.x, wv[8], wv[9]); unpack2(ub.y, wv[10], wv[11]);
            unpack2(ub.z, wv[12], wv[13]); unpack2(ub.w, wv[14], wv[15]);
            if (dy == 2) {
                #pragma unroll
                for (int j = 0; j < 8; ++j) ctr[j] = wv[j + 4];
            }
            #pragma unroll
            for (int dx = 0; dx < 5; ++dx) {
                float wt = dw5w[lc * 25 + dy * 5 + dx];
                #pragma unroll
                for (int j = 0; j < 8; ++j) acc[j] += wt * wv[j + dx + 2];
            }
        }
    } else {
        int lc = c - 192;
        float b0 = dw7b[lc];
        #pragma unroll
        for (int j = 0; j < 8; ++j) acc[j] = b0;
        #pragma unroll
        for (int dy = 0; dy < 7; ++dy) {
            int i = yy + dy;
            uint4 ua = *(const uint4*)&ls[i][x0];
            uint4 ub = *(const uint4*)&ls[i][x0 + 8];
            float wv[16];
            unpack2(ua.x, wv[0], wv[1]); unpack2(ua.y, wv[2], wv[3]);
            unpack2(ua.z, wv[4], wv[5]); unpack2(ua.w, wv[6], wv[7]);
            unpack2(ub.x, wv[8], wv[9]); unpack2(ub.y, wv[10], wv[11]);
            unpack2(ub.z, wv[12], wv[13]); unpack2(ub.w, wv[14], wv[15]);
            if (dy == 3) {
                #pragma unroll
                for (int j = 0; j < 8; ++j) ctr[j] = wv[j + 4];
            }
            #pragma unroll
            for (int dx = 0; dx < 7; ++dx) {
                float wt = dw7w[lc * 49 + dy * 7 + dx];
                #pragma unroll
                for (int j = 0; j < 8; ++j) acc[j] += wt * wv[j + dx + 1];
            }
        }
    }

    bf16x8 o;
    #pragma unroll
    for (int j = 0; j < 8; ++j) {
        float val = fw * acc[j] + ctr[j];
        o[j] = (short)f2bf(gelu_exact(val) * bg + bb2);
    }
    ushort* outp = h2 + (((size_t)b * HID + c) << 12);
    *(bf16x8*)&outp[((r0 + yy) << 6) + x0] = o;
}

// ---------------- fc2 MFMA: out = bn2(fc2w @ h2) + x2 ----------------
__global__ __launch_bounds__(256) void fc2_mfma(const ushort* __restrict__ h2,
                                                const ushort* __restrict__ fc2wb,
                                                const float* __restrict__ bn2g,
                                                const float* __restrict__ bn2b,
                                                const float* __restrict__ x2,
                                                float* __restrict__ out) {
    int b = blockIdx.y;
    int tok0 = blockIdx.x * 64;
    int tid = threadIdx.x;
    int w = tid >> 6;
    int lr = tid & 15;
    int lg = (tid & 63) >> 4;
    __shared__ ushort Xt[64][256];    // [tok][chan], chunk-swizzled (32 KB)
    for (int k = 0; k < 8; ++k) {
        int e = tid + k * 256;        // 2048 chunks of 8 toks
        int c = e >> 3, t8 = (e & 7) * 8;
        bf16x8 v = *(const bf16x8*)&h2[((size_t)(b * 256 + c)) * NN + tok0 + t8];
        #pragma unroll
        for (int j = 0; j < 8; ++j) {
            int t = t8 + j;
            Xt[t][((c >> 3) ^ (t & 7)) * 8 + (c & 7)] = (ushort)v[j];
        }
    }
    __syncthreads();
    int brow = w * 16 + lr;
    f32x4 acc[4];
    #pragma unroll
    for (int mt = 0; mt < 4; ++mt) acc[mt] = (f32x4){0.f, 0.f, 0.f, 0.f};
    #pragma unroll
    for (int ks = 0; ks < 8; ++ks) {
        bf16x8 bfr = *(const bf16x8*)&Xt[brow][(((ks * 4 + lg) & 7) ^ (lr & 7)) * 8 + ((ks * 4 + lg) & ~7) * 8];
        #pragma unroll
        for (int mt = 0; mt < 4; ++mt) {
            bf16x8 a = *(const bf16x8*)&fc2wb[(mt * 16 + lr) * 256 + ks * 32 + lg * 8];
            acc[mt] = MFMA16(a, bfr, acc[mt]);
        }
    }
    const float sb = rsqrtf(1.f + EPSV);
    int tok = tok0 + w * 16 + lr;
    #pragma unroll
    for (int mt = 0; mt < 4; ++mt) {
        #pragma unroll
        for (int r = 0; r < 4; ++r) {
            int o = mt * 16 + lg * 4 + r;
            size_t off = ((size_t)b * 64 + o) * NN + tok;
            out[off] = acc[mt][r] * bn2g[o] * sb + bn2b[o] + x2[off];
        }
    }
}

extern "C" void kernel_launch(void* const* d_in, const int* in_sizes, int n_in,
                              void* d_out, int out_size, void* d_ws, size_t ws_size,
                              hipStream_t stream) {
    const float* x    = (const float*)d_in[0];
    const float* cnn  = (const float*)d_in[1];
    const float* n1g  = (const float*)d_in[2];
    const float* n1b  = (const float*)d_in[3];
    const float* n2g  = (const float*)d_in[4];
    const float* n2b  = (const float*)d_in[5];
    const float* n3g  = (const float*)d_in[6];
    const float* n3b  = (const float*)d_in[7];
    const float* qw   = (const float*)d_in[8];
    const float* qb   = (const float*)d_in[9];
    const float* kvw  = (const float*)d_in[10];
    const float* kvb  = (const float*)d_in[11];
    const float* lcw  = (const float*)d_in[12];
    const float* lcb  = (const float*)d_in[13];
    const float* fc1w = (const float*)d_in[14];
    const float* bn1g = (const float*)d_in[15];
    const float* bn1b = (const float*)d_in[16];
    const float* dw1w = (const float*)d_in[17];
    const float* dw1b = (const float*)d_in[18];
    const float* dw3w = (const float*)d_in[19];
    const float* dw3b = (const float*)d_in[20];
    const float* dw5w = (const float*)d_in[21];
    const float* dw5b = (const float*)d_in[22];
    const float* dw7w = (const float*)d_in[23];
    const float* dw7b = (const float*)d_in[24];
    const float* bnmg = (const float*)d_in[25];
    const float* bnmb = (const float*)d_in[26];
    const float* fftw = (const float*)d_in[27];
    const float* fc2w = (const float*)d_in[28];
    const float* bn2g = (const float*)d_in[29];
    const float* bn2b = (const float*)d_in[30];

    float* ws = (float*)d_ws;
    float* stats = ws;                     // 64
    float* part  = ws + 64;                // 1024
    float* part2 = ws + 1088;              // 2048
    float* base  = ws + 3200;
    const size_t M = 1048576;
    float* x2     = base;                              // [0, 1M)
    ushort* qr_bf = (ushort*)(base + M);               // [1M, 1.5M)
    ushort* kr_bf = (ushort*)(base + M + M / 2);       // [1.5M, 2M)
    ushort* vt_bf = (ushort*)(base + 2 * M);           // [2M, 2.5M)
    ushort* Opart = (ushort*)(base + 7 * M / 2);       // [3.5M, 7.5M)
    float* ml     = base + 15 * M / 2;                 // [7.5M, 7.75M)
    ushort* h1 = (ushort*)(base + M);                  // [1M,3M) overlay qr/kr/vt (dead post-attn)
    ushort* h2 = (ushort*)(base + 7 * M / 2);          // overlay Opart head (dead post-combine)
    ushort* fc1wb = (ushort*)(base + 8 * M);           // 16384 ushorts
    ushort* fc2wb = fc1wb + 16384;
    ushort* qwb   = fc2wb + 16384;                     // 4096
    ushort* kvwb  = qwb + 4096;                        // 8192
    float* outp = (float*)d_out;

    wprep_kernel<<<176, 256, 0, stream>>>(fc1w, fc2w, qw, kvw, fc1wb, fc2wb, qwb, kvwb);
    stats_pair_kernel<<<dim3(64, 4), 256, 0, stream>>>(x, cnn, part);
    stats_fin_kernel<<<8, 64, 0, stream>>>(part, stats);
    qkv_fused<<<dim3(64, 4), 256, 0, stream>>>(x, n1g, n1b, qwb, qb, cnn, n3g, n3b,
                                               lcw, lcb, kvwb, kvb, stats,
                                               qr_bf, kr_bf, vt_bf);
    attn_kernel<<<dim3(64, 4, NCH), 256, 0, stream>>>(qr_bf, kr_bf, vt_bf, Opart, ml);
    combine_kernel<<<1024, 256, 0, stream>>>(Opart, ml, x, x2, part2);
    stats2b_kernel<<<4, 256, 0, stream>>>(part2, stats, 2);
    fc1_mfma<<<dim3(128, 4), 256, 0, stream>>>(x2, fc1wb, n2g, n2b, bn1g, bn1b, stats, h1);
    mixer_kernel<<<dim3(512, 4), 256, 0, stream>>>(h1, dw1w, dw1b, dw3w, dw3b, dw5w, dw5b,
                                                   dw7w, dw7b, fftw, bnmg, bnmb, h2);
    fc2_mfma<<<dim3(64, 4), 256, 0, stream>>>(h2, fc2wb, bn2g, bn2b, x2, outp);
}

// Round 14
// 120.745 us; speedup vs baseline: 1.0895x; 1.0895x over previous
//
#include <hip/hip_runtime.h>
#include <hip/hip_bf16.h>
#include <math.h>

#define BB 4
#define CC 64
#define NN 4096
#define HD 64
#define HID 256
#define EPSV 1e-5f
#define CNT (CC*NN)
#define NCH 8            // KV split chunks

typedef float f32x4 __attribute__((ext_vector_type(4)));
typedef short bf16x8 __attribute__((ext_vector_type(8)));
typedef short bf16x4 __attribute__((ext_vector_type(4)));
#define MFMA16(a, b, c) __builtin_amdgcn_mfma_f32_16x16x32_bf16(a, b, c, 0, 0, 0)

__device__ __forceinline__ float gelu_exact(float x) {
    return 0.5f * x * (1.0f + erff(x * 0.70710678118654752f));
}
__device__ __forceinline__ ushort f2bf(float f) {
    unsigned u = __float_as_uint(f);
    unsigned r = (u + 0x7FFFu + ((u >> 16) & 1u)) >> 16;
    return (ushort)r;
}
__device__ __forceinline__ float bf2f(ushort u) {
    return __uint_as_float(((unsigned)u) << 16);
}
__device__ __forceinline__ unsigned cvtpk(float lo, float hi) {
    unsigned r;
    asm("v_cvt_pk_bf16_f32 %0, %1, %2" : "=v"(r) : "v"(lo), "v"(hi));
    return r;
}
__device__ __forceinline__ void unpack2(unsigned u, float& lo, float& hi) {
    lo = __uint_as_float(u << 16);
    hi = __uint_as_float(u & 0xffff0000u);
}

// ---------------- weight prep: fp32 -> bf16 (fc1, fc2, qw, kvw) ----------------
__global__ __launch_bounds__(256) void wprep_kernel(const float* __restrict__ fc1w,
                                                    const float* __restrict__ fc2w,
                                                    const float* __restrict__ qw,
                                                    const float* __restrict__ kvw,
                                                    ushort* __restrict__ fc1wb,
                                                    ushort* __restrict__ fc2wb,
                                                    ushort* __restrict__ qwb,
                                                    ushort* __restrict__ kvwb) {
    int i = blockIdx.x * 256 + threadIdx.x;   // 45056
    if (i < 16384) fc1wb[i] = f2bf(fc1w[i]);
    else if (i < 32768) fc2wb[i - 16384] = f2bf(fc2w[i - 16384]);
    else if (i < 36864) qwb[i - 32768] = f2bf(qw[i - 32768]);
    else if (i < 45056) kvwb[i - 36864] = f2bf(kvw[i - 36864]);
}

// ---------------- fused stats stage 1 for x and cnn ----------------
__global__ __launch_bounds__(256) void stats_pair_kernel(const float* __restrict__ x,
                                                         const float* __restrict__ cnn,
                                                         float* __restrict__ part) {
    int b = blockIdx.y;
    int blk = blockIdx.x;
    const float4* p0 = (const float4*)(x + (size_t)b * CNT);
    const float4* p1 = (const float4*)(cnn + (size_t)b * CNT);
    float s0 = 0.f, s20 = 0.f, s1 = 0.f, s21 = 0.f;
    #pragma unroll
    for (int k = 0; k < 4; ++k) {
        float4 v = p0[blk * 1024 + k * 256 + threadIdx.x];
        s0  += v.x + v.y + v.z + v.w;
        s20 += v.x * v.x + v.y * v.y + v.z * v.z + v.w * v.w;
        float4 u = p1[blk * 1024 + k * 256 + threadIdx.x];
        s1  += u.x + u.y + u.z + u.w;
        s21 += u.x * u.x + u.y * u.y + u.z * u.z + u.w * u.w;
    }
    #pragma unroll
    for (int off = 32; off > 0; off >>= 1) {
        s0  += __shfl_xor(s0, off);
        s20 += __shfl_xor(s20, off);
        s1  += __shfl_xor(s1, off);
        s21 += __shfl_xor(s21, off);
    }
    __shared__ float sh[4][4];
    int wid = threadIdx.x >> 6, lane = threadIdx.x & 63;
    if (lane == 0) { sh[wid][0] = s0; sh[wid][1] = s20; sh[wid][2] = s1; sh[wid][3] = s21; }
    __syncthreads();
    if (threadIdx.x == 0) {
        float a0 = sh[0][0] + sh[1][0] + sh[2][0] + sh[3][0];
        float a1 = sh[0][1] + sh[1][1] + sh[2][1] + sh[3][1];
        float a2 = sh[0][2] + sh[1][2] + sh[2][2] + sh[3][2];
        float a3 = sh[0][3] + sh[1][3] + sh[2][3] + sh[3][3];
        part[((0 * 4 + b) * 64 + blk) * 2]     = a0;
        part[((0 * 4 + b) * 64 + blk) * 2 + 1] = a1;
        part[((1 * 4 + b) * 64 + blk) * 2]     = a2;
        part[((1 * 4 + b) * 64 + blk) * 2 + 1] = a3;
    }
}

// ---------------- stats finalize (both slots) ----------------
__global__ __launch_bounds__(64) void stats_fin_kernel(const float* __restrict__ part,
                                                       float* __restrict__ stats) {
    int sb_ = blockIdx.x;    // slot*4 + b
    int lane = threadIdx.x;
    float s = part[(sb_ * 64 + lane) * 2];
    float s2 = part[(sb_ * 64 + lane) * 2 + 1];
    #pragma unroll
    for (int off = 32; off > 0; off >>= 1) {
        s  += __shfl_xor(s, off);
        s2 += __shfl_xor(s2, off);
    }
    if (lane == 0) {
        int slot = sb_ >> 2, b = sb_ & 3;
        float mu = s / (float)CNT;
        float var = s2 / (float)CNT - mu * mu;
        stats[slot * 8 + b] = mu;
        stats[slot * 8 + 4 + b] = rsqrtf(var + EPSV);
    }
}

// ---------------- stats stage 2b (256 partials, slot 2) ----------------
__global__ __launch_bounds__(256) void stats2b_kernel(const float* __restrict__ part2,
                                                      float* __restrict__ stats, int slot) {
    int b = blockIdx.x;
    int t = threadIdx.x;
    float s = part2[(b * 256 + t) * 2];
    float s2 = part2[(b * 256 + t) * 2 + 1];
    #pragma unroll
    for (int off = 32; off > 0; off >>= 1) {
        s  += __shfl_xor(s, off);
        s2 += __shfl_xor(s2, off);
    }
    __shared__ float shs[4], shs2[4];
    int wid = t >> 6, lane = t & 63;
    if (lane == 0) { shs[wid] = s; shs2[wid] = s2; }
    __syncthreads();
    if (t == 0) {
        float S = shs[0] + shs[1] + shs[2] + shs[3];
        float S2 = shs2[0] + shs2[1] + shs2[2] + shs2[3];
        float mu = S / (float)CNT;
        float var = S2 / (float)CNT - mu * mu;
        stats[slot * 8 + b] = mu;
        stats[slot * 8 + 4 + b] = rsqrtf(var + EPSV);
    }
}

// ---------------- dw3k: kvin = dw3(gn(cnn)) + bias + gn(cnn) ----------------
__global__ __launch_bounds__(256) void dw3k_kernel(const float* __restrict__ cnn,
                                                   const float* __restrict__ n3g,
                                                   const float* __restrict__ n3b,
                                                   const float* __restrict__ lcw,
                                                   const float* __restrict__ lcb,
                                                   const float* __restrict__ stats,
                                                   float* __restrict__ kvin) {
    int i = blockIdx.x * 256 + threadIdx.x;   // 1,048,576
    int x = i & 63;
    int y = (i >> 6) & 63;
    int c = (i >> 12) & 63;
    int b = i >> 18;
    float mu = stats[1 * 8 + b];
    float rs = stats[1 * 8 + 4 + b];
    float sc = rs * n3g[c];
    float of = n3b[c] - mu * sc;
    const float* plane = cnn + ((size_t)(i >> 12) << 12);
    float acc = lcb[c];
    #pragma unroll
    for (int dy = 0; dy < 3; ++dy) {
        int yy = y + dy - 1;
        if (yy < 0 || yy >= 64) continue;
        #pragma unroll
        for (int dx = 0; dx < 3; ++dx) {
            int xx = x + dx - 1;
            if (xx < 0 || xx >= 64) continue;
            acc += lcw[c * 9 + dy * 3 + dx] * (plane[(yy << 6) + xx] * sc + of);
        }
    }
    kvin[i] = acc + plane[(y << 6) + x] * sc + of;
}

// ---------------- Q MFMA: gn(x) -> proj -> bias+RoPE -> scaled bf16 (B,N,HD) ----------------
// Output pre-scaled by SCL2 = HD^-0.5 * log2(e) so attn softmax works in base-2 units.
__global__ __launch_bounds__(256) void q_mfma(const float* __restrict__ x,
                                              const float* __restrict__ n1g,
                                              const float* __restrict__ n1b,
                                              const ushort* __restrict__ qwb,
                                              const float* __restrict__ qb,
                                              const float* __restrict__ stats,
                                              ushort* __restrict__ qr) {
    const float SCL2 = 0.125f * 1.44269504f;
    int b = blockIdx.y;
    int tok0 = blockIdx.x * 64;
    int tid = threadIdx.x;
    int w = tid >> 6;
    int lr = tid & 15;
    int lg = (tid & 63) >> 4;
    float mu = stats[0 * 8 + b];
    float rs = stats[0 * 8 + 4 + b];
    __shared__ ushort Xt[64][64];     // [tok][chan], chunk-swizzled
    for (int k = 0; k < 16; ++k) {
        int e = tid + k * 256;
        int c = e >> 6, t = e & 63;
        float v = (x[((size_t)(b * 64 + c)) * NN + tok0 + t] - mu) * rs * n1g[c] + n1b[c];
        Xt[t][((c >> 3) ^ (t & 7)) * 8 + (c & 7)] = f2bf(v);
    }
    __syncthreads();
    int brow = w * 16 + lr;
    bf16x8 bf0 = *(const bf16x8*)&Xt[brow][((0 + lg) ^ (lr & 7)) * 8];
    bf16x8 bf1 = *(const bf16x8*)&Xt[brow][((4 + lg) ^ (lr & 7)) * 8];
    f32x4 acc[4];
    #pragma unroll
    for (int mt = 0; mt < 4; ++mt) acc[mt] = (f32x4){0.f, 0.f, 0.f, 0.f};
    #pragma unroll
    for (int mt = 0; mt < 4; ++mt) {
        bf16x8 a0 = *(const bf16x8*)&qwb[(mt * 16 + lr) * 64 + lg * 8];
        bf16x8 a1 = *(const bf16x8*)&qwb[(mt * 16 + lr) * 64 + 32 + lg * 8];
        acc[mt] = MFMA16(a0, bf0, acc[mt]);
        acc[mt] = MFMA16(a1, bf1, acc[mt]);
    }
    int tok = tok0 + w * 16 + lr;
    int hh = tok >> 6, ww2 = tok & 63;
    ushort* qrow = qr + ((size_t)b * NN + tok) * 64;
    #pragma unroll
    for (int mt = 0; mt < 4; ++mt) {
        #pragma unroll
        for (int pr = 0; pr < 2; ++pr) {
            int o = mt * 16 + lg * 4 + pr * 2;
            float a0 = acc[mt][pr * 2]     + qb[o];
            float a1 = acc[mt][pr * 2 + 1] + qb[o + 1];
            int j = (o & 31) >> 1;
            float freq = exp2f(-0.88584749f * (float)j);
            float pos = (o < 32) ? (float)hh : (float)ww2;
            float st, ct;
            __sincosf(pos * freq, &st, &ct);
            qrow[o]     = f2bf((a0 * ct - a1 * st) * SCL2);
            qrow[o + 1] = f2bf((a1 * ct + a0 * st) * SCL2);
        }
    }
}

// ---------------- KV MFMA: kvin -> proj; K+RoPE (B,N,HD); V^T key-permuted (B,HD,N) ----------------
__global__ __launch_bounds__(256) void kv_mfma(const float* __restrict__ kvin,
                                               const ushort* __restrict__ kvwb,
                                               const float* __restrict__ kvb,
                                               ushort* __restrict__ kr,
                                               ushort* __restrict__ vt) {
    int b = blockIdx.y;
    int tok0 = blockIdx.x * 64;
    int tid = threadIdx.x;
    int w = tid >> 6;
    int lr = tid & 15;
    int lg = (tid & 63) >> 4;
    __shared__ ushort Xt[64][64];
    for (int k = 0; k < 16; ++k) {
        int e = tid + k * 256;
        int c = e >> 6, t = e & 63;
        Xt[t][((c >> 3) ^ (t & 7)) * 8 + (c & 7)] =
            f2bf(kvin[((size_t)(b * 64 + c)) * NN + tok0 + t]);
    }
    __syncthreads();
    int brow = w * 16 + lr;
    bf16x8 bf0 = *(const bf16x8*)&Xt[brow][((0 + lg) ^ (lr & 7)) * 8];
    bf16x8 bf1 = *(const bf16x8*)&Xt[brow][((4 + lg) ^ (lr & 7)) * 8];
    f32x4 acc[8];
    #pragma unroll
    for (int mt = 0; mt < 8; ++mt) acc[mt] = (f32x4){0.f, 0.f, 0.f, 0.f};
    #pragma unroll
    for (int mt = 0; mt < 8; ++mt) {
        bf16x8 a0 = *(const bf16x8*)&kvwb[(mt * 16 + lr) * 64 + lg * 8];
        bf16x8 a1 = *(const bf16x8*)&kvwb[(mt * 16 + lr) * 64 + 32 + lg * 8];
        acc[mt] = MFMA16(a0, bf0, acc[mt]);
        acc[mt] = MFMA16(a1, bf1, acc[mt]);
    }
    int tl = w * 16 + lr;                 // token-in-block
    int tok = tok0 + tl;
    int hh = tok >> 6, ww2 = tok & 63;
    int permk = (lr >> 2) * 16 + w * 4 + (lr & 3);   // perm(tl) for V key order
    ushort* krow = kr + ((size_t)b * NN + tok) * 64;
    #pragma unroll
    for (int mt = 0; mt < 4; ++mt) {      // K half, with RoPE
        #pragma unroll
        for (int pr = 0; pr < 2; ++pr) {
            int o = mt * 16 + lg * 4 + pr * 2;
            float a0 = acc[mt][pr * 2]     + kvb[o];
            float a1 = acc[mt][pr * 2 + 1] + kvb[o + 1];
            int j = (o & 31) >> 1;
            float freq = exp2f(-0.88584749f * (float)j);
            float pos = (o < 32) ? (float)hh : (float)ww2;
            float st, ct;
            __sincosf(pos * freq, &st, &ct);
            krow[o]     = f2bf(a0 * ct - a1 * st);
            krow[o + 1] = f2bf(a1 * ct + a0 * st);
        }
    }
    #pragma unroll
    for (int mt = 4; mt < 8; ++mt) {      // V half, key-permuted transpose store
        #pragma unroll
        for (int r = 0; r < 4; ++r) {
            int o = mt * 16 + lg * 4 + r;          // [64,128)
            float a0 = acc[mt][r] + kvb[o];
            vt[((size_t)b * 64 + (o - 64)) * NN + tok0 + permk] = f2bf(a0);
        }
    }
}

// ---------------- MFMA flash attention v4.1: swapped QK^T, in-reg P, b128 PV, pre-scaled Q ----------------
// grid dim3(64, B, NCH), 256 thr = 4 waves x 16 q-rows; KV tile 64; chunk = 512 keys
__global__ __launch_bounds__(256) void attn_kernel(const ushort* __restrict__ qr,
                                                   const ushort* __restrict__ kr,
                                                   const ushort* __restrict__ vt,
                                                   ushort* __restrict__ Opart,
                                                   float* __restrict__ ml) {
    int b = blockIdx.y;
    int q0 = blockIdx.x * 64;
    int chunk = blockIdx.z;
    int tid = threadIdx.x;
    int w = tid >> 6;
    int lane = tid & 63;
    int lr = lane & 15;
    int lg = lane >> 4;

    __shared__ ushort Kl[64 * 64];
    __shared__ ushort Vl[64 * 64];

    bf16x8 qf[2];
    {
        const ushort* qp = qr + ((size_t)b * NN + q0 + w * 16 + lr) * 64;
        qf[0] = *(const bf16x8*)(qp + lg * 8);
        qf[1] = *(const bf16x8*)(qp + 32 + lg * 8);
    }

    f32x4 oacc[4];
    #pragma unroll
    for (int t = 0; t < 4; ++t) oacc[t] = (f32x4){0.f, 0.f, 0.f, 0.f};
    float m_ = -INFINITY, l_ = 0.f;     // base-2 scalar state for q-row = q0+w*16+lr

    const size_t kbase = ((size_t)b * NN) * 64;
    const int t0 = chunk * 8, tend = t0 + 8;

    for (int t = t0; t < tend; ++t) {
        int k0 = t * 64;
        __syncthreads();
        #pragma unroll
        for (int it = 0; it < 2; ++it) {
            int e = tid + it * 256;
            int row = e >> 3, cib = e & 7;
            int sw = cib ^ (row & 7);
            *(bf16x8*)(Kl + row * 64 + sw * 8) =
                *(const bf16x8*)(kr + kbase + (size_t)(k0 + row) * 64 + cib * 8);
            *(bf16x8*)(Vl + row * 64 + sw * 8) =
                *(const bf16x8*)(vt + ((size_t)b * 64 + row) * NN + k0 + cib * 8);
        }
        __syncthreads();

        // S^T = K Q : lane holds q=lr, keys kt*16 + lg*4 + r   (already base-2 scaled)
        f32x4 sacc[4];
        #pragma unroll
        for (int kt = 0; kt < 4; ++kt) {
            int row = kt * 16 + lr;
            bf16x8 k0f = *(const bf16x8*)(Kl + row * 64 + ((0 * 4 + lg) ^ (lr & 7)) * 8);
            bf16x8 k1f = *(const bf16x8*)(Kl + row * 64 + ((1 * 4 + lg) ^ (lr & 7)) * 8);
            f32x4 z = {0.f, 0.f, 0.f, 0.f};
            z = MFMA16(k0f, qf[0], z);
            sacc[kt] = MFMA16(k1f, qf[1], z);
        }

        float vmax = fmaxf(fmaxf(fmaxf(sacc[0][0], sacc[0][1]), fmaxf(sacc[0][2], sacc[0][3])),
                           fmaxf(fmaxf(sacc[1][0], sacc[1][1]), fmaxf(sacc[1][2], sacc[1][3])));
        vmax = fmaxf(vmax, fmaxf(fmaxf(fmaxf(sacc[2][0], sacc[2][1]), fmaxf(sacc[2][2], sacc[2][3])),
                                 fmaxf(fmaxf(sacc[3][0], sacc[3][1]), fmaxf(sacc[3][2], sacc[3][3]))));
        vmax = fmaxf(vmax, __shfl_xor(vmax, 16));
        vmax = fmaxf(vmax, __shfl_xor(vmax, 32));
        if (__any(vmax - m_ > 8.f)) {          // defer-max
            float mn = fmaxf(m_, vmax);
            float cr = exp2f(m_ - mn);
            l_ *= cr;
            m_ = mn;
            float crq[4];
            #pragma unroll
            for (int r = 0; r < 4; ++r) crq[r] = __shfl(cr, lg * 4 + r);
            #pragma unroll
            for (int ht = 0; ht < 4; ++ht)
                #pragma unroll
                for (int r = 0; r < 4; ++r) oacc[ht][r] *= crq[r];
        }

        unsigned u[8];
        float lsum = 0.f;
        #pragma unroll
        for (int kt = 0; kt < 4; ++kt) {
            float p0 = exp2f(sacc[kt][0] - m_);
            float p1 = exp2f(sacc[kt][1] - m_);
            float p2 = exp2f(sacc[kt][2] - m_);
            float p3 = exp2f(sacc[kt][3] - m_);
            lsum += (p0 + p1) + (p2 + p3);
            u[kt * 2]     = cvtpk(p0, p1);
            u[kt * 2 + 1] = cvtpk(p2, p3);
        }
        lsum += __shfl_xor(lsum, 16);
        lsum += __shfl_xor(lsum, 32);
        l_ += lsum;

        uint4 t0v = {u[0], u[1], u[2], u[3]};   // keys {lg*4+r, 16+lg*4+r}
        uint4 t1v = {u[4], u[5], u[6], u[7]};   // keys {32+lg*4+r, 48+lg*4+r}
        bf16x8 pa0 = __builtin_bit_cast(bf16x8, t0v);
        bf16x8 pa1 = __builtin_bit_cast(bf16x8, t1v);
        // PV: V stored key-permuted so lane's keys are contiguous chunks lg*2, lg*2+1
        #pragma unroll
        for (int ht = 0; ht < 4; ++ht) {
            int row = ht * 16 + lr;
            bf16x8 vf0 = *(const bf16x8*)(Vl + row * 64 + ((lg * 2) ^ (row & 7)) * 8);
            bf16x8 vf1 = *(const bf16x8*)(Vl + row * 64 + ((lg * 2 + 1) ^ (row & 7)) * 8);
            oacc[ht] = MFMA16(pa0, vf0, oacc[ht]);
            oacc[ht] = MFMA16(pa1, vf1, oacc[ht]);
        }
    }

    int n0 = q0 + w * 16 + lg * 4;
    #pragma unroll
    for (int ht = 0; ht < 4; ++ht) {
        int hd = ht * 16 + lr;
        ushort4 o4;
        o4.x = f2bf(oacc[ht][0]);
        o4.y = f2bf(oacc[ht][1]);
        o4.z = f2bf(oacc[ht][2]);
        o4.w = f2bf(oacc[ht][3]);
        *(ushort4*)&Opart[(((size_t)chunk * BB + b) * 64 + hd) * NN + n0] = o4;
    }
    if (lg == 0) {
        int n = q0 + w * 16 + lr;
        ml[((size_t)b * NN + n) * 16 + chunk * 2]     = m_;
        ml[((size_t)b * NN + n) * 16 + chunk * 2 + 1] = l_;
    }
}

// ---------------- combine: x2 = sum_c O_c*w_c + x; fused stats partials ----------------
__global__ __launch_bounds__(256) void combine_kernel(const ushort* __restrict__ Opart,
                                                      const float* __restrict__ ml,
                                                      const float* __restrict__ x,
                                                      float* __restrict__ x2,
                                                      float* __restrict__ part2) {
    int i = blockIdx.x * 256 + threadIdx.x;   // 262144
    int n4 = i & 1023;
    int hd = (i >> 10) & 63;
    int b = i >> 16;
    int n0 = n4 << 2;
    float wgt[4][NCH];
    const float* mlp = ml + ((size_t)b * NN + n0) * 16;
    #pragma unroll
    for (int tk = 0; tk < 4; ++tk) {
        float m[NCH], l[NCH];
        const float4* p4 = (const float4*)(mlp + tk * 16);
        #pragma unroll
        for (int q = 0; q < 4; ++q) {
            float4 v = p4[q];
            m[q * 2] = v.x; l[q * 2] = v.y; m[q * 2 + 1] = v.z; l[q * 2 + 1] = v.w;
        }
        float M = m[0];
        #pragma unroll
        for (int c = 1; c < NCH; ++c) M = fmaxf(M, m[c]);
        float e[NCH], L = 0.f;
        #pragma unroll
        for (int c = 0; c < NCH; ++c) { e[c] = exp2f(m[c] - M); L += l[c] * e[c]; }
        float inv = 1.f / L;
        #pragma unroll
        for (int c = 0; c < NCH; ++c) wgt[tk][c] = e[c] * inv;
    }
    float4 acc = {0.f, 0.f, 0.f, 0.f};
    #pragma unroll
    for (int c = 0; c < NCH; ++c) {
        ushort4 o4 = *(const ushort4*)&Opart[(((size_t)c * BB + b) * 64 + hd) * NN + n0];
        acc.x += bf2f(o4.x) * wgt[0][c];
        acc.y += bf2f(o4.y) * wgt[1][c];
        acc.z += bf2f(o4.z) * wgt[2][c];
        acc.w += bf2f(o4.w) * wgt[3][c];
    }
    size_t off = ((size_t)b * 64 + hd) * NN + n0;
    float4 xv = *(const float4*)&x[off];
    acc.x += xv.x; acc.y += xv.y; acc.z += xv.z; acc.w += xv.w;
    *(float4*)&x2[off] = acc;

    float s = acc.x + acc.y + acc.z + acc.w;
    float s2 = acc.x * acc.x + acc.y * acc.y + acc.z * acc.z + acc.w * acc.w;
    #pragma unroll
    for (int off2 = 32; off2 > 0; off2 >>= 1) {
        s  += __shfl_xor(s, off2);
        s2 += __shfl_xor(s2, off2);
    }
    __shared__ float shs[4], shs2[4];
    int wid = threadIdx.x >> 6, lane = threadIdx.x & 63;
    if (lane == 0) { shs[wid] = s; shs2[wid] = s2; }
    __syncthreads();
    if (threadIdx.x == 0) {
        part2[blockIdx.x * 2]     = shs[0] + shs[1] + shs[2] + shs[3];
        part2[blockIdx.x * 2 + 1] = shs2[0] + shs2[1] + shs2[2] + shs2[3];
    }
}

// ---------------- fc1 MFMA: h1 = gelu(bn1(fc1w @ gn2(x2))) -> bf16 ----------------
__global__ __launch_bounds__(256) void fc1_mfma(const float* __restrict__ x2,
                                                const ushort* __restrict__ fc1wb,
                                                const float* __restrict__ n2g,
                                                const float* __restrict__ n2b,
                                                const float* __restrict__ bn1g,
                                                const float* __restrict__ bn1b,
                                                const float* __restrict__ stats,
                                                ushort* __restrict__ h1) {
    int b = blockIdx.y;
    int tok0 = (blockIdx.x >> 1) * 64;
    int half = blockIdx.x & 1;
    int tid = threadIdx.x;
    int w = tid >> 6;
    int lr = tid & 15;
    int lg = (tid & 63) >> 4;
    float mu = stats[2 * 8 + b];
    float rs = stats[2 * 8 + 4 + b];
    __shared__ ushort Xt[64][64];     // [tok][chan], chunk-swizzled
    for (int k = 0; k < 16; ++k) {
        int e = tid + k * 256;
        int c = e >> 6, t = e & 63;
        float v = (x2[((size_t)(b * 64 + c)) * NN + tok0 + t] - mu) * rs * n2g[c] + n2b[c];
        Xt[t][((c >> 3) ^ (t & 7)) * 8 + (c & 7)] = f2bf(v);
    }
    __syncthreads();
    int brow = w * 16 + lr;
    bf16x8 bf0 = *(const bf16x8*)&Xt[brow][((0 + lg) ^ (lr & 7)) * 8];
    bf16x8 bf1 = *(const bf16x8*)&Xt[brow][((4 + lg) ^ (lr & 7)) * 8];
    f32x4 acc[8];
    #pragma unroll
    for (int mt = 0; mt < 8; ++mt) acc[mt] = (f32x4){0.f, 0.f, 0.f, 0.f};
    const ushort* wb = fc1wb + (size_t)(half * 128) * 64;
    #pragma unroll
    for (int mt = 0; mt < 8; ++mt) {
        bf16x8 a0 = *(const bf16x8*)&wb[(mt * 16 + lr) * 64 + lg * 8];
        bf16x8 a1 = *(const bf16x8*)&wb[(mt * 16 + lr) * 64 + 32 + lg * 8];
        acc[mt] = MFMA16(a0, bf0, acc[mt]);
        acc[mt] = MFMA16(a1, bf1, acc[mt]);
    }
    const float sb = rsqrtf(1.f + EPSV);
    int tok = tok0 + w * 16 + lr;
    #pragma unroll
    for (int mt = 0; mt < 8; ++mt) {
        #pragma unroll
        for (int r = 0; r < 4; ++r) {
            int o = half * 128 + mt * 16 + lg * 4 + r;
            float vv = acc[mt][r] * bn1g[o] * sb + bn1b[o];
            h1[((size_t)b * HID + o) * NN + tok] = f2bf(gelu_exact(vv));
        }
    }
}

// ---------------- mixer v2: register sliding-window; 32-row half planes ----------------
__global__ __launch_bounds__(256) void mixer_kernel(const ushort* __restrict__ h1,
                                                    const float* __restrict__ dw1w, const float* __restrict__ dw1b,
                                                    const float* __restrict__ dw3w, const float* __restrict__ dw3b,
                                                    const float* __restrict__ dw5w, const float* __restrict__ dw5b,
                                                    const float* __restrict__ dw7w, const float* __restrict__ dw7b,
                                                    const float* __restrict__ fftw,
                                                    const float* __restrict__ bnmg, const float* __restrict__ bnmb,
                                                    ushort* __restrict__ h2) {
    int c = blockIdx.x >> 1;
    int r0 = (blockIdx.x & 1) * 32;
    int b = blockIdx.y;
    int tid = threadIdx.x;
    __shared__ ushort ls[38][80];      // 6080 B
    uint* lz = (uint*)&ls[0][0];
    #pragma unroll
    for (int k = 0; k < 6; ++k) {
        int i = tid + k * 256;
        if (i < 1520) lz[i] = 0;
    }
    __syncthreads();
    const ushort* plane = h1 + (((size_t)b * HID + c) << 12);
    for (int e = tid; e < 304; e += 256) {
        int i = e >> 3, xc = e & 7;
        int gr = r0 + i - 3;
        if (gr >= 0 && gr < 64) {
            bf16x8 v = *(const bf16x8*)&plane[(gr << 6) + xc * 8];
            bf16x4 lo = {v[0], v[1], v[2], v[3]};
            bf16x4 hi = {v[4], v[5], v[6], v[7]};
            *(bf16x4*)&ls[i][xc * 8 + 4] = lo;
            *(bf16x4*)&ls[i][xc * 8 + 8] = hi;
        }
    }
    __syncthreads();

    int yy = tid >> 3;
    int x0 = (tid & 7) * 8;
    const float sb = rsqrtf(1.f + EPSV);
    float fw = fftw[c];
    float bg = bnmg[c] * sb, bb2 = bnmb[c];
    float acc[8], ctr[8];
    #pragma unroll
    for (int j = 0; j < 8; ++j) acc[j] = 0.f;

    if (c < 64) {
        float w0 = dw1w[c], b0 = dw1b[c];
        uint4 ua = *(const uint4*)&ls[yy + 3][x0];
        uint4 ub = *(const uint4*)&ls[yy + 3][x0 + 8];
        float wv[16];
        unpack2(ua.x, wv[0], wv[1]); unpack2(ua.y, wv[2], wv[3]);
        unpack2(ua.z, wv[4], wv[5]); unpack2(ua.w, wv[6], wv[7]);
        unpack2(ub.x, wv[8], wv[9]); unpack2(ub.y, wv[10], wv[11]);
        unpack2(ub.z, wv[12], wv[13]); unpack2(ub.w, wv[14], wv[15]);
        #pragma unroll
        for (int j = 0; j < 8; ++j) { ctr[j] = wv[j + 4]; acc[j] = w0 * ctr[j] + b0; }
    } else if (c < 128) {
        int lc = c - 64;
        float b0 = dw3b[lc];
        #pragma unroll
        for (int j = 0; j < 8; ++j) acc[j] = b0;
        #pragma unroll
        for (int dy = 0; dy < 3; ++dy) {
            int i = yy + dy + 2;
            uint4 ua = *(const uint4*)&ls[i][x0];
            uint4 ub = *(const uint4*)&ls[i][x0 + 8];
            float wv[16];
            unpack2(ua.x, wv[0], wv[1]); unpack2(ua.y, wv[2], wv[3]);
            unpack2(ua.z, wv[4], wv[5]); unpack2(ua.w, wv[6], wv[7]);
            unpack2(ub.x, wv[8], wv[9]); unpack2(ub.y, wv[10], wv[11]);
            unpack2(ub.z, wv[12], wv[13]); unpack2(ub.w, wv[14], wv[15]);
            if (dy == 1) {
                #pragma unroll
                for (int j = 0; j < 8; ++j) ctr[j] = wv[j + 4];
            }
            #pragma unroll
            for (int dx = 0; dx < 3; ++dx) {
                float wt = dw3w[lc * 9 + dy * 3 + dx];
                #pragma unroll
                for (int j = 0; j < 8; ++j) acc[j] += wt * wv[j + dx + 3];
            }
        }
    } else if (c < 192) {
        int lc = c - 128;
        float b0 = dw5b[lc];
        #pragma unroll
        for (int j = 0; j < 8; ++j) acc[j] = b0;
        #pragma unroll
        for (int dy = 0; dy < 5; ++dy) {
            int i = yy + dy + 1;
            uint4 ua = *(const uint4*)&ls[i][x0];
            uint4 ub = *(const uint4*)&ls[i][x0 + 8];
            float wv[16];
            unpack2(ua.x, wv[0], wv[1]); unpack2(ua.y, wv[2], wv[3]);
            unpack2(ua.z, wv[4], wv[5]); unpack2(ua.w, wv[6], wv[7]);
            unpack2(ub.x, wv[8], wv[9]); unpack2(ub.y, wv[10], wv[11]);
            unpack2(ub.z, wv[12], wv[13]); unpack2(ub.w, wv[14], wv[15]);
            if (dy == 2) {
                #pragma unroll
                for (int j = 0; j < 8; ++j) ctr[j] = wv[j + 4];
            }
            #pragma unroll
            for (int dx = 0; dx < 5; ++dx) {
                float wt = dw5w[lc * 25 + dy * 5 + dx];
                #pragma unroll
                for (int j = 0; j < 8; ++j) acc[j] += wt * wv[j + dx + 2];
            }
        }
    } else {
        int lc = c - 192;
        float b0 = dw7b[lc];
        #pragma unroll
        for (int j = 0; j < 8; ++j) acc[j] = b0;
        #pragma unroll
        for (int dy = 0; dy < 7; ++dy) {
            int i = yy + dy;
            uint4 ua = *(const uint4*)&ls[i][x0];
            uint4 ub = *(const uint4*)&ls[i][x0 + 8];
            float wv[16];
            unpack2(ua.x, wv[0], wv[1]); unpack2(ua.y, wv[2], wv[3]);
            unpack2(ua.z, wv[4], wv[5]); unpack2(ua.w, wv[6], wv[7]);
            unpack2(ub.x, wv[8], wv[9]); unpack2(ub.y, wv[10], wv[11]);
            unpack2(ub.z, wv[12], wv[13]); unpack2(ub.w, wv[14], wv[15]);
            if (dy == 3) {
                #pragma unroll
                for (int j = 0; j < 8; ++j) ctr[j] = wv[j + 4];
            }
            #pragma unroll
            for (int dx = 0; dx < 7; ++dx) {
                float wt = dw7w[lc * 49 + dy * 7 + dx];
                #pragma unroll
                for (int j = 0; j < 8; ++j) acc[j] += wt * wv[j + dx + 1];
            }
        }
    }

    bf16x8 o;
    #pragma unroll
    for (int j = 0; j < 8; ++j) {
        float val = fw * acc[j] + ctr[j];
        o[j] = (short)f2bf(gelu_exact(val) * bg + bb2);
    }
    ushort* outp = h2 + (((size_t)b * HID + c) << 12);
    *(bf16x8*)&outp[((r0 + yy) << 6) + x0] = o;
}

// ---------------- fc2 MFMA: out = bn2(fc2w @ h2) + x2 ----------------
__global__ __launch_bounds__(256) void fc2_mfma(const ushort* __restrict__ h2,
                                                const ushort* __restrict__ fc2wb,
                                                const float* __restrict__ bn2g,
                                                const float* __restrict__ bn2b,
                                                const float* __restrict__ x2,
                                                float* __restrict__ out) {
    int b = blockIdx.y;
    int tok0 = blockIdx.x * 64;
    int tid = threadIdx.x;
    int w = tid >> 6;
    int lr = tid & 15;
    int lg = (tid & 63) >> 4;
    __shared__ ushort Xt[64][256];    // [tok][chan], chunk-swizzled (32 KB)
    for (int k = 0; k < 8; ++k) {
        int e = tid + k * 256;        // 2048 chunks of 8 toks
        int c = e >> 3, t8 = (e & 7) * 8;
        bf16x8 v = *(const bf16x8*)&h2[((size_t)(b * 256 + c)) * NN + tok0 + t8];
        #pragma unroll
        for (int j = 0; j < 8; ++j) {
            int t = t8 + j;
            Xt[t][((c >> 3) ^ (t & 7)) * 8 + (c & 7)] = (ushort)v[j];
        }
    }
    __syncthreads();
    int brow = w * 16 + lr;
    f32x4 acc[4];
    #pragma unroll
    for (int mt = 0; mt < 4; ++mt) acc[mt] = (f32x4){0.f, 0.f, 0.f, 0.f};
    #pragma unroll
    for (int ks = 0; ks < 8; ++ks) {
        bf16x8 bfr = *(const bf16x8*)&Xt[brow][(((ks * 4 + lg) & 7) ^ (lr & 7)) * 8 + ((ks * 4 + lg) & ~7) * 8];
        #pragma unroll
        for (int mt = 0; mt < 4; ++mt) {
            bf16x8 a = *(const bf16x8*)&fc2wb[(mt * 16 + lr) * 256 + ks * 32 + lg * 8];
            acc[mt] = MFMA16(a, bfr, acc[mt]);
        }
    }
    const float sb = rsqrtf(1.f + EPSV);
    int tok = tok0 + w * 16 + lr;
    #pragma unroll
    for (int mt = 0; mt < 4; ++mt) {
        #pragma unroll
        for (int r = 0; r < 4; ++r) {
            int o = mt * 16 + lg * 4 + r;
            size_t off = ((size_t)b * 64 + o) * NN + tok;
            out[off] = acc[mt][r] * bn2g[o] * sb + bn2b[o] + x2[off];
        }
    }
}

extern "C" void kernel_launch(void* const* d_in, const int* in_sizes, int n_in,
                              void* d_out, int out_size, void* d_ws, size_t ws_size,
                              hipStream_t stream) {
    const float* x    = (const float*)d_in[0];
    const float* cnn  = (const float*)d_in[1];
    const float* n1g  = (const float*)d_in[2];
    const float* n1b  = (const float*)d_in[3];
    const float* n2g  = (const float*)d_in[4];
    const float* n2b  = (const float*)d_in[5];
    const float* n3g  = (const float*)d_in[6];
    const float* n3b  = (const float*)d_in[7];
    const float* qw   = (const float*)d_in[8];
    const float* qb   = (const float*)d_in[9];
    const float* kvw  = (const float*)d_in[10];
    const float* kvb  = (const float*)d_in[11];
    const float* lcw  = (const float*)d_in[12];
    const float* lcb  = (const float*)d_in[13];
    const float* fc1w = (const float*)d_in[14];
    const float* bn1g = (const float*)d_in[15];
    const float* bn1b = (const float*)d_in[16];
    const float* dw1w = (const float*)d_in[17];
    const float* dw1b = (const float*)d_in[18];
    const float* dw3w = (const float*)d_in[19];
    const float* dw3b = (const float*)d_in[20];
    const float* dw5w = (const float*)d_in[21];
    const float* dw5b = (const float*)d_in[22];
    const float* dw7w = (const float*)d_in[23];
    const float* dw7b = (const float*)d_in[24];
    const float* bnmg = (const float*)d_in[25];
    const float* bnmb = (const float*)d_in[26];
    const float* fftw = (const float*)d_in[27];
    const float* fc2w = (const float*)d_in[28];
    const float* bn2g = (const float*)d_in[29];
    const float* bn2b = (const float*)d_in[30];

    float* ws = (float*)d_ws;
    float* stats = ws;                     // 64
    float* part  = ws + 64;                // 1024
    float* part2 = ws + 1088;              // 2048
    float* base  = ws + 3200;
    const size_t M = 1048576;
    float* x2     = base;                              // [0, 1M)
    ushort* qr_bf = (ushort*)(base + M);               // [1M, 1.5M)
    ushort* kr_bf = (ushort*)(base + M + M / 2);       // [1.5M, 2M)
    ushort* vt_bf = (ushort*)(base + 2 * M);           // [2M, 2.5M)
    float* kvin   = base + 5 * M / 2;                  // [2.5M, 3.5M)
    ushort* Opart = (ushort*)(base + 7 * M / 2);       // [3.5M, 7.5M)
    float* ml     = base + 15 * M / 2;                 // [7.5M, 7.75M)
    ushort* h1 = (ushort*)(base + M);                  // overlay qr/kr/vt/kvin (dead post-attn)
    ushort* h2 = (ushort*)(base + 7 * M / 2);          // overlay Opart head (dead post-combine)
    ushort* fc1wb = (ushort*)(base + 8 * M);           // 16384 ushorts
    ushort* fc2wb = fc1wb + 16384;
    ushort* qwb   = fc2wb + 16384;                     // 4096
    ushort* kvwb  = qwb + 4096;                        // 8192
    float* outp = (float*)d_out;

    wprep_kernel<<<176, 256, 0, stream>>>(fc1w, fc2w, qw, kvw, fc1wb, fc2wb, qwb, kvwb);
    stats_pair_kernel<<<dim3(64, 4), 256, 0, stream>>>(x, cnn, part);
    stats_fin_kernel<<<8, 64, 0, stream>>>(part, stats);
    dw3k_kernel<<<4096, 256, 0, stream>>>(cnn, n3g, n3b, lcw, lcb, stats, kvin);
    q_mfma<<<dim3(64, 4), 256, 0, stream>>>(x, n1g, n1b, qwb, qb, stats, qr_bf);
    kv_mfma<<<dim3(64, 4), 256, 0, stream>>>(kvin, kvwb, kvb, kr_bf, vt_bf);
    attn_kernel<<<dim3(64, 4, NCH), 256, 0, stream>>>(qr_bf, kr_bf, vt_bf, Opart, ml);
    combine_kernel<<<1024, 256, 0, stream>>>(Opart, ml, x, x2, part2);
    stats2b_kernel<<<4, 256, 0, stream>>>(part2, stats, 2);
    fc1_mfma<<<dim3(128, 4), 256, 0, stream>>>(x2, fc1wb, n2g, n2b, bn1g, bn1b, stats, h1);
    mixer_kernel<<<dim3(512, 4), 256, 0, stream>>>(h1, dw1w, dw1b, dw3w, dw3b, dw5w, dw5b,
                                                   dw7w, dw7b, fftw, bnmg, bnmb, h2);
    fc2_mfma<<<dim3(64, 4), 256, 0, stream>>>(h2, fc2wb, bn2g, bn2b, x2, outp);
}

// Round 15
// 114.726 us; speedup vs baseline: 1.1467x; 1.0525x over previous
//
#include <hip/hip_runtime.h>
#include <hip/hip_bf16.h>
#include <math.h>

#define BB 4
#define CC 64
#define NN 4096
#define HD 64
#define HID 256
#define EPSV 1e-5f
#define CNT (CC*NN)
#define NCH 8            // KV split chunks

typedef float f32x4 __attribute__((ext_vector_type(4)));
typedef short bf16x8 __attribute__((ext_vector_type(8)));
typedef short bf16x4 __attribute__((ext_vector_type(4)));
#define MFMA16(a, b, c) __builtin_amdgcn_mfma_f32_16x16x32_bf16(a, b, c, 0, 0, 0)

__device__ __forceinline__ float gelu_exact(float x) {
    return 0.5f * x * (1.0f + erff(x * 0.70710678118654752f));
}
__device__ __forceinline__ ushort f2bf(float f) {
    unsigned u = __float_as_uint(f);
    unsigned r = (u + 0x7FFFu + ((u >> 16) & 1u)) >> 16;
    return (ushort)r;
}
__device__ __forceinline__ float bf2f(ushort u) {
    return __uint_as_float(((unsigned)u) << 16);
}
__device__ __forceinline__ unsigned cvtpk(float lo, float hi) {
    unsigned r;
    asm("v_cvt_pk_bf16_f32 %0, %1, %2" : "=v"(r) : "v"(lo), "v"(hi));
    return r;
}
__device__ __forceinline__ void unpack2(unsigned u, float& lo, float& hi) {
    lo = __uint_as_float(u << 16);
    hi = __uint_as_float(u & 0xffff0000u);
}

// ---------------- weight prep: fp32 -> bf16 (fc1, fc2, qw, kvw) ----------------
__global__ __launch_bounds__(256) void wprep_kernel(const float* __restrict__ fc1w,
                                                    const float* __restrict__ fc2w,
                                                    const float* __restrict__ qw,
                                                    const float* __restrict__ kvw,
                                                    ushort* __restrict__ fc1wb,
                                                    ushort* __restrict__ fc2wb,
                                                    ushort* __restrict__ qwb,
                                                    ushort* __restrict__ kvwb) {
    int i = blockIdx.x * 256 + threadIdx.x;   // 45056
    if (i < 16384) fc1wb[i] = f2bf(fc1w[i]);
    else if (i < 32768) fc2wb[i - 16384] = f2bf(fc2w[i - 16384]);
    else if (i < 36864) qwb[i - 32768] = f2bf(qw[i - 32768]);
    else if (i < 45056) kvwb[i - 36864] = f2bf(kvw[i - 36864]);
}

// ---------------- fused stats stage 1 for x and cnn ----------------
__global__ __launch_bounds__(256) void stats_pair_kernel(const float* __restrict__ x,
                                                         const float* __restrict__ cnn,
                                                         float* __restrict__ part) {
    int b = blockIdx.y;
    int blk = blockIdx.x;
    const float4* p0 = (const float4*)(x + (size_t)b * CNT);
    const float4* p1 = (const float4*)(cnn + (size_t)b * CNT);
    float s0 = 0.f, s20 = 0.f, s1 = 0.f, s21 = 0.f;
    #pragma unroll
    for (int k = 0; k < 4; ++k) {
        float4 v = p0[blk * 1024 + k * 256 + threadIdx.x];
        s0  += v.x + v.y + v.z + v.w;
        s20 += v.x * v.x + v.y * v.y + v.z * v.z + v.w * v.w;
        float4 u = p1[blk * 1024 + k * 256 + threadIdx.x];
        s1  += u.x + u.y + u.z + u.w;
        s21 += u.x * u.x + u.y * u.y + u.z * u.z + u.w * u.w;
    }
    #pragma unroll
    for (int off = 32; off > 0; off >>= 1) {
        s0  += __shfl_xor(s0, off);
        s20 += __shfl_xor(s20, off);
        s1  += __shfl_xor(s1, off);
        s21 += __shfl_xor(s21, off);
    }
    __shared__ float sh[4][4];
    int wid = threadIdx.x >> 6, lane = threadIdx.x & 63;
    if (lane == 0) { sh[wid][0] = s0; sh[wid][1] = s20; sh[wid][2] = s1; sh[wid][3] = s21; }
    __syncthreads();
    if (threadIdx.x == 0) {
        float a0 = sh[0][0] + sh[1][0] + sh[2][0] + sh[3][0];
        float a1 = sh[0][1] + sh[1][1] + sh[2][1] + sh[3][1];
        float a2 = sh[0][2] + sh[1][2] + sh[2][2] + sh[3][2];
        float a3 = sh[0][3] + sh[1][3] + sh[2][3] + sh[3][3];
        part[((0 * 4 + b) * 64 + blk) * 2]     = a0;
        part[((0 * 4 + b) * 64 + blk) * 2 + 1] = a1;
        part[((1 * 4 + b) * 64 + blk) * 2]     = a2;
        part[((1 * 4 + b) * 64 + blk) * 2 + 1] = a3;
    }
}

// ---------------- stats finalize (both slots) ----------------
__global__ __launch_bounds__(64) void stats_fin_kernel(const float* __restrict__ part,
                                                       float* __restrict__ stats) {
    int sb_ = blockIdx.x;    // slot*4 + b
    int lane = threadIdx.x;
    float s = part[(sb_ * 64 + lane) * 2];
    float s2 = part[(sb_ * 64 + lane) * 2 + 1];
    #pragma unroll
    for (int off = 32; off > 0; off >>= 1) {
        s  += __shfl_xor(s, off);
        s2 += __shfl_xor(s2, off);
    }
    if (lane == 0) {
        int slot = sb_ >> 2, b = sb_ & 3;
        float mu = s / (float)CNT;
        float var = s2 / (float)CNT - mu * mu;
        stats[slot * 8 + b] = mu;
        stats[slot * 8 + 4 + b] = rsqrtf(var + EPSV);
    }
}

// ---------------- stats stage 2b (256 partials, slot 2) ----------------
__global__ __launch_bounds__(256) void stats2b_kernel(const float* __restrict__ part2,
                                                      float* __restrict__ stats, int slot) {
    int b = blockIdx.x;
    int t = threadIdx.x;
    float s = part2[(b * 256 + t) * 2];
    float s2 = part2[(b * 256 + t) * 2 + 1];
    #pragma unroll
    for (int off = 32; off > 0; off >>= 1) {
        s  += __shfl_xor(s, off);
        s2 += __shfl_xor(s2, off);
    }
    __shared__ float shs[4], shs2[4];
    int wid = t >> 6, lane = t & 63;
    if (lane == 0) { shs[wid] = s; shs2[wid] = s2; }
    __syncthreads();
    if (t == 0) {
        float S = shs[0] + shs[1] + shs[2] + shs[3];
        float S2 = shs2[0] + shs2[1] + shs2[2] + shs2[3];
        float mu = S / (float)CNT;
        float var = S2 / (float)CNT - mu * mu;
        stats[slot * 8 + b] = mu;
        stats[slot * 8 + 4 + b] = rsqrtf(var + EPSV);
    }
}

// ---------------- dw3k: kvin = dw3(gn(cnn)) + bias + gn(cnn) ----------------
__global__ __launch_bounds__(256) void dw3k_kernel(const float* __restrict__ cnn,
                                                   const float* __restrict__ n3g,
                                                   const float* __restrict__ n3b,
                                                   const float* __restrict__ lcw,
                                                   const float* __restrict__ lcb,
                                                   const float* __restrict__ stats,
                                                   float* __restrict__ kvin) {
    int i = blockIdx.x * 256 + threadIdx.x;   // 1,048,576
    int x = i & 63;
    int y = (i >> 6) & 63;
    int c = (i >> 12) & 63;
    int b = i >> 18;
    float mu = stats[1 * 8 + b];
    float rs = stats[1 * 8 + 4 + b];
    float sc = rs * n3g[c];
    float of = n3b[c] - mu * sc;
    const float* plane = cnn + ((size_t)(i >> 12) << 12);
    float acc = lcb[c];
    #pragma unroll
    for (int dy = 0; dy < 3; ++dy) {
        int yy = y + dy - 1;
        if (yy < 0 || yy >= 64) continue;
        #pragma unroll
        for (int dx = 0; dx < 3; ++dx) {
            int xx = x + dx - 1;
            if (xx < 0 || xx >= 64) continue;
            acc += lcw[c * 9 + dy * 3 + dx] * (plane[(yy << 6) + xx] * sc + of);
        }
    }
    kvin[i] = acc + plane[(y << 6) + x] * sc + of;
}

// ---------------- Q MFMA: gn(x) -> proj -> bias+RoPE -> scaled bf16 (B,N,HD) ----------------
// Output pre-scaled by SCL2 = HD^-0.5 * log2(e) so attn softmax works in base-2 units.
__global__ __launch_bounds__(256) void q_mfma(const float* __restrict__ x,
                                              const float* __restrict__ n1g,
                                              const float* __restrict__ n1b,
                                              const ushort* __restrict__ qwb,
                                              const float* __restrict__ qb,
                                              const float* __restrict__ stats,
                                              ushort* __restrict__ qr) {
    const float SCL2 = 0.125f * 1.44269504f;
    int b = blockIdx.y;
    int tok0 = blockIdx.x * 64;
    int tid = threadIdx.x;
    int w = tid >> 6;
    int lr = tid & 15;
    int lg = (tid & 63) >> 4;
    float mu = stats[0 * 8 + b];
    float rs = stats[0 * 8 + 4 + b];
    __shared__ ushort Xt[64][64];     // [tok][chan], chunk-swizzled
    for (int k = 0; k < 16; ++k) {
        int e = tid + k * 256;
        int c = e >> 6, t = e & 63;
        float v = (x[((size_t)(b * 64 + c)) * NN + tok0 + t] - mu) * rs * n1g[c] + n1b[c];
        Xt[t][((c >> 3) ^ (t & 7)) * 8 + (c & 7)] = f2bf(v);
    }
    __syncthreads();
    int brow = w * 16 + lr;
    bf16x8 bf0 = *(const bf16x8*)&Xt[brow][((0 + lg) ^ (lr & 7)) * 8];
    bf16x8 bf1 = *(const bf16x8*)&Xt[brow][((4 + lg) ^ (lr & 7)) * 8];
    f32x4 acc[4];
    #pragma unroll
    for (int mt = 0; mt < 4; ++mt) acc[mt] = (f32x4){0.f, 0.f, 0.f, 0.f};
    #pragma unroll
    for (int mt = 0; mt < 4; ++mt) {
        bf16x8 a0 = *(const bf16x8*)&qwb[(mt * 16 + lr) * 64 + lg * 8];
        bf16x8 a1 = *(const bf16x8*)&qwb[(mt * 16 + lr) * 64 + 32 + lg * 8];
        acc[mt] = MFMA16(a0, bf0, acc[mt]);
        acc[mt] = MFMA16(a1, bf1, acc[mt]);
    }
    int tok = tok0 + w * 16 + lr;
    int hh = tok >> 6, ww2 = tok & 63;
    ushort* qrow = qr + ((size_t)b * NN + tok) * 64;
    #pragma unroll
    for (int mt = 0; mt < 4; ++mt) {
        #pragma unroll
        for (int pr = 0; pr < 2; ++pr) {
            int o = mt * 16 + lg * 4 + pr * 2;
            float a0 = acc[mt][pr * 2]     + qb[o];
            float a1 = acc[mt][pr * 2 + 1] + qb[o + 1];
            int j = (o & 31) >> 1;
            float freq = exp2f(-0.88584749f * (float)j);
            float pos = (o < 32) ? (float)hh : (float)ww2;
            float st, ct;
            __sincosf(pos * freq, &st, &ct);
            qrow[o]     = f2bf((a0 * ct - a1 * st) * SCL2);
            qrow[o + 1] = f2bf((a1 * ct + a0 * st) * SCL2);
        }
    }
}

// ---------------- KV MFMA: kvin -> proj; K+RoPE (B,N,HD); V^T key-permuted (B,HD,N) ----------------
__global__ __launch_bounds__(256) void kv_mfma(const float* __restrict__ kvin,
                                               const ushort* __restrict__ kvwb,
                                               const float* __restrict__ kvb,
                                               ushort* __restrict__ kr,
                                               ushort* __restrict__ vt) {
    int b = blockIdx.y;
    int tok0 = blockIdx.x * 64;
    int tid = threadIdx.x;
    int w = tid >> 6;
    int lr = tid & 15;
    int lg = (tid & 63) >> 4;
    __shared__ ushort Xt[64][64];
    for (int k = 0; k < 16; ++k) {
        int e = tid + k * 256;
        int c = e >> 6, t = e & 63;
        Xt[t][((c >> 3) ^ (t & 7)) * 8 + (c & 7)] =
            f2bf(kvin[((size_t)(b * 64 + c)) * NN + tok0 + t]);
    }
    __syncthreads();
    int brow = w * 16 + lr;
    bf16x8 bf0 = *(const bf16x8*)&Xt[brow][((0 + lg) ^ (lr & 7)) * 8];
    bf16x8 bf1 = *(const bf16x8*)&Xt[brow][((4 + lg) ^ (lr & 7)) * 8];
    f32x4 acc[8];
    #pragma unroll
    for (int mt = 0; mt < 8; ++mt) acc[mt] = (f32x4){0.f, 0.f, 0.f, 0.f};
    #pragma unroll
    for (int mt = 0; mt < 8; ++mt) {
        bf16x8 a0 = *(const bf16x8*)&kvwb[(mt * 16 + lr) * 64 + lg * 8];
        bf16x8 a1 = *(const bf16x8*)&kvwb[(mt * 16 + lr) * 64 + 32 + lg * 8];
        acc[mt] = MFMA16(a0, bf0, acc[mt]);
        acc[mt] = MFMA16(a1, bf1, acc[mt]);
    }
    int tl = w * 16 + lr;                 // token-in-block
    int tok = tok0 + tl;
    int hh = tok >> 6, ww2 = tok & 63;
    int permk = (lr >> 2) * 16 + w * 4 + (lr & 3);   // perm(tl) for V key order
    ushort* krow = kr + ((size_t)b * NN + tok) * 64;
    #pragma unroll
    for (int mt = 0; mt < 4; ++mt) {      // K half, with RoPE
        #pragma unroll
        for (int pr = 0; pr < 2; ++pr) {
            int o = mt * 16 + lg * 4 + pr * 2;
            float a0 = acc[mt][pr * 2]     + kvb[o];
            float a1 = acc[mt][pr * 2 + 1] + kvb[o + 1];
            int j = (o & 31) >> 1;
            float freq = exp2f(-0.88584749f * (float)j);
            float pos = (o < 32) ? (float)hh : (float)ww2;
            float st, ct;
            __sincosf(pos * freq, &st, &ct);
            krow[o]     = f2bf(a0 * ct - a1 * st);
            krow[o + 1] = f2bf(a1 * ct + a0 * st);
        }
    }
    #pragma unroll
    for (int mt = 4; mt < 8; ++mt) {      // V half, key-permuted transpose store
        #pragma unroll
        for (int r = 0; r < 4; ++r) {
            int o = mt * 16 + lg * 4 + r;          // [64,128)
            float a0 = acc[mt][r] + kvb[o];
            vt[((size_t)b * 64 + (o - 64)) * NN + tok0 + permk] = f2bf(a0);
        }
    }
}

// ---------------- MFMA flash attention v4.2: hoisted staging, max3, setprio ----------------
// grid dim3(64, B, NCH), 256 thr = 4 waves x 16 q-rows; KV tile 64; chunk = 512 keys
__global__ __launch_bounds__(256) void attn_kernel(const ushort* __restrict__ qr,
                                                   const ushort* __restrict__ kr,
                                                   const ushort* __restrict__ vt,
                                                   ushort* __restrict__ Opart,
                                                   float* __restrict__ ml) {
    int b = blockIdx.y;
    int q0 = blockIdx.x * 64;
    int chunk = blockIdx.z;
    int tid = threadIdx.x;
    int w = tid >> 6;
    int lane = tid & 63;
    int lr = lane & 15;
    int lg = lane >> 4;

    __shared__ ushort Kl[64 * 64];
    __shared__ ushort Vl[64 * 64];

    bf16x8 qf[2];
    {
        const ushort* qp = qr + ((size_t)b * NN + q0 + w * 16 + lr) * 64;
        qf[0] = *(const bf16x8*)(qp + lg * 8);
        qf[1] = *(const bf16x8*)(qp + 32 + lg * 8);
    }

    f32x4 oacc[4];
    #pragma unroll
    for (int t = 0; t < 4; ++t) oacc[t] = (f32x4){0.f, 0.f, 0.f, 0.f};
    float m_ = -INFINITY, l_ = 0.f;     // base-2 scalar state for q-row = q0+w*16+lr

    const int t0 = chunk * 8;
    // hoisted staging coords (loop-invariant; pointers advance by constant stride)
    const int srow0 = tid >> 3;          // 0..31
    const int srow1 = srow0 + 32;        // 32..63
    const int scib = tid & 7;
    const int kd0 = srow0 * 64 + (scib ^ (srow0 & 7)) * 8;
    const int kd1 = srow1 * 64 + (scib ^ (srow1 & 7)) * 8;
    const ushort* kp0 = kr + ((size_t)b * NN + t0 * 64 + srow0) * 64 + scib * 8;
    const ushort* kp1 = kr + ((size_t)b * NN + t0 * 64 + srow1) * 64 + scib * 8;
    const ushort* vp0 = vt + ((size_t)b * 64 + srow0) * NN + t0 * 64 + scib * 8;
    const ushort* vp1 = vt + ((size_t)b * 64 + srow1) * NN + t0 * 64 + scib * 8;
    const int rs7 = lr & 7;

    for (int t = 0; t < 8; ++t) {
        __syncthreads();
        *(bf16x8*)(Kl + kd0) = *(const bf16x8*)kp0;
        *(bf16x8*)(Kl + kd1) = *(const bf16x8*)kp1;
        *(bf16x8*)(Vl + kd0) = *(const bf16x8*)vp0;
        *(bf16x8*)(Vl + kd1) = *(const bf16x8*)vp1;
        kp0 += 4096; kp1 += 4096; vp0 += 64; vp1 += 64;
        __syncthreads();

        // S^T = K Q : lane holds q=lr, keys kt*16 + lg*4 + r   (already base-2 scaled)
        f32x4 sacc[4];
        __builtin_amdgcn_s_setprio(1);
        #pragma unroll
        for (int kt = 0; kt < 4; ++kt) {
            int row = kt * 16 + lr;
            bf16x8 k0f = *(const bf16x8*)(Kl + row * 64 + ((0 * 4 + lg) ^ rs7) * 8);
            bf16x8 k1f = *(const bf16x8*)(Kl + row * 64 + ((1 * 4 + lg) ^ rs7) * 8);
            f32x4 z = {0.f, 0.f, 0.f, 0.f};
            z = MFMA16(k0f, qf[0], z);
            sacc[kt] = MFMA16(k1f, qf[1], z);
        }
        __builtin_amdgcn_s_setprio(0);

        // row max via max3 triples (8 ops) then 2 shfl
        float m0 = fmaxf(fmaxf(sacc[0][0], sacc[0][1]), sacc[0][2]);
        float m1 = fmaxf(fmaxf(sacc[0][3], sacc[1][0]), sacc[1][1]);
        float m2 = fmaxf(fmaxf(sacc[1][2], sacc[1][3]), sacc[2][0]);
        float m3 = fmaxf(fmaxf(sacc[2][1], sacc[2][2]), sacc[2][3]);
        float m4 = fmaxf(fmaxf(sacc[3][0], sacc[3][1]), sacc[3][2]);
        float n0v = fmaxf(fmaxf(m0, m1), m2);
        float n1v = fmaxf(fmaxf(m3, m4), sacc[3][3]);
        float vmax = fmaxf(n0v, n1v);
        vmax = fmaxf(vmax, __shfl_xor(vmax, 16));
        vmax = fmaxf(vmax, __shfl_xor(vmax, 32));
        if (__any(vmax - m_ > 8.f)) {          // defer-max
            float mn = fmaxf(m_, vmax);
            float cr = exp2f(m_ - mn);
            l_ *= cr;
            m_ = mn;
            float crq[4];
            #pragma unroll
            for (int r = 0; r < 4; ++r) crq[r] = __shfl(cr, lg * 4 + r);
            #pragma unroll
            for (int ht = 0; ht < 4; ++ht)
                #pragma unroll
                for (int r = 0; r < 4; ++r) oacc[ht][r] *= crq[r];
        }

        unsigned u[8];
        float lsum = 0.f;
        #pragma unroll
        for (int kt = 0; kt < 4; ++kt) {
            float p0 = exp2f(sacc[kt][0] - m_);
            float p1 = exp2f(sacc[kt][1] - m_);
            float p2 = exp2f(sacc[kt][2] - m_);
            float p3 = exp2f(sacc[kt][3] - m_);
            lsum += (p0 + p1) + (p2 + p3);
            u[kt * 2]     = cvtpk(p0, p1);
            u[kt * 2 + 1] = cvtpk(p2, p3);
        }
        lsum += __shfl_xor(lsum, 16);
        lsum += __shfl_xor(lsum, 32);
        l_ += lsum;

        uint4 t0v = {u[0], u[1], u[2], u[3]};   // keys {lg*4+r, 16+lg*4+r}
        uint4 t1v = {u[4], u[5], u[6], u[7]};   // keys {32+lg*4+r, 48+lg*4+r}
        bf16x8 pa0 = __builtin_bit_cast(bf16x8, t0v);
        bf16x8 pa1 = __builtin_bit_cast(bf16x8, t1v);
        // PV: V stored key-permuted so lane's keys are contiguous chunks lg*2, lg*2+1
        __builtin_amdgcn_s_setprio(1);
        #pragma unroll
        for (int ht = 0; ht < 4; ++ht) {
            int row = ht * 16 + lr;
            bf16x8 vf0 = *(const bf16x8*)(Vl + row * 64 + ((lg * 2) ^ rs7) * 8);
            bf16x8 vf1 = *(const bf16x8*)(Vl + row * 64 + ((lg * 2 + 1) ^ rs7) * 8);
            oacc[ht] = MFMA16(pa0, vf0, oacc[ht]);
            oacc[ht] = MFMA16(pa1, vf1, oacc[ht]);
        }
        __builtin_amdgcn_s_setprio(0);
    }

    int n0 = q0 + w * 16 + lg * 4;
    #pragma unroll
    for (int ht = 0; ht < 4; ++ht) {
        int hd = ht * 16 + lr;
        ushort4 o4;
        o4.x = f2bf(oacc[ht][0]);
        o4.y = f2bf(oacc[ht][1]);
        o4.z = f2bf(oacc[ht][2]);
        o4.w = f2bf(oacc[ht][3]);
        *(ushort4*)&Opart[(((size_t)chunk * BB + b) * 64 + hd) * NN + n0] = o4;
    }
    if (lg == 0) {
        int n = q0 + w * 16 + lr;
        ml[((size_t)b * NN + n) * 16 + chunk * 2]     = m_;
        ml[((size_t)b * NN + n) * 16 + chunk * 2 + 1] = l_;
    }
}

// ---------------- combine: x2 = sum_c O_c*w_c + x; fused stats partials ----------------
__global__ __launch_bounds__(256) void combine_kernel(const ushort* __restrict__ Opart,
                                                      const float* __restrict__ ml,
                                                      const float* __restrict__ x,
                                                      float* __restrict__ x2,
                                                      float* __restrict__ part2) {
    int i = blockIdx.x * 256 + threadIdx.x;   // 262144
    int n4 = i & 1023;
    int hd = (i >> 10) & 63;
    int b = i >> 16;
    int n0 = n4 << 2;
    float wgt[4][NCH];
    const float* mlp = ml + ((size_t)b * NN + n0) * 16;
    #pragma unroll
    for (int tk = 0; tk < 4; ++tk) {
        float m[NCH], l[NCH];
        const float4* p4 = (const float4*)(mlp + tk * 16);
        #pragma unroll
        for (int q = 0; q < 4; ++q) {
            float4 v = p4[q];
            m[q * 2] = v.x; l[q * 2] = v.y; m[q * 2 + 1] = v.z; l[q * 2 + 1] = v.w;
        }
        float M = m[0];
        #pragma unroll
        for (int c = 1; c < NCH; ++c) M = fmaxf(M, m[c]);
        float e[NCH], L = 0.f;
        #pragma unroll
        for (int c = 0; c < NCH; ++c) { e[c] = exp2f(m[c] - M); L += l[c] * e[c]; }
        float inv = 1.f / L;
        #pragma unroll
        for (int c = 0; c < NCH; ++c) wgt[tk][c] = e[c] * inv;
    }
    float4 acc = {0.f, 0.f, 0.f, 0.f};
    #pragma unroll
    for (int c = 0; c < NCH; ++c) {
        ushort4 o4 = *(const ushort4*)&Opart[(((size_t)c * BB + b) * 64 + hd) * NN + n0];
        acc.x += bf2f(o4.x) * wgt[0][c];
        acc.y += bf2f(o4.y) * wgt[1][c];
        acc.z += bf2f(o4.z) * wgt[2][c];
        acc.w += bf2f(o4.w) * wgt[3][c];
    }
    size_t off = ((size_t)b * 64 + hd) * NN + n0;
    float4 xv = *(const float4*)&x[off];
    acc.x += xv.x; acc.y += xv.y; acc.z += xv.z; acc.w += xv.w;
    *(float4*)&x2[off] = acc;

    float s = acc.x + acc.y + acc.z + acc.w;
    float s2 = acc.x * acc.x + acc.y * acc.y + acc.z * acc.z + acc.w * acc.w;
    #pragma unroll
    for (int off2 = 32; off2 > 0; off2 >>= 1) {
        s  += __shfl_xor(s, off2);
        s2 += __shfl_xor(s2, off2);
    }
    __shared__ float shs[4], shs2[4];
    int wid = threadIdx.x >> 6, lane = threadIdx.x & 63;
    if (lane == 0) { shs[wid] = s; shs2[wid] = s2; }
    __syncthreads();
    if (threadIdx.x == 0) {
        part2[blockIdx.x * 2]     = shs[0] + shs[1] + shs[2] + shs[3];
        part2[blockIdx.x * 2 + 1] = shs2[0] + shs2[1] + shs2[2] + shs2[3];
    }
}

// ---------------- fc1 MFMA: h1 = gelu(bn1(fc1w @ gn2(x2))) -> bf16 ----------------
__global__ __launch_bounds__(256) void fc1_mfma(const float* __restrict__ x2,
                                                const ushort* __restrict__ fc1wb,
                                                const float* __restrict__ n2g,
                                                const float* __restrict__ n2b,
                                                const float* __restrict__ bn1g,
                                                const float* __restrict__ bn1b,
                                                const float* __restrict__ stats,
                                                ushort* __restrict__ h1) {
    int b = blockIdx.y;
    int tok0 = (blockIdx.x >> 1) * 64;
    int half = blockIdx.x & 1;
    int tid = threadIdx.x;
    int w = tid >> 6;
    int lr = tid & 15;
    int lg = (tid & 63) >> 4;
    float mu = stats[2 * 8 + b];
    float rs = stats[2 * 8 + 4 + b];
    __shared__ ushort Xt[64][64];     // [tok][chan], chunk-swizzled
    for (int k = 0; k < 16; ++k) {
        int e = tid + k * 256;
        int c = e >> 6, t = e & 63;
        float v = (x2[((size_t)(b * 64 + c)) * NN + tok0 + t] - mu) * rs * n2g[c] + n2b[c];
        Xt[t][((c >> 3) ^ (t & 7)) * 8 + (c & 7)] = f2bf(v);
    }
    __syncthreads();
    int brow = w * 16 + lr;
    bf16x8 bf0 = *(const bf16x8*)&Xt[brow][((0 + lg) ^ (lr & 7)) * 8];
    bf16x8 bf1 = *(const bf16x8*)&Xt[brow][((4 + lg) ^ (lr & 7)) * 8];
    f32x4 acc[8];
    #pragma unroll
    for (int mt = 0; mt < 8; ++mt) acc[mt] = (f32x4){0.f, 0.f, 0.f, 0.f};
    const ushort* wb = fc1wb + (size_t)(half * 128) * 64;
    #pragma unroll
    for (int mt = 0; mt < 8; ++mt) {
        bf16x8 a0 = *(const bf16x8*)&wb[(mt * 16 + lr) * 64 + lg * 8];
        bf16x8 a1 = *(const bf16x8*)&wb[(mt * 16 + lr) * 64 + 32 + lg * 8];
        acc[mt] = MFMA16(a0, bf0, acc[mt]);
        acc[mt] = MFMA16(a1, bf1, acc[mt]);
    }
    const float sb = rsqrtf(1.f + EPSV);
    int tok = tok0 + w * 16 + lr;
    #pragma unroll
    for (int mt = 0; mt < 8; ++mt) {
        #pragma unroll
        for (int r = 0; r < 4; ++r) {
            int o = half * 128 + mt * 16 + lg * 4 + r;
            float vv = acc[mt][r] * bn1g[o] * sb + bn1b[o];
            h1[((size_t)b * HID + o) * NN + tok] = f2bf(gelu_exact(vv));
        }
    }
}

// ---------------- mixer v2: register sliding-window; 32-row half planes ----------------
__global__ __launch_bounds__(256) void mixer_kernel(const ushort* __restrict__ h1,
                                                    const float* __restrict__ dw1w, const float* __restrict__ dw1b,
                                                    const float* __restrict__ dw3w, const float* __restrict__ dw3b,
                                                    const float* __restrict__ dw5w, const float* __restrict__ dw5b,
                                                    const float* __restrict__ dw7w, const float* __restrict__ dw7b,
                                                    const float* __restrict__ fftw,
                                                    const float* __restrict__ bnmg, const float* __restrict__ bnmb,
                                                    ushort* __restrict__ h2) {
    int c = blockIdx.x >> 1;
    int r0 = (blockIdx.x & 1) * 32;
    int b = blockIdx.y;
    int tid = threadIdx.x;
    __shared__ ushort ls[38][80];      // 6080 B
    uint* lz = (uint*)&ls[0][0];
    #pragma unroll
    for (int k = 0; k < 6; ++k) {
        int i = tid + k * 256;
        if (i < 1520) lz[i] = 0;
    }
    __syncthreads();
    const ushort* plane = h1 + (((size_t)b * HID + c) << 12);
    for (int e = tid; e < 304; e += 256) {
        int i = e >> 3, xc = e & 7;
        int gr = r0 + i - 3;
        if (gr >= 0 && gr < 64) {
            bf16x8 v = *(const bf16x8*)&plane[(gr << 6) + xc * 8];
            bf16x4 lo = {v[0], v[1], v[2], v[3]};
            bf16x4 hi = {v[4], v[5], v[6], v[7]};
            *(bf16x4*)&ls[i][xc * 8 + 4] = lo;
            *(bf16x4*)&ls[i][xc * 8 + 8] = hi;
        }
    }
    __syncthreads();

    int yy = tid >> 3;
    int x0 = (tid & 7) * 8;
    const float sb = rsqrtf(1.f + EPSV);
    float fw = fftw[c];
    float bg = bnmg[c] * sb, bb2 = bnmb[c];
    float acc[8], ctr[8];
    #pragma unroll
    for (int j = 0; j < 8; ++j) acc[j] = 0.f;

    if (c < 64) {
        float w0 = dw1w[c], b0 = dw1b[c];
        uint4 ua = *(const uint4*)&ls[yy + 3][x0];
        uint4 ub = *(const uint4*)&ls[yy + 3][x0 + 8];
        float wv[16];
        unpack2(ua.x, wv[0], wv[1]); unpack2(ua.y, wv[2], wv[3]);
        unpack2(ua.z, wv[4], wv[5]); unpack2(ua.w, wv[6], wv[7]);
        unpack2(ub.x, wv[8], wv[9]); unpack2(ub.y, wv[10], wv[11]);
        unpack2(ub.z, wv[12], wv[13]); unpack2(ub.w, wv[14], wv[15]);
        #pragma unroll
        for (int j = 0; j < 8; ++j) { ctr[j] = wv[j + 4]; acc[j] = w0 * ctr[j] + b0; }
    } else if (c < 128) {
        int lc = c - 64;
        float b0 = dw3b[lc];
        #pragma unroll
        for (int j = 0; j < 8; ++j) acc[j] = b0;
        #pragma unroll
        for (int dy = 0; dy < 3; ++dy) {
            int i = yy + dy + 2;
            uint4 ua = *(const uint4*)&ls[i][x0];
            uint4 ub = *(const uint4*)&ls[i][x0 + 8];
            float wv[16];
            unpack2(ua.x, wv[0], wv[1]); unpack2(ua.y, wv[2], wv[3]);
            unpack2(ua.z, wv[4], wv[5]); unpack2(ua.w, wv[6], wv[7]);
            unpack2(ub.x, wv[8], wv[9]); unpack2(ub.y, wv[10], wv[11]);
            unpack2(ub.z, wv[12], wv[13]); unpack2(ub.w, wv[14], wv[15]);
            if (dy == 1) {
                #pragma unroll
                for (int j = 0; j < 8; ++j) ctr[j] = wv[j + 4];
            }
            #pragma unroll
            for (int dx = 0; dx < 3; ++dx) {
                float wt = dw3w[lc * 9 + dy * 3 + dx];
                #pragma unroll
                for (int j = 0; j < 8; ++j) acc[j] += wt * wv[j + dx + 3];
            }
        }
    } else if (c < 192) {
        int lc = c - 128;
        float b0 = dw5b[lc];
        #pragma unroll
        for (int j = 0; j < 8; ++j) acc[j] = b0;
        #pragma unroll
        for (int dy = 0; dy < 5; ++dy) {
            int i = yy + dy + 1;
            uint4 ua = *(const uint4*)&ls[i][x0];
            uint4 ub = *(const uint4*)&ls[i][x0 + 8];
            float wv[16];
            unpack2(ua.x, wv[0], wv[1]); unpack2(ua.y, wv[2], wv[3]);
            unpack2(ua.z, wv[4], wv[5]); unpack2(ua.w, wv[6], wv[7]);
            unpack2(ub.x, wv[8], wv[9]); unpack2(ub.y, wv[10], wv[11]);
            unpack2(ub.z, wv[12], wv[13]); unpack2(ub.w, wv[14], wv[15]);
            if (dy == 2) {
                #pragma unroll
                for (int j = 0; j < 8; ++j) ctr[j] = wv[j + 4];
            }
            #pragma unroll
            for (int dx = 0; dx < 5; ++dx) {
                float wt = dw5w[lc * 25 + dy * 5 + dx];
                #pragma unroll
                for (int j = 0; j < 8; ++j) acc[j] += wt * wv[j + dx + 2];
            }
        }
    } else {
        int lc = c - 192;
        float b0 = dw7b[lc];
        #pragma unroll
        for (int j = 0; j < 8; ++j) acc[j] = b0;
        #pragma unroll
        for (int dy = 0; dy < 7; ++dy) {
            int i = yy + dy;
            uint4 ua = *(const uint4*)&ls[i][x0];
            uint4 ub = *(const uint4*)&ls[i][x0 + 8];
            float wv[16];
            unpack2(ua.x, wv[0], wv[1]); unpack2(ua.y, wv[2], wv[3]);
            unpack2(ua.z, wv[4], wv[5]); unpack2(ua.w, wv[6], wv[7]);
            unpack2(ub.x, wv[8], wv[9]); unpack2(ub.y, wv[10], wv[11]);
            unpack2(ub.z, wv[12], wv[13]); unpack2(ub.w, wv[14], wv[15]);
            if (dy == 3) {
                #pragma unroll
                for (int j = 0; j < 8; ++j) ctr[j] = wv[j + 4];
            }
            #pragma unroll
            for (int dx = 0; dx < 7; ++dx) {
                float wt = dw7w[lc * 49 + dy * 7 + dx];
                #pragma unroll
                for (int j = 0; j < 8; ++j) acc[j] += wt * wv[j + dx + 1];
            }
        }
    }

    bf16x8 o;
    #pragma unroll
    for (int j = 0; j < 8; ++j) {
        float val = fw * acc[j] + ctr[j];
        o[j] = (short)f2bf(gelu_exact(val) * bg + bb2);
    }
    ushort* outp = h2 + (((size_t)b * HID + c) << 12);
    *(bf16x8*)&outp[((r0 + yy) << 6) + x0] = o;
}

// ---------------- fc2 MFMA: out = bn2(fc2w @ h2) + x2 ----------------
__global__ __launch_bounds__(256) void fc2_mfma(const ushort* __restrict__ h2,
                                                const ushort* __restrict__ fc2wb,
                                                const float* __restrict__ bn2g,
                                                const float* __restrict__ bn2b,
                                                const float* __restrict__ x2,
                                                float* __restrict__ out) {
    int b = blockIdx.y;
    int tok0 = blockIdx.x * 64;
    int tid = threadIdx.x;
    int w = tid >> 6;
    int lr = tid & 15;
    int lg = (tid & 63) >> 4;
    __shared__ ushort Xt[64][256];    // [tok][chan], chunk-swizzled (32 KB)
    for (int k = 0; k < 8; ++k) {
        int e = tid + k * 256;        // 2048 chunks of 8 toks
        int c = e >> 3, t8 = (e & 7) * 8;
        bf16x8 v = *(const bf16x8*)&h2[((size_t)(b * 256 + c)) * NN + tok0 + t8];
        #pragma unroll
        for (int j = 0; j < 8; ++j) {
            int t = t8 + j;
            Xt[t][((c >> 3) ^ (t & 7)) * 8 + (c & 7)] = (ushort)v[j];
        }
    }
    __syncthreads();
    int brow = w * 16 + lr;
    f32x4 acc[4];
    #pragma unroll
    for (int mt = 0; mt < 4; ++mt) acc[mt] = (f32x4){0.f, 0.f, 0.f, 0.f};
    #pragma unroll
    for (int ks = 0; ks < 8; ++ks) {
        bf16x8 bfr = *(const bf16x8*)&Xt[brow][(((ks * 4 + lg) & 7) ^ (lr & 7)) * 8 + ((ks * 4 + lg) & ~7) * 8];
        #pragma unroll
        for (int mt = 0; mt < 4; ++mt) {
            bf16x8 a = *(const bf16x8*)&fc2wb[(mt * 16 + lr) * 256 + ks * 32 + lg * 8];
            acc[mt] = MFMA16(a, bfr, acc[mt]);
        }
    }
    const float sb = rsqrtf(1.f + EPSV);
    int tok = tok0 + w * 16 + lr;
    #pragma unroll
    for (int mt = 0; mt < 4; ++mt) {
        #pragma unroll
        for (int r = 0; r < 4; ++r) {
            int o = mt * 16 + lg * 4 + r;
            size_t off = ((size_t)b * 64 + o) * NN + tok;
            out[off] = acc[mt][r] * bn2g[o] * sb + bn2b[o] + x2[off];
        }
    }
}

extern "C" void kernel_launch(void* const* d_in, const int* in_sizes, int n_in,
                              void* d_out, int out_size, void* d_ws, size_t ws_size,
                              hipStream_t stream) {
    const float* x    = (const float*)d_in[0];
    const float* cnn  = (const float*)d_in[1];
    const float* n1g  = (const float*)d_in[2];
    const float* n1b  = (const float*)d_in[3];
    const float* n2g  = (const float*)d_in[4];
    const float* n2b  = (const float*)d_in[5];
    const float* n3g  = (const float*)d_in[6];
    const float* n3b  = (const float*)d_in[7];
    const float* qw   = (const float*)d_in[8];
    const float* qb   = (const float*)d_in[9];
    const float* kvw  = (const float*)d_in[10];
    const float* kvb  = (const float*)d_in[11];
    const float* lcw  = (const float*)d_in[12];
    const float* lcb  = (const float*)d_in[13];
    const float* fc1w = (const float*)d_in[14];
    const float* bn1g = (const float*)d_in[15];
    const float* bn1b = (const float*)d_in[16];
    const float* dw1w = (const float*)d_in[17];
    const float* dw1b = (const float*)d_in[18];
    const float* dw3w = (const float*)d_in[19];
    const float* dw3b = (const float*)d_in[20];
    const float* dw5w = (const float*)d_in[21];
    const float* dw5b = (const float*)d_in[22];
    const float* dw7w = (const float*)d_in[23];
    const float* dw7b = (const float*)d_in[24];
    const float* bnmg = (const float*)d_in[25];
    const float* bnmb = (const float*)d_in[26];
    const float* fftw = (const float*)d_in[27];
    const float* fc2w = (const float*)d_in[28];
    const float* bn2g = (const float*)d_in[29];
    const float* bn2b = (const float*)d_in[30];

    float* ws = (float*)d_ws;
    float* stats = ws;                     // 64
    float* part  = ws + 64;                // 1024
    float* part2 = ws + 1088;              // 2048
    float* base  = ws + 3200;
    const size_t M = 1048576;
    float* x2     = base;                              // [0, 1M)
    ushort* qr_bf = (ushort*)(base + M);               // [1M, 1.5M)
    ushort* kr_bf = (ushort*)(base + M + M / 2);       // [1.5M, 2M)
    ushort* vt_bf = (ushort*)(base + 2 * M);           // [2M, 2.5M)
    float* kvin   = base + 5 * M / 2;                  // [2.5M, 3.5M)
    ushort* Opart = (ushort*)(base + 7 * M / 2);       // [3.5M, 7.5M)
    float* ml     = base + 15 * M / 2;                 // [7.5M, 7.75M)
    ushort* h1 = (ushort*)(base + M);                  // overlay qr/kr/vt/kvin (dead post-attn)
    ushort* h2 = (ushort*)(base + 7 * M / 2);          // overlay Opart head (dead post-combine)
    ushort* fc1wb = (ushort*)(base + 8 * M);           // 16384 ushorts
    ushort* fc2wb = fc1wb + 16384;
    ushort* qwb   = fc2wb + 16384;                     // 4096
    ushort* kvwb  = qwb + 4096;                        // 8192
    float* outp = (float*)d_out;

    wprep_kernel<<<176, 256, 0, stream>>>(fc1w, fc2w, qw, kvw, fc1wb, fc2wb, qwb, kvwb);
    stats_pair_kernel<<<dim3(64, 4), 256, 0, stream>>>(x, cnn, part);
    stats_fin_kernel<<<8, 64, 0, stream>>>(part, stats);
    dw3k_kernel<<<4096, 256, 0, stream>>>(cnn, n3g, n3b, lcw, lcb, stats, kvin);
    q_mfma<<<dim3(64, 4), 256, 0, stream>>>(x, n1g, n1b, qwb, qb, stats, qr_bf);
    kv_mfma<<<dim3(64, 4), 256, 0, stream>>>(kvin, kvwb, kvb, kr_bf, vt_bf);
    attn_kernel<<<dim3(64, 4, NCH), 256, 0, stream>>>(qr_bf, kr_bf, vt_bf, Opart, ml);
    combine_kernel<<<1024, 256, 0, stream>>>(Opart, ml, x, x2, part2);
    stats2b_kernel<<<4, 256, 0, stream>>>(part2, stats, 2);
    fc1_mfma<<<dim3(128, 4), 256, 0, stream>>>(x2, fc1wb, n2g, n2b, bn1g, bn1b, stats, h1);
    mixer_kernel<<<dim3(512, 4), 256, 0, stream>>>(h1, dw1w, dw1b, dw3w, dw3b, dw5w, dw5b,
                                                   dw7w, dw7b, fftw, bnmg, bnmb, h2);
    fc2_mfma<<<dim3(64, 4), 256, 0, stream>>>(h2, fc2wb, bn2g, bn2b, x2, outp);
}

// Round 18
// 110.149 us; speedup vs baseline: 1.1943x; 1.0416x over previous
//
#include <hip/hip_runtime.h>
#include <hip/hip_bf16.h>
#include <math.h>

#define BB 4
#define CC 64
#define NN 4096
#define HD 64
#define HID 256
#define EPSV 1e-5f
#define CNT (CC*NN)
#define NCH 8            // KV split chunks

typedef float f32x4 __attribute__((ext_vector_type(4)));
typedef short bf16x8 __attribute__((ext_vector_type(8)));
typedef short bf16x4 __attribute__((ext_vector_type(4)));
#define MFMA16(a, b, c) __builtin_amdgcn_mfma_f32_16x16x32_bf16(a, b, c, 0, 0, 0)

__device__ __forceinline__ float gelu_exact(float x) {
    return 0.5f * x * (1.0f + erff(x * 0.70710678118654752f));
}
__device__ __forceinline__ ushort f2bf(float f) {
    unsigned u = __float_as_uint(f);
    unsigned r = (u + 0x7FFFu + ((u >> 16) & 1u)) >> 16;
    return (ushort)r;
}
__device__ __forceinline__ float bf2f(ushort u) {
    return __uint_as_float(((unsigned)u) << 16);
}
__device__ __forceinline__ unsigned cvtpk(float lo, float hi) {
    unsigned r;
    asm("v_cvt_pk_bf16_f32 %0, %1, %2" : "=v"(r) : "v"(lo), "v"(hi));
    return r;
}
__device__ __forceinline__ void unpack2(unsigned u, float& lo, float& hi) {
    lo = __uint_as_float(u << 16);
    hi = __uint_as_float(u & 0xffff0000u);
}

// ---------------- stats stage 1 (x, cnn) + fused weight prep ----------------
// grid dim3(108, 4): bx<64 -> stats partials for batch by; bx>=64 -> wprep slice
__global__ __launch_bounds__(256) void stats_wprep_kernel(const float* __restrict__ x,
                                                          const float* __restrict__ cnn,
                                                          float* __restrict__ part,
                                                          const float* __restrict__ fc1w,
                                                          const float* __restrict__ fc2w,
                                                          const float* __restrict__ qw,
                                                          const float* __restrict__ kvw,
                                                          ushort* __restrict__ fc1wb,
                                                          ushort* __restrict__ fc2wb,
                                                          ushort* __restrict__ qwb,
                                                          ushort* __restrict__ kvwb) {
    int b = blockIdx.y;
    int blk = blockIdx.x;
    if (blk >= 64) {
        int i = (b * 44 + (blk - 64)) * 256 + threadIdx.x;   // < 45056
        if (i < 16384) fc1wb[i] = f2bf(fc1w[i]);
        else if (i < 32768) fc2wb[i - 16384] = f2bf(fc2w[i - 16384]);
        else if (i < 36864) qwb[i - 32768] = f2bf(qw[i - 32768]);
        else if (i < 45056) kvwb[i - 36864] = f2bf(kvw[i - 36864]);
        return;
    }
    const float4* p0 = (const float4*)(x + (size_t)b * CNT);
    const float4* p1 = (const float4*)(cnn + (size_t)b * CNT);
    float s0 = 0.f, s20 = 0.f, s1 = 0.f, s21 = 0.f;
    #pragma unroll
    for (int k = 0; k < 4; ++k) {
        float4 v = p0[blk * 1024 + k * 256 + threadIdx.x];
        s0  += v.x + v.y + v.z + v.w;
        s20 += v.x * v.x + v.y * v.y + v.z * v.z + v.w * v.w;
        float4 u = p1[blk * 1024 + k * 256 + threadIdx.x];
        s1  += u.x + u.y + u.z + u.w;
        s21 += u.x * u.x + u.y * u.y + u.z * u.z + u.w * u.w;
    }
    #pragma unroll
    for (int off = 32; off > 0; off >>= 1) {
        s0  += __shfl_xor(s0, off);
        s20 += __shfl_xor(s20, off);
        s1  += __shfl_xor(s1, off);
        s21 += __shfl_xor(s21, off);
    }
    __shared__ float sh[4][4];
    int wid = threadIdx.x >> 6, lane = threadIdx.x & 63;
    if (lane == 0) { sh[wid][0] = s0; sh[wid][1] = s20; sh[wid][2] = s1; sh[wid][3] = s21; }
    __syncthreads();
    if (threadIdx.x == 0) {
        float a0 = sh[0][0] + sh[1][0] + sh[2][0] + sh[3][0];
        float a1 = sh[0][1] + sh[1][1] + sh[2][1] + sh[3][1];
        float a2 = sh[0][2] + sh[1][2] + sh[2][2] + sh[3][2];
        float a3 = sh[0][3] + sh[1][3] + sh[2][3] + sh[3][3];
        part[((0 * 4 + b) * 64 + blk) * 2]     = a0;
        part[((0 * 4 + b) * 64 + blk) * 2 + 1] = a1;
        part[((1 * 4 + b) * 64 + blk) * 2]     = a2;
        part[((1 * 4 + b) * 64 + blk) * 2 + 1] = a3;
    }
}

// ---------------- stats finalize (both slots) ----------------
__global__ __launch_bounds__(64) void stats_fin_kernel(const float* __restrict__ part,
                                                       float* __restrict__ stats) {
    int sb_ = blockIdx.x;    // slot*4 + b
    int lane = threadIdx.x;
    float s = part[(sb_ * 64 + lane) * 2];
    float s2 = part[(sb_ * 64 + lane) * 2 + 1];
    #pragma unroll
    for (int off = 32; off > 0; off >>= 1) {
        s  += __shfl_xor(s, off);
        s2 += __shfl_xor(s2, off);
    }
    if (lane == 0) {
        int slot = sb_ >> 2, b = sb_ & 3;
        float mu = s / (float)CNT;
        float var = s2 / (float)CNT - mu * mu;
        stats[slot * 8 + b] = mu;
        stats[slot * 8 + 4 + b] = rsqrtf(var + EPSV);
    }
}

// ---------------- stats stage 2b (256 partials, slot 2) ----------------
__global__ __launch_bounds__(256) void stats2b_kernel(const float* __restrict__ part2,
                                                      float* __restrict__ stats, int slot) {
    int b = blockIdx.x;
    int t = threadIdx.x;
    float s = part2[(b * 256 + t) * 2];
    float s2 = part2[(b * 256 + t) * 2 + 1];
    #pragma unroll
    for (int off = 32; off > 0; off >>= 1) {
        s  += __shfl_xor(s, off);
        s2 += __shfl_xor(s2, off);
    }
    __shared__ float shs[4], shs2[4];
    int wid = t >> 6, lane = t & 63;
    if (lane == 0) { shs[wid] = s; shs2[wid] = s2; }
    __syncthreads();
    if (t == 0) {
        float S = shs[0] + shs[1] + shs[2] + shs[3];
        float S2 = shs2[0] + shs2[1] + shs2[2] + shs2[3];
        float mu = S / (float)CNT;
        float var = S2 / (float)CNT - mu * mu;
        stats[slot * 8 + b] = mu;
        stats[slot * 8 + 4 + b] = rsqrtf(var + EPSV);
    }
}

// ---------------- dw3k: kvin = dw3(gn(cnn)) + bias + gn(cnn) ----------------
__global__ __launch_bounds__(256) void dw3k_kernel(const float* __restrict__ cnn,
                                                   const float* __restrict__ n3g,
                                                   const float* __restrict__ n3b,
                                                   const float* __restrict__ lcw,
                                                   const float* __restrict__ lcb,
                                                   const float* __restrict__ stats,
                                                   float* __restrict__ kvin) {
    int i = blockIdx.x * 256 + threadIdx.x;   // 1,048,576
    int x = i & 63;
    int y = (i >> 6) & 63;
    int c = (i >> 12) & 63;
    int b = i >> 18;
    float mu = stats[1 * 8 + b];
    float rs = stats[1 * 8 + 4 + b];
    float sc = rs * n3g[c];
    float of = n3b[c] - mu * sc;
    const float* plane = cnn + ((size_t)(i >> 12) << 12);
    float acc = lcb[c];
    #pragma unroll
    for (int dy = 0; dy < 3; ++dy) {
        int yy = y + dy - 1;
        if (yy < 0 || yy >= 64) continue;
        #pragma unroll
        for (int dx = 0; dx < 3; ++dx) {
            int xx = x + dx - 1;
            if (xx < 0 || xx >= 64) continue;
            acc += lcw[c * 9 + dy * 3 + dx] * (plane[(yy << 6) + xx] * sc + of);
        }
    }
    kvin[i] = acc + plane[(y << 6) + x] * sc + of;
}

// ---------------- QKV MFMA fused dispatch: bx<64 -> Q path; bx>=64 -> KV path ----------------
// Q path: gn(x)->proj->bias+RoPE->bf16*SCL2 (B,N,HD). KV: kvin->proj; K+RoPE; V^T permuted.
__global__ __launch_bounds__(256) void qkv_mfma(const float* __restrict__ x,
                                                const float* __restrict__ n1g,
                                                const float* __restrict__ n1b,
                                                const ushort* __restrict__ qwb,
                                                const float* __restrict__ qb,
                                                const float* __restrict__ kvin,
                                                const ushort* __restrict__ kvwb,
                                                const float* __restrict__ kvb,
                                                const float* __restrict__ stats,
                                                ushort* __restrict__ qr,
                                                ushort* __restrict__ kr,
                                                ushort* __restrict__ vt) {
    const float SCL2 = 0.125f * 1.44269504f;
    int b = blockIdx.y;
    int tid = threadIdx.x;
    int w = tid >> 6;
    int lr = tid & 15;
    int lg = (tid & 63) >> 4;
    __shared__ ushort Xt[64][64];
    int brow = w * 16 + lr;

    if (blockIdx.x < 64) {
        // ---------- Q path ----------
        int tok0 = blockIdx.x * 64;
        float mu = stats[0 * 8 + b];
        float rs = stats[0 * 8 + 4 + b];
        for (int k = 0; k < 16; ++k) {
            int e = tid + k * 256;
            int c = e >> 6, t = e & 63;
            float v = (x[((size_t)(b * 64 + c)) * NN + tok0 + t] - mu) * rs * n1g[c] + n1b[c];
            Xt[t][((c >> 3) ^ (t & 7)) * 8 + (c & 7)] = f2bf(v);
        }
        __syncthreads();
        bf16x8 bf0 = *(const bf16x8*)&Xt[brow][((0 + lg) ^ (lr & 7)) * 8];
        bf16x8 bf1 = *(const bf16x8*)&Xt[brow][((4 + lg) ^ (lr & 7)) * 8];
        f32x4 acc[4];
        #pragma unroll
        for (int mt = 0; mt < 4; ++mt) acc[mt] = (f32x4){0.f, 0.f, 0.f, 0.f};
        #pragma unroll
        for (int mt = 0; mt < 4; ++mt) {
            bf16x8 a0 = *(const bf16x8*)&qwb[(mt * 16 + lr) * 64 + lg * 8];
            bf16x8 a1 = *(const bf16x8*)&qwb[(mt * 16 + lr) * 64 + 32 + lg * 8];
            acc[mt] = MFMA16(a0, bf0, acc[mt]);
            acc[mt] = MFMA16(a1, bf1, acc[mt]);
        }
        int tok = tok0 + w * 16 + lr;
        int hh = tok >> 6, ww2 = tok & 63;
        ushort* qrow = qr + ((size_t)b * NN + tok) * 64;
        #pragma unroll
        for (int mt = 0; mt < 4; ++mt) {
            #pragma unroll
            for (int pr = 0; pr < 2; ++pr) {
                int o = mt * 16 + lg * 4 + pr * 2;
                float a0 = acc[mt][pr * 2]     + qb[o];
                float a1 = acc[mt][pr * 2 + 1] + qb[o + 1];
                int j = (o & 31) >> 1;
                float freq = exp2f(-0.88584749f * (float)j);
                float pos = (o < 32) ? (float)hh : (float)ww2;
                float st, ct;
                __sincosf(pos * freq, &st, &ct);
                qrow[o]     = f2bf((a0 * ct - a1 * st) * SCL2);
                qrow[o + 1] = f2bf((a1 * ct + a0 * st) * SCL2);
            }
        }
    } else {
        // ---------- KV path ----------
        int tok0 = (blockIdx.x - 64) * 64;
        for (int k = 0; k < 16; ++k) {
            int e = tid + k * 256;
            int c = e >> 6, t = e & 63;
            Xt[t][((c >> 3) ^ (t & 7)) * 8 + (c & 7)] =
                f2bf(kvin[((size_t)(b * 64 + c)) * NN + tok0 + t]);
        }
        __syncthreads();
        bf16x8 bf0 = *(const bf16x8*)&Xt[brow][((0 + lg) ^ (lr & 7)) * 8];
        bf16x8 bf1 = *(const bf16x8*)&Xt[brow][((4 + lg) ^ (lr & 7)) * 8];
        f32x4 acc[8];
        #pragma unroll
        for (int mt = 0; mt < 8; ++mt) acc[mt] = (f32x4){0.f, 0.f, 0.f, 0.f};
        #pragma unroll
        for (int mt = 0; mt < 8; ++mt) {
            bf16x8 a0 = *(const bf16x8*)&kvwb[(mt * 16 + lr) * 64 + lg * 8];
            bf16x8 a1 = *(const bf16x8*)&kvwb[(mt * 16 + lr) * 64 + 32 + lg * 8];
            acc[mt] = MFMA16(a0, bf0, acc[mt]);
            acc[mt] = MFMA16(a1, bf1, acc[mt]);
        }
        int tl = w * 16 + lr;
        int tok = tok0 + tl;
        int hh = tok >> 6, ww2 = tok & 63;
        int permk = (lr >> 2) * 16 + w * 4 + (lr & 3);
        ushort* krow = kr + ((size_t)b * NN + tok) * 64;
        #pragma unroll
        for (int mt = 0; mt < 4; ++mt) {      // K half, with RoPE
            #pragma unroll
            for (int pr = 0; pr < 2; ++pr) {
                int o = mt * 16 + lg * 4 + pr * 2;
                float a0 = acc[mt][pr * 2]     + kvb[o];
                float a1 = acc[mt][pr * 2 + 1] + kvb[o + 1];
                int j = (o & 31) >> 1;
                float freq = exp2f(-0.88584749f * (float)j);
                float pos = (o < 32) ? (float)hh : (float)ww2;
                float st, ct;
                __sincosf(pos * freq, &st, &ct);
                krow[o]     = f2bf(a0 * ct - a1 * st);
                krow[o + 1] = f2bf(a1 * ct + a0 * st);
            }
        }
        #pragma unroll
        for (int mt = 4; mt < 8; ++mt) {      // V half, key-permuted transpose store
            #pragma unroll
            for (int r = 0; r < 4; ++r) {
                int o = mt * 16 + lg * 4 + r;
                float a0 = acc[mt][r] + kvb[o];
                vt[((size_t)b * 64 + (o - 64)) * NN + tok0 + permk] = f2bf(a0);
            }
        }
    }
}

// ---------------- MFMA flash attention v4.2: hoisted staging, max3, setprio ----------------
// grid dim3(64, B, NCH), 256 thr = 4 waves x 16 q-rows; KV tile 64; chunk = 512 keys
__global__ __launch_bounds__(256) void attn_kernel(const ushort* __restrict__ qr,
                                                   const ushort* __restrict__ kr,
                                                   const ushort* __restrict__ vt,
                                                   ushort* __restrict__ Opart,
                                                   float* __restrict__ ml) {
    int b = blockIdx.y;
    int q0 = blockIdx.x * 64;
    int chunk = blockIdx.z;
    int tid = threadIdx.x;
    int w = tid >> 6;
    int lane = tid & 63;
    int lr = lane & 15;
    int lg = lane >> 4;

    __shared__ ushort Kl[64 * 64];
    __shared__ ushort Vl[64 * 64];

    bf16x8 qf[2];
    {
        const ushort* qp = qr + ((size_t)b * NN + q0 + w * 16 + lr) * 64;
        qf[0] = *(const bf16x8*)(qp + lg * 8);
        qf[1] = *(const bf16x8*)(qp + 32 + lg * 8);
    }

    f32x4 oacc[4];
    #pragma unroll
    for (int t = 0; t < 4; ++t) oacc[t] = (f32x4){0.f, 0.f, 0.f, 0.f};
    float m_ = -INFINITY, l_ = 0.f;     // base-2 scalar state for q-row = q0+w*16+lr

    const int t0 = chunk * 8;
    const int srow0 = tid >> 3;          // 0..31
    const int srow1 = srow0 + 32;        // 32..63
    const int scib = tid & 7;
    const int kd0 = srow0 * 64 + (scib ^ (srow0 & 7)) * 8;
    const int kd1 = srow1 * 64 + (scib ^ (srow1 & 7)) * 8;
    const ushort* kp0 = kr + ((size_t)b * NN + t0 * 64 + srow0) * 64 + scib * 8;
    const ushort* kp1 = kr + ((size_t)b * NN + t0 * 64 + srow1) * 64 + scib * 8;
    const ushort* vp0 = vt + ((size_t)b * 64 + srow0) * NN + t0 * 64 + scib * 8;
    const ushort* vp1 = vt + ((size_t)b * 64 + srow1) * NN + t0 * 64 + scib * 8;
    const int rs7 = lr & 7;

    for (int t = 0; t < 8; ++t) {
        __syncthreads();
        *(bf16x8*)(Kl + kd0) = *(const bf16x8*)kp0;
        *(bf16x8*)(Kl + kd1) = *(const bf16x8*)kp1;
        *(bf16x8*)(Vl + kd0) = *(const bf16x8*)vp0;
        *(bf16x8*)(Vl + kd1) = *(const bf16x8*)vp1;
        kp0 += 4096; kp1 += 4096; vp0 += 64; vp1 += 64;
        __syncthreads();

        f32x4 sacc[4];
        __builtin_amdgcn_s_setprio(1);
        #pragma unroll
        for (int kt = 0; kt < 4; ++kt) {
            int row = kt * 16 + lr;
            bf16x8 k0f = *(const bf16x8*)(Kl + row * 64 + ((0 * 4 + lg) ^ rs7) * 8);
            bf16x8 k1f = *(const bf16x8*)(Kl + row * 64 + ((1 * 4 + lg) ^ rs7) * 8);
            f32x4 z = {0.f, 0.f, 0.f, 0.f};
            z = MFMA16(k0f, qf[0], z);
            sacc[kt] = MFMA16(k1f, qf[1], z);
        }
        __builtin_amdgcn_s_setprio(0);

        float m0 = fmaxf(fmaxf(sacc[0][0], sacc[0][1]), sacc[0][2]);
        float m1 = fmaxf(fmaxf(sacc[0][3], sacc[1][0]), sacc[1][1]);
        float m2 = fmaxf(fmaxf(sacc[1][2], sacc[1][3]), sacc[2][0]);
        float m3 = fmaxf(fmaxf(sacc[2][1], sacc[2][2]), sacc[2][3]);
        float m4 = fmaxf(fmaxf(sacc[3][0], sacc[3][1]), sacc[3][2]);
        float n0v = fmaxf(fmaxf(m0, m1), m2);
        float n1v = fmaxf(fmaxf(m3, m4), sacc[3][3]);
        float vmax = fmaxf(n0v, n1v);
        vmax = fmaxf(vmax, __shfl_xor(vmax, 16));
        vmax = fmaxf(vmax, __shfl_xor(vmax, 32));
        if (__any(vmax - m_ > 8.f)) {          // defer-max
            float mn = fmaxf(m_, vmax);
            float cr = exp2f(m_ - mn);
            l_ *= cr;
            m_ = mn;
            float crq[4];
            #pragma unroll
            for (int r = 0; r < 4; ++r) crq[r] = __shfl(cr, lg * 4 + r);
            #pragma unroll
            for (int ht = 0; ht < 4; ++ht)
                #pragma unroll
                for (int r = 0; r < 4; ++r) oacc[ht][r] *= crq[r];
        }

        unsigned u[8];
        float lsum = 0.f;
        #pragma unroll
        for (int kt = 0; kt < 4; ++kt) {
            float p0 = exp2f(sacc[kt][0] - m_);
            float p1 = exp2f(sacc[kt][1] - m_);
            float p2 = exp2f(sacc[kt][2] - m_);
            float p3 = exp2f(sacc[kt][3] - m_);
            lsum += (p0 + p1) + (p2 + p3);
            u[kt * 2]     = cvtpk(p0, p1);
            u[kt * 2 + 1] = cvtpk(p2, p3);
        }
        lsum += __shfl_xor(lsum, 16);
        lsum += __shfl_xor(lsum, 32);
        l_ += lsum;

        uint4 t0v = {u[0], u[1], u[2], u[3]};
        uint4 t1v = {u[4], u[5], u[6], u[7]};
        bf16x8 pa0 = __builtin_bit_cast(bf16x8, t0v);
        bf16x8 pa1 = __builtin_bit_cast(bf16x8, t1v);
        __builtin_amdgcn_s_setprio(1);
        #pragma unroll
        for (int ht = 0; ht < 4; ++ht) {
            int row = ht * 16 + lr;
            bf16x8 vf0 = *(const bf16x8*)(Vl + row * 64 + ((lg * 2) ^ rs7) * 8);
            bf16x8 vf1 = *(const bf16x8*)(Vl + row * 64 + ((lg * 2 + 1) ^ rs7) * 8);
            oacc[ht] = MFMA16(pa0, vf0, oacc[ht]);
            oacc[ht] = MFMA16(pa1, vf1, oacc[ht]);
        }
        __builtin_amdgcn_s_setprio(0);
    }

    int n0 = q0 + w * 16 + lg * 4;
    #pragma unroll
    for (int ht = 0; ht < 4; ++ht) {
        int hd = ht * 16 + lr;
        ushort4 o4;
        o4.x = f2bf(oacc[ht][0]);
        o4.y = f2bf(oacc[ht][1]);
        o4.z = f2bf(oacc[ht][2]);
        o4.w = f2bf(oacc[ht][3]);
        *(ushort4*)&Opart[(((size_t)chunk * BB + b) * 64 + hd) * NN + n0] = o4;
    }
    if (lg == 0) {
        int n = q0 + w * 16 + lr;
        ml[((size_t)b * NN + n) * 16 + chunk * 2]     = m_;
        ml[((size_t)b * NN + n) * 16 + chunk * 2 + 1] = l_;
    }
}

// ---------------- combine: x2 = sum_c O_c*w_c + x; fused stats partials ----------------
__global__ __launch_bounds__(256) void combine_kernel(const ushort* __restrict__ Opart,
                                                      const float* __restrict__ ml,
                                                      const float* __restrict__ x,
                                                      float* __restrict__ x2,
                                                      float* __restrict__ part2) {
    int i = blockIdx.x * 256 + threadIdx.x;   // 262144
    int n4 = i & 1023;
    int hd = (i >> 10) & 63;
    int b = i >> 16;
    int n0 = n4 << 2;
    float wgt[4][NCH];
    const float* mlp = ml + ((size_t)b * NN + n0) * 16;
    #pragma unroll
    for (int tk = 0; tk < 4; ++tk) {
        float m[NCH], l[NCH];
        const float4* p4 = (const float4*)(mlp + tk * 16);
        #pragma unroll
        for (int q = 0; q < 4; ++q) {
            float4 v = p4[q];
            m[q * 2] = v.x; l[q * 2] = v.y; m[q * 2 + 1] = v.z; l[q * 2 + 1] = v.w;
        }
        float M = m[0];
        #pragma unroll
        for (int c = 1; c < NCH; ++c) M = fmaxf(M, m[c]);
        float e[NCH], L = 0.f;
        #pragma unroll
        for (int c = 0; c < NCH; ++c) { e[c] = exp2f(m[c] - M); L += l[c] * e[c]; }
        float inv = 1.f / L;
        #pragma unroll
        for (int c = 0; c < NCH; ++c) wgt[tk][c] = e[c] * inv;
    }
    float4 acc = {0.f, 0.f, 0.f, 0.f};
    #pragma unroll
    for (int c = 0; c < NCH; ++c) {
        ushort4 o4 = *(const ushort4*)&Opart[(((size_t)c * BB + b) * 64 + hd) * NN + n0];
        acc.x += bf2f(o4.x) * wgt[0][c];
        acc.y += bf2f(o4.y) * wgt[1][c];
        acc.z += bf2f(o4.z) * wgt[2][c];
        acc.w += bf2f(o4.w) * wgt[3][c];
    }
    size_t off = ((size_t)b * 64 + hd) * NN + n0;
    float4 xv = *(const float4*)&x[off];
    acc.x += xv.x; acc.y += xv.y; acc.z += xv.z; acc.w += xv.w;
    *(float4*)&x2[off] = acc;

    float s = acc.x + acc.y + acc.z + acc.w;
    float s2 = acc.x * acc.x + acc.y * acc.y + acc.z * acc.z + acc.w * acc.w;
    #pragma unroll
    for (int off2 = 32; off2 > 0; off2 >>= 1) {
        s  += __shfl_xor(s, off2);
        s2 += __shfl_xor(s2, off2);
    }
    __shared__ float shs[4], shs2[4];
    int wid = threadIdx.x >> 6, lane = threadIdx.x & 63;
    if (lane == 0) { shs[wid] = s; shs2[wid] = s2; }
    __syncthreads();
    if (threadIdx.x == 0) {
        part2[blockIdx.x * 2]     = shs[0] + shs[1] + shs[2] + shs[3];
        part2[blockIdx.x * 2 + 1] = shs2[0] + shs2[1] + shs2[2] + shs2[3];
    }
}

// ---------------- fc1 MFMA: h1 = gelu(bn1(fc1w @ gn2(x2))) -> bf16 ----------------
__global__ __launch_bounds__(256) void fc1_mfma(const float* __restrict__ x2,
                                                const ushort* __restrict__ fc1wb,
                                                const float* __restrict__ n2g,
                                                const float* __restrict__ n2b,
                                                const float* __restrict__ bn1g,
                                                const float* __restrict__ bn1b,
                                                const float* __restrict__ stats,
                                                ushort* __restrict__ h1) {
    int b = blockIdx.y;
    int tok0 = (blockIdx.x >> 1) * 64;
    int half = blockIdx.x & 1;
    int tid = threadIdx.x;
    int w = tid >> 6;
    int lr = tid & 15;
    int lg = (tid & 63) >> 4;
    float mu = stats[2 * 8 + b];
    float rs = stats[2 * 8 + 4 + b];
    __shared__ ushort Xt[64][64];     // [tok][chan], chunk-swizzled
    for (int k = 0; k < 16; ++k) {
        int e = tid + k * 256;
        int c = e >> 6, t = e & 63;
        float v = (x2[((size_t)(b * 64 + c)) * NN + tok0 + t] - mu) * rs * n2g[c] + n2b[c];
        Xt[t][((c >> 3) ^ (t & 7)) * 8 + (c & 7)] = f2bf(v);
    }
    __syncthreads();
    int brow = w * 16 + lr;
    bf16x8 bf0 = *(const bf16x8*)&Xt[brow][((0 + lg) ^ (lr & 7)) * 8];
    bf16x8 bf1 = *(const bf16x8*)&Xt[brow][((4 + lg) ^ (lr & 7)) * 8];
    f32x4 acc[8];
    #pragma unroll
    for (int mt = 0; mt < 8; ++mt) acc[mt] = (f32x4){0.f, 0.f, 0.f, 0.f};
    const ushort* wb = fc1wb + (size_t)(half * 128) * 64;
    #pragma unroll
    for (int mt = 0; mt < 8; ++mt) {
        bf16x8 a0 = *(const bf16x8*)&wb[(mt * 16 + lr) * 64 + lg * 8];
        bf16x8 a1 = *(const bf16x8*)&wb[(mt * 16 + lr) * 64 + 32 + lg * 8];
        acc[mt] = MFMA16(a0, bf0, acc[mt]);
        acc[mt] = MFMA16(a1, bf1, acc[mt]);
    }
    const float sb = rsqrtf(1.f + EPSV);
    int tok = tok0 + w * 16 + lr;
    #pragma unroll
    for (int mt = 0; mt < 8; ++mt) {
        #pragma unroll
        for (int r = 0; r < 4; ++r) {
            int o = half * 128 + mt * 16 + lg * 4 + r;
            float vv = acc[mt][r] * bn1g[o] * sb + bn1b[o];
            h1[((size_t)b * HID + o) * NN + tok] = f2bf(gelu_exact(vv));
        }
    }
}

// ---------------- mixer v2: register sliding-window; 32-row half planes ----------------
__global__ __launch_bounds__(256) void mixer_kernel(const ushort* __restrict__ h1,
                                                    const float* __restrict__ dw1w, const float* __restrict__ dw1b,
                                                    const float* __restrict__ dw3w, const float* __restrict__ dw3b,
                                                    const float* __restrict__ dw5w, const float* __restrict__ dw5b,
                                                    const float* __restrict__ dw7w, const float* __restrict__ dw7b,
                                                    const float* __restrict__ fftw,
                                                    const float* __restrict__ bnmg, const float* __restrict__ bnmb,
                                                    ushort* __restrict__ h2) {
    int c = blockIdx.x >> 1;
    int r0 = (blockIdx.x & 1) * 32;
    int b = blockIdx.y;
    int tid = threadIdx.x;
    __shared__ ushort ls[38][80];      // 6080 B
    uint* lz = (uint*)&ls[0][0];
    #pragma unroll
    for (int k = 0; k < 6; ++k) {
        int i = tid + k * 256;
        if (i < 1520) lz[i] = 0;
    }
    __syncthreads();
    const ushort* plane = h1 + (((size_t)b * HID + c) << 12);
    for (int e = tid; e < 304; e += 256) {
        int i = e >> 3, xc = e & 7;
        int gr = r0 + i - 3;
        if (gr >= 0 && gr < 64) {
            bf16x8 v = *(const bf16x8*)&plane[(gr << 6) + xc * 8];
            bf16x4 lo = {v[0], v[1], v[2], v[3]};
            bf16x4 hi = {v[4], v[5], v[6], v[7]};
            *(bf16x4*)&ls[i][xc * 8 + 4] = lo;
            *(bf16x4*)&ls[i][xc * 8 + 8] = hi;
        }
    }
    __syncthreads();

    int yy = tid >> 3;
    int x0 = (tid & 7) * 8;
    const float sb = rsqrtf(1.f + EPSV);
    float fw = fftw[c];
    float bg = bnmg[c] * sb, bb2 = bnmb[c];
    float acc[8], ctr[8];
    #pragma unroll
    for (int j = 0; j < 8; ++j) acc[j] = 0.f;

    if (c < 64) {
        float w0 = dw1w[c], b0 = dw1b[c];
        uint4 ua = *(const uint4*)&ls[yy + 3][x0];
        uint4 ub = *(const uint4*)&ls[yy + 3][x0 + 8];
        float wv[16];
        unpack2(ua.x, wv[0], wv[1]); unpack2(ua.y, wv[2], wv[3]);
        unpack2(ua.z, wv[4], wv[5]); unpack2(ua.w, wv[6], wv[7]);
        unpack2(ub.x, wv[8], wv[9]); unpack2(ub.y, wv[10], wv[11]);
        unpack2(ub.z, wv[12], wv[13]); unpack2(ub.w, wv[14], wv[15]);
        #pragma unroll
        for (int j = 0; j < 8; ++j) { ctr[j] = wv[j + 4]; acc[j] = w0 * ctr[j] + b0; }
    } else if (c < 128) {
        int lc = c - 64;
        float b0 = dw3b[lc];
        #pragma unroll
        for (int j = 0; j < 8; ++j) acc[j] = b0;
        #pragma unroll
        for (int dy = 0; dy < 3; ++dy) {
            int i = yy + dy + 2;
            uint4 ua = *(const uint4*)&ls[i][x0];
            uint4 ub = *(const uint4*)&ls[i][x0 + 8];
            float wv[16];
            unpack2(ua.x, wv[0], wv[1]); unpack2(ua.y, wv[2], wv[3]);
            unpack2(ua.z, wv[4], wv[5]); unpack2(ua.w, wv[6], wv[7]);
            unpack2(ub.x, wv[8], wv[9]); unpack2(ub.y, wv[10], wv[11]);
            unpack2(ub.z, wv[12], wv[13]); unpack2(ub.w, wv[14], wv[15]);
            if (dy == 1) {
                #pragma unroll
                for (int j = 0; j < 8; ++j) ctr[j] = wv[j + 4];
            }
            #pragma unroll
            for (int dx = 0; dx < 3; ++dx) {
                float wt = dw3w[lc * 9 + dy * 3 + dx];
                #pragma unroll
                for (int j = 0; j < 8; ++j) acc[j] += wt * wv[j + dx + 3];
            }
        }
    } else if (c < 192) {
        int lc = c - 128;
        float b0 = dw5b[lc];
        #pragma unroll
        for (int j = 0; j < 8; ++j) acc[j] = b0;
        #pragma unroll
        for (int dy = 0; dy < 5; ++dy) {
            int i = yy + dy + 1;
            uint4 ua = *(const uint4*)&ls[i][x0];
            uint4 ub = *(const uint4*)&ls[i][x0 + 8];
            float wv[16];
            unpack2(ua.x, wv[0], wv[1]); unpack2(ua.y, wv[2], wv[3]);
            unpack2(ua.z, wv[4], wv[5]); unpack2(ua.w, wv[6], wv[7]);
            unpack2(ub.x, wv[8], wv[9]); unpack2(ub.y, wv[10], wv[11]);
            unpack2(ub.z, wv[12], wv[13]); unpack2(ub.w, wv[14], wv[15]);
            if (dy == 2) {
                #pragma unroll
                for (int j = 0; j < 8; ++j) ctr[j] = wv[j + 4];
            }
            #pragma unroll
            for (int dx = 0; dx < 5; ++dx) {
                float wt = dw5w[lc * 25 + dy * 5 + dx];
                #pragma unroll
                for (int j = 0; j < 8; ++j) acc[j] += wt * wv[j + dx + 2];
            }
        }
    } else {
        int lc = c - 192;
        float b0 = dw7b[lc];
        #pragma unroll
        for (int j = 0; j < 8; ++j) acc[j] = b0;
        #pragma unroll
        for (int dy = 0; dy < 7; ++dy) {
            int i = yy + dy;
            uint4 ua = *(const uint4*)&ls[i][x0];
            uint4 ub = *(const uint4*)&ls[i][x0 + 8];
            float wv[16];
            unpack2(ua.x, wv[0], wv[1]); unpack2(ua.y, wv[2], wv[3]);
            unpack2(ua.z, wv[4], wv[5]); unpack2(ua.w, wv[6], wv[7]);
            unpack2(ub.x, wv[8], wv[9]); unpack2(ub.y, wv[10], wv[11]);
            unpack2(ub.z, wv[12], wv[13]); unpack2(ub.w, wv[14], wv[15]);
            if (dy == 3) {
                #pragma unroll
                for (int j = 0; j < 8; ++j) ctr[j] = wv[j + 4];
            }
            #pragma unroll
            for (int dx = 0; dx < 7; ++dx) {
                float wt = dw7w[lc * 49 + dy * 7 + dx];
                #pragma unroll
                for (int j = 0; j < 8; ++j) acc[j] += wt * wv[j + dx + 1];
            }
        }
    }

    bf16x8 o;
    #pragma unroll
    for (int j = 0; j < 8; ++j) {
        float val = fw * acc[j] + ctr[j];
        o[j] = (short)f2bf(gelu_exact(val) * bg + bb2);
    }
    ushort* outp = h2 + (((size_t)b * HID + c) << 12);
    *(bf16x8*)&outp[((r0 + yy) << 6) + x0] = o;
}

// ---------------- fc2 MFMA: out = bn2(fc2w @ h2) + x2 ----------------
__global__ __launch_bounds__(256) void fc2_mfma(const ushort* __restrict__ h2,
                                                const ushort* __restrict__ fc2wb,
                                                const float* __restrict__ bn2g,
                                                const float* __restrict__ bn2b,
                                                const float* __restrict__ x2,
                                                float* __restrict__ out) {
    int b = blockIdx.y;
    int tok0 = blockIdx.x * 64;
    int tid = threadIdx.x;
    int w = tid >> 6;
    int lr = tid & 15;
    int lg = (tid & 63) >> 4;
    __shared__ ushort Xt[64][256];    // [tok][chan], chunk-swizzled (32 KB)
    for (int k = 0; k < 8; ++k) {
        int e = tid + k * 256;        // 2048 chunks of 8 toks
        int c = e >> 3, t8 = (e & 7) * 8;
        bf16x8 v = *(const bf16x8*)&h2[((size_t)(b * 256 + c)) * NN + tok0 + t8];
        #pragma unroll
        for (int j = 0; j < 8; ++j) {
            int t = t8 + j;
            Xt[t][((c >> 3) ^ (t & 7)) * 8 + (c & 7)] = (ushort)v[j];
        }
    }
    __syncthreads();
    int brow = w * 16 + lr;
    f32x4 acc[4];
    #pragma unroll
    for (int mt = 0; mt < 4; ++mt) acc[mt] = (f32x4){0.f, 0.f, 0.f, 0.f};
    #pragma unroll
    for (int ks = 0; ks < 8; ++ks) {
        bf16x8 bfr = *(const bf16x8*)&Xt[brow][(((ks * 4 + lg) & 7) ^ (lr & 7)) * 8 + ((ks * 4 + lg) & ~7) * 8];
        #pragma unroll
        for (int mt = 0; mt < 4; ++mt) {
            bf16x8 a = *(const bf16x8*)&fc2wb[(mt * 16 + lr) * 256 + ks * 32 + lg * 8];
            acc[mt] = MFMA16(a, bfr, acc[mt]);
        }
    }
    const float sb = rsqrtf(1.f + EPSV);
    int tok = tok0 + w * 16 + lr;
    #pragma unroll
    for (int mt = 0; mt < 4; ++mt) {
        #pragma unroll
        for (int r = 0; r < 4; ++r) {
            int o = mt * 16 + lg * 4 + r;
            size_t off = ((size_t)b * 64 + o) * NN + tok;
            out[off] = acc[mt][r] * bn2g[o] * sb + bn2b[o] + x2[off];
        }
    }
}

extern "C" void kernel_launch(void* const* d_in, const int* in_sizes, int n_in,
                              void* d_out, int out_size, void* d_ws, size_t ws_size,
                              hipStream_t stream) {
    const float* x    = (const float*)d_in[0];
    const float* cnn  = (const float*)d_in[1];
    const float* n1g  = (const float*)d_in[2];
    const float* n1b  = (const float*)d_in[3];
    const float* n2g  = (const float*)d_in[4];
    const float* n2b  = (const float*)d_in[5];
    const float* n3g  = (const float*)d_in[6];
    const float* n3b  = (const float*)d_in[7];
    const float* qw   = (const float*)d_in[8];
    const float* qb   = (const float*)d_in[9];
    const float* kvw  = (const float*)d_in[10];
    const float* kvb  = (const float*)d_in[11];
    const float* lcw  = (const float*)d_in[12];
    const float* lcb  = (const float*)d_in[13];
    const float* fc1w = (const float*)d_in[14];
    const float* bn1g = (const float*)d_in[15];
    const float* bn1b = (const float*)d_in[16];
    const float* dw1w = (const float*)d_in[17];
    const float* dw1b = (const float*)d_in[18];
    const float* dw3w = (const float*)d_in[19];
    const float* dw3b = (const float*)d_in[20];
    const float* dw5w = (const float*)d_in[21];
    const float* dw5b = (const float*)d_in[22];
    const float* dw7w = (const float*)d_in[23];
    const float* dw7b = (const float*)d_in[24];
    const float* bnmg = (const float*)d_in[25];
    const float* bnmb = (const float*)d_in[26];
    const float* fftw = (const float*)d_in[27];
    const float* fc2w = (const float*)d_in[28];
    const float* bn2g = (const float*)d_in[29];
    const float* bn2b = (const float*)d_in[30];

    float* ws = (float*)d_ws;
    float* stats = ws;                     // 64
    float* part  = ws + 64;                // 1024
    float* part2 = ws + 1088;              // 2048
    float* base  = ws + 3200;
    const size_t M = 1048576;
    float* x2     = base;                              // [0, 1M)
    ushort* qr_bf = (ushort*)(base + M);               // [1M, 1.5M)
    ushort* kr_bf = (ushort*)(base + M + M / 2);       // [1.5M, 2M)
    ushort* vt_bf = (ushort*)(base + 2 * M);           // [2M, 2.5M)
    float* kvin   = base + 5 * M / 2;                  // [2.5M, 3.5M)
    ushort* Opart = (ushort*)(base + 7 * M / 2);       // [3.5M, 7.5M)
    float* ml     = base + 15 * M / 2;                 // [7.5M, 7.75M)
    ushort* h1 = (ushort*)(base + M);                  // overlay qr/kr/vt/kvin (dead post-attn)
    ushort* h2 = (ushort*)(base + 7 * M / 2);          // overlay Opart head (dead post-combine)
    ushort* fc1wb = (ushort*)(base + 8 * M);           // 16384 ushorts
    ushort* fc2wb = fc1wb + 16384;
    ushort* qwb   = fc2wb + 16384;                     // 4096
    ushort* kvwb  = qwb + 4096;                        // 8192
    float* outp = (float*)d_out;

    stats_wprep_kernel<<<dim3(108, 4), 256, 0, stream>>>(x, cnn, part, fc1w, fc2w, qw, kvw,
                                                         fc1wb, fc2wb, qwb, kvwb);
    stats_fin_kernel<<<8, 64, 0, stream>>>(part, stats);
    dw3k_kernel<<<4096, 256, 0, stream>>>(cnn, n3g, n3b, lcw, lcb, stats, kvin);
    qkv_mfma<<<dim3(128, 4), 256, 0, stream>>>(x, n1g, n1b, qwb, qb, kvin, kvwb, kvb,
                                               stats, qr_bf, kr_bf, vt_bf);
    attn_kernel<<<dim3(64, 4, NCH), 256, 0, stream>>>(qr_bf, kr_bf, vt_bf, Opart, ml);
    combine_kernel<<<1024, 256, 0, stream>>>(Opart, ml, x, x2, part2);
    stats2b_kernel<<<4, 256, 0, stream>>>(part2, stats, 2);
    fc1_mfma<<<dim3(128, 4), 256, 0, stream>>>(x2, fc1wb, n2g, n2b, bn1g, bn1b, stats, h1);
    mixer_kernel<<<dim3(512, 4), 256, 0, stream>>>(h1, dw1w, dw1b, dw3w, dw3b, dw5w, dw5b,
                                                   dw7w, dw7b, fftw, bnmg, bnmb, h2);
    fc2_mfma<<<dim3(64, 4), 256, 0, stream>>>(h2, fc2wb, bn2g, bn2b, x2, outp);
}

// Round 19
// 106.960 us; speedup vs baseline: 1.2299x; 1.0298x over previous
//
#include <hip/hip_runtime.h>
#include <hip/hip_bf16.h>
#include <math.h>

#define BB 4
#define CC 64
#define NN 4096
#define HD 64
#define HID 256
#define EPSV 1e-5f
#define CNT (CC*NN)
#define NCH 8            // KV split chunks

typedef float f32x4 __attribute__((ext_vector_type(4)));
typedef short bf16x8 __attribute__((ext_vector_type(8)));
typedef short bf16x4 __attribute__((ext_vector_type(4)));
#define MFMA16(a, b, c) __builtin_amdgcn_mfma_f32_16x16x32_bf16(a, b, c, 0, 0, 0)

__device__ __forceinline__ float gelu_exact(float x) {
    return 0.5f * x * (1.0f + erff(x * 0.70710678118654752f));
}
__device__ __forceinline__ ushort f2bf(float f) {
    unsigned u = __float_as_uint(f);
    unsigned r = (u + 0x7FFFu + ((u >> 16) & 1u)) >> 16;
    return (ushort)r;
}
__device__ __forceinline__ float bf2f(ushort u) {
    return __uint_as_float(((unsigned)u) << 16);
}
__device__ __forceinline__ unsigned cvtpk(float lo, float hi) {
    unsigned r;
    asm("v_cvt_pk_bf16_f32 %0, %1, %2" : "=v"(r) : "v"(lo), "v"(hi));
    return r;
}
__device__ __forceinline__ void unpack2(unsigned u, float& lo, float& hi) {
    lo = __uint_as_float(u << 16);
    hi = __uint_as_float(u & 0xffff0000u);
}

// ---------------- stats stage 1 (x, cnn) + fused weight prep ----------------
// grid dim3(108, 4): bx<64 -> stats partials for batch by; bx>=64 -> wprep slice
__global__ __launch_bounds__(256) void stats_wprep_kernel(const float* __restrict__ x,
                                                          const float* __restrict__ cnn,
                                                          float* __restrict__ part,
                                                          const float* __restrict__ fc1w,
                                                          const float* __restrict__ fc2w,
                                                          const float* __restrict__ qw,
                                                          const float* __restrict__ kvw,
                                                          ushort* __restrict__ fc1wb,
                                                          ushort* __restrict__ fc2wb,
                                                          ushort* __restrict__ qwb,
                                                          ushort* __restrict__ kvwb) {
    int b = blockIdx.y;
    int blk = blockIdx.x;
    if (blk >= 64) {
        int i = (b * 44 + (blk - 64)) * 256 + threadIdx.x;   // < 45056
        if (i < 16384) fc1wb[i] = f2bf(fc1w[i]);
        else if (i < 32768) fc2wb[i - 16384] = f2bf(fc2w[i - 16384]);
        else if (i < 36864) qwb[i - 32768] = f2bf(qw[i - 32768]);
        else if (i < 45056) kvwb[i - 36864] = f2bf(kvw[i - 36864]);
        return;
    }
    const float4* p0 = (const float4*)(x + (size_t)b * CNT);
    const float4* p1 = (const float4*)(cnn + (size_t)b * CNT);
    float s0 = 0.f, s20 = 0.f, s1 = 0.f, s21 = 0.f;
    #pragma unroll
    for (int k = 0; k < 4; ++k) {
        float4 v = p0[blk * 1024 + k * 256 + threadIdx.x];
        s0  += v.x + v.y + v.z + v.w;
        s20 += v.x * v.x + v.y * v.y + v.z * v.z + v.w * v.w;
        float4 u = p1[blk * 1024 + k * 256 + threadIdx.x];
        s1  += u.x + u.y + u.z + u.w;
        s21 += u.x * u.x + u.y * u.y + u.z * u.z + u.w * u.w;
    }
    #pragma unroll
    for (int off = 32; off > 0; off >>= 1) {
        s0  += __shfl_xor(s0, off);
        s20 += __shfl_xor(s20, off);
        s1  += __shfl_xor(s1, off);
        s21 += __shfl_xor(s21, off);
    }
    __shared__ float sh[4][4];
    int wid = threadIdx.x >> 6, lane = threadIdx.x & 63;
    if (lane == 0) { sh[wid][0] = s0; sh[wid][1] = s20; sh[wid][2] = s1; sh[wid][3] = s21; }
    __syncthreads();
    if (threadIdx.x == 0) {
        float a0 = sh[0][0] + sh[1][0] + sh[2][0] + sh[3][0];
        float a1 = sh[0][1] + sh[1][1] + sh[2][1] + sh[3][1];
        float a2 = sh[0][2] + sh[1][2] + sh[2][2] + sh[3][2];
        float a3 = sh[0][3] + sh[1][3] + sh[2][3] + sh[3][3];
        part[((0 * 4 + b) * 64 + blk) * 2]     = a0;
        part[((0 * 4 + b) * 64 + blk) * 2 + 1] = a1;
        part[((1 * 4 + b) * 64 + blk) * 2]     = a2;
        part[((1 * 4 + b) * 64 + blk) * 2 + 1] = a3;
    }
}

// ---------------- dw3k: kvin = dw3(gn(cnn)) + bias + gn(cnn); inline slot-1 stats ----------------
__global__ __launch_bounds__(256) void dw3k_kernel(const float* __restrict__ cnn,
                                                   const float* __restrict__ n3g,
                                                   const float* __restrict__ n3b,
                                                   const float* __restrict__ lcw,
                                                   const float* __restrict__ lcb,
                                                   const float* __restrict__ part,
                                                   float* __restrict__ kvin) {
    int i = blockIdx.x * 256 + threadIdx.x;   // 1,048,576
    int b = blockIdx.x >> 10;
    __shared__ float smr[2];
    if (threadIdx.x < 64) {
        float s  = part[((4 + b) * 64 + threadIdx.x) * 2];
        float s2 = part[((4 + b) * 64 + threadIdx.x) * 2 + 1];
        #pragma unroll
        for (int off = 32; off > 0; off >>= 1) {
            s  += __shfl_xor(s, off);
            s2 += __shfl_xor(s2, off);
        }
        if (threadIdx.x == 0) {
            float mu = s / (float)CNT;
            float var = s2 / (float)CNT - mu * mu;
            smr[0] = mu;
            smr[1] = rsqrtf(var + EPSV);
        }
    }
    __syncthreads();
    float mu = smr[0];
    float rs = smr[1];
    int x = i & 63;
    int y = (i >> 6) & 63;
    int c = (i >> 12) & 63;
    float sc = rs * n3g[c];
    float of = n3b[c] - mu * sc;
    const float* plane = cnn + ((size_t)(i >> 12) << 12);
    float acc = lcb[c];
    #pragma unroll
    for (int dy = 0; dy < 3; ++dy) {
        int yy = y + dy - 1;
        if (yy < 0 || yy >= 64) continue;
        #pragma unroll
        for (int dx = 0; dx < 3; ++dx) {
            int xx = x + dx - 1;
            if (xx < 0 || xx >= 64) continue;
            acc += lcw[c * 9 + dy * 3 + dx] * (plane[(yy << 6) + xx] * sc + of);
        }
    }
    kvin[i] = acc + plane[(y << 6) + x] * sc + of;
}

// ---------------- QKV MFMA fused dispatch: bx<64 -> Q path; bx>=64 -> KV path ----------------
// Q path: inline slot-0 stats; gn(x)->proj->bias+RoPE->bf16*SCL2. KV: kvin->proj.
__global__ __launch_bounds__(256) void qkv_mfma(const float* __restrict__ x,
                                                const float* __restrict__ n1g,
                                                const float* __restrict__ n1b,
                                                const ushort* __restrict__ qwb,
                                                const float* __restrict__ qb,
                                                const float* __restrict__ kvin,
                                                const ushort* __restrict__ kvwb,
                                                const float* __restrict__ kvb,
                                                const float* __restrict__ part,
                                                ushort* __restrict__ qr,
                                                ushort* __restrict__ kr,
                                                ushort* __restrict__ vt) {
    const float SCL2 = 0.125f * 1.44269504f;
    int b = blockIdx.y;
    int tid = threadIdx.x;
    int w = tid >> 6;
    int lr = tid & 15;
    int lg = (tid & 63) >> 4;
    __shared__ ushort Xt[64][64];
    __shared__ float qmr[2];
    int brow = w * 16 + lr;

    if (blockIdx.x < 64) {
        // ---------- Q path ----------
        int tok0 = blockIdx.x * 64;
        if (tid < 64) {
            float s  = part[((0 * 4 + b) * 64 + tid) * 2];
            float s2 = part[((0 * 4 + b) * 64 + tid) * 2 + 1];
            #pragma unroll
            for (int off = 32; off > 0; off >>= 1) {
                s  += __shfl_xor(s, off);
                s2 += __shfl_xor(s2, off);
            }
            if (tid == 0) {
                float mu = s / (float)CNT;
                float var = s2 / (float)CNT - mu * mu;
                qmr[0] = mu;
                qmr[1] = rsqrtf(var + EPSV);
            }
        }
        __syncthreads();
        float mu = qmr[0];
        float rs = qmr[1];
        for (int k = 0; k < 16; ++k) {
            int e = tid + k * 256;
            int c = e >> 6, t = e & 63;
            float v = (x[((size_t)(b * 64 + c)) * NN + tok0 + t] - mu) * rs * n1g[c] + n1b[c];
            Xt[t][((c >> 3) ^ (t & 7)) * 8 + (c & 7)] = f2bf(v);
        }
        __syncthreads();
        bf16x8 bf0 = *(const bf16x8*)&Xt[brow][((0 + lg) ^ (lr & 7)) * 8];
        bf16x8 bf1 = *(const bf16x8*)&Xt[brow][((4 + lg) ^ (lr & 7)) * 8];
        f32x4 acc[4];
        #pragma unroll
        for (int mt = 0; mt < 4; ++mt) acc[mt] = (f32x4){0.f, 0.f, 0.f, 0.f};
        #pragma unroll
        for (int mt = 0; mt < 4; ++mt) {
            bf16x8 a0 = *(const bf16x8*)&qwb[(mt * 16 + lr) * 64 + lg * 8];
            bf16x8 a1 = *(const bf16x8*)&qwb[(mt * 16 + lr) * 64 + 32 + lg * 8];
            acc[mt] = MFMA16(a0, bf0, acc[mt]);
            acc[mt] = MFMA16(a1, bf1, acc[mt]);
        }
        int tok = tok0 + w * 16 + lr;
        int hh = tok >> 6, ww2 = tok & 63;
        ushort* qrow = qr + ((size_t)b * NN + tok) * 64;
        #pragma unroll
        for (int mt = 0; mt < 4; ++mt) {
            #pragma unroll
            for (int pr = 0; pr < 2; ++pr) {
                int o = mt * 16 + lg * 4 + pr * 2;
                float a0 = acc[mt][pr * 2]     + qb[o];
                float a1 = acc[mt][pr * 2 + 1] + qb[o + 1];
                int j = (o & 31) >> 1;
                float freq = exp2f(-0.88584749f * (float)j);
                float pos = (o < 32) ? (float)hh : (float)ww2;
                float st, ct;
                __sincosf(pos * freq, &st, &ct);
                qrow[o]     = f2bf((a0 * ct - a1 * st) * SCL2);
                qrow[o + 1] = f2bf((a1 * ct + a0 * st) * SCL2);
            }
        }
    } else {
        // ---------- KV path ----------
        int tok0 = (blockIdx.x - 64) * 64;
        for (int k = 0; k < 16; ++k) {
            int e = tid + k * 256;
            int c = e >> 6, t = e & 63;
            Xt[t][((c >> 3) ^ (t & 7)) * 8 + (c & 7)] =
                f2bf(kvin[((size_t)(b * 64 + c)) * NN + tok0 + t]);
        }
        __syncthreads();
        bf16x8 bf0 = *(const bf16x8*)&Xt[brow][((0 + lg) ^ (lr & 7)) * 8];
        bf16x8 bf1 = *(const bf16x8*)&Xt[brow][((4 + lg) ^ (lr & 7)) * 8];
        f32x4 acc[8];
        #pragma unroll
        for (int mt = 0; mt < 8; ++mt) acc[mt] = (f32x4){0.f, 0.f, 0.f, 0.f};
        #pragma unroll
        for (int mt = 0; mt < 8; ++mt) {
            bf16x8 a0 = *(const bf16x8*)&kvwb[(mt * 16 + lr) * 64 + lg * 8];
            bf16x8 a1 = *(const bf16x8*)&kvwb[(mt * 16 + lr) * 64 + 32 + lg * 8];
            acc[mt] = MFMA16(a0, bf0, acc[mt]);
            acc[mt] = MFMA16(a1, bf1, acc[mt]);
        }
        int tl = w * 16 + lr;
        int tok = tok0 + tl;
        int hh = tok >> 6, ww2 = tok & 63;
        int permk = (lr >> 2) * 16 + w * 4 + (lr & 3);
        ushort* krow = kr + ((size_t)b * NN + tok) * 64;
        #pragma unroll
        for (int mt = 0; mt < 4; ++mt) {      // K half, with RoPE
            #pragma unroll
            for (int pr = 0; pr < 2; ++pr) {
                int o = mt * 16 + lg * 4 + pr * 2;
                float a0 = acc[mt][pr * 2]     + kvb[o];
                float a1 = acc[mt][pr * 2 + 1] + kvb[o + 1];
                int j = (o & 31) >> 1;
                float freq = exp2f(-0.88584749f * (float)j);
                float pos = (o < 32) ? (float)hh : (float)ww2;
                float st, ct;
                __sincosf(pos * freq, &st, &ct);
                krow[o]     = f2bf(a0 * ct - a1 * st);
                krow[o + 1] = f2bf(a1 * ct + a0 * st);
            }
        }
        #pragma unroll
        for (int mt = 4; mt < 8; ++mt) {      // V half, key-permuted transpose store
            #pragma unroll
            for (int r = 0; r < 4; ++r) {
                int o = mt * 16 + lg * 4 + r;
                float a0 = acc[mt][r] + kvb[o];
                vt[((size_t)b * 64 + (o - 64)) * NN + tok0 + permk] = f2bf(a0);
            }
        }
    }
}

// ---------------- MFMA flash attention v4.2: hoisted staging, max3, setprio ----------------
// grid dim3(64, B, NCH), 256 thr = 4 waves x 16 q-rows; KV tile 64; chunk = 512 keys
__global__ __launch_bounds__(256) void attn_kernel(const ushort* __restrict__ qr,
                                                   const ushort* __restrict__ kr,
                                                   const ushort* __restrict__ vt,
                                                   ushort* __restrict__ Opart,
                                                   float* __restrict__ ml) {
    int b = blockIdx.y;
    int q0 = blockIdx.x * 64;
    int chunk = blockIdx.z;
    int tid = threadIdx.x;
    int w = tid >> 6;
    int lane = tid & 63;
    int lr = lane & 15;
    int lg = lane >> 4;

    __shared__ ushort Kl[64 * 64];
    __shared__ ushort Vl[64 * 64];

    bf16x8 qf[2];
    {
        const ushort* qp = qr + ((size_t)b * NN + q0 + w * 16 + lr) * 64;
        qf[0] = *(const bf16x8*)(qp + lg * 8);
        qf[1] = *(const bf16x8*)(qp + 32 + lg * 8);
    }

    f32x4 oacc[4];
    #pragma unroll
    for (int t = 0; t < 4; ++t) oacc[t] = (f32x4){0.f, 0.f, 0.f, 0.f};
    float m_ = -INFINITY, l_ = 0.f;     // base-2 scalar state for q-row = q0+w*16+lr

    const int t0 = chunk * 8;
    const int srow0 = tid >> 3;          // 0..31
    const int srow1 = srow0 + 32;        // 32..63
    const int scib = tid & 7;
    const int kd0 = srow0 * 64 + (scib ^ (srow0 & 7)) * 8;
    const int kd1 = srow1 * 64 + (scib ^ (srow1 & 7)) * 8;
    const ushort* kp0 = kr + ((size_t)b * NN + t0 * 64 + srow0) * 64 + scib * 8;
    const ushort* kp1 = kr + ((size_t)b * NN + t0 * 64 + srow1) * 64 + scib * 8;
    const ushort* vp0 = vt + ((size_t)b * 64 + srow0) * NN + t0 * 64 + scib * 8;
    const ushort* vp1 = vt + ((size_t)b * 64 + srow1) * NN + t0 * 64 + scib * 8;
    const int rs7 = lr & 7;

    for (int t = 0; t < 8; ++t) {
        __syncthreads();
        *(bf16x8*)(Kl + kd0) = *(const bf16x8*)kp0;
        *(bf16x8*)(Kl + kd1) = *(const bf16x8*)kp1;
        *(bf16x8*)(Vl + kd0) = *(const bf16x8*)vp0;
        *(bf16x8*)(Vl + kd1) = *(const bf16x8*)vp1;
        kp0 += 4096; kp1 += 4096; vp0 += 64; vp1 += 64;
        __syncthreads();

        f32x4 sacc[4];
        __builtin_amdgcn_s_setprio(1);
        #pragma unroll
        for (int kt = 0; kt < 4; ++kt) {
            int row = kt * 16 + lr;
            bf16x8 k0f = *(const bf16x8*)(Kl + row * 64 + ((0 * 4 + lg) ^ rs7) * 8);
            bf16x8 k1f = *(const bf16x8*)(Kl + row * 64 + ((1 * 4 + lg) ^ rs7) * 8);
            f32x4 z = {0.f, 0.f, 0.f, 0.f};
            z = MFMA16(k0f, qf[0], z);
            sacc[kt] = MFMA16(k1f, qf[1], z);
        }
        __builtin_amdgcn_s_setprio(0);

        float m0 = fmaxf(fmaxf(sacc[0][0], sacc[0][1]), sacc[0][2]);
        float m1 = fmaxf(fmaxf(sacc[0][3], sacc[1][0]), sacc[1][1]);
        float m2 = fmaxf(fmaxf(sacc[1][2], sacc[1][3]), sacc[2][0]);
        float m3 = fmaxf(fmaxf(sacc[2][1], sacc[2][2]), sacc[2][3]);
        float m4 = fmaxf(fmaxf(sacc[3][0], sacc[3][1]), sacc[3][2]);
        float n0v = fmaxf(fmaxf(m0, m1), m2);
        float n1v = fmaxf(fmaxf(m3, m4), sacc[3][3]);
        float vmax = fmaxf(n0v, n1v);
        vmax = fmaxf(vmax, __shfl_xor(vmax, 16));
        vmax = fmaxf(vmax, __shfl_xor(vmax, 32));
        if (__any(vmax - m_ > 8.f)) {          // defer-max
            float mn = fmaxf(m_, vmax);
            float cr = exp2f(m_ - mn);
            l_ *= cr;
            m_ = mn;
            float crq[4];
            #pragma unroll
            for (int r = 0; r < 4; ++r) crq[r] = __shfl(cr, lg * 4 + r);
            #pragma unroll
            for (int ht = 0; ht < 4; ++ht)
                #pragma unroll
                for (int r = 0; r < 4; ++r) oacc[ht][r] *= crq[r];
        }

        unsigned u[8];
        float lsum = 0.f;
        #pragma unroll
        for (int kt = 0; kt < 4; ++kt) {
            float p0 = exp2f(sacc[kt][0] - m_);
            float p1 = exp2f(sacc[kt][1] - m_);
            float p2 = exp2f(sacc[kt][2] - m_);
            float p3 = exp2f(sacc[kt][3] - m_);
            lsum += (p0 + p1) + (p2 + p3);
            u[kt * 2]     = cvtpk(p0, p1);
            u[kt * 2 + 1] = cvtpk(p2, p3);
        }
        lsum += __shfl_xor(lsum, 16);
        lsum += __shfl_xor(lsum, 32);
        l_ += lsum;

        uint4 t0v = {u[0], u[1], u[2], u[3]};
        uint4 t1v = {u[4], u[5], u[6], u[7]};
        bf16x8 pa0 = __builtin_bit_cast(bf16x8, t0v);
        bf16x8 pa1 = __builtin_bit_cast(bf16x8, t1v);
        __builtin_amdgcn_s_setprio(1);
        #pragma unroll
        for (int ht = 0; ht < 4; ++ht) {
            int row = ht * 16 + lr;
            bf16x8 vf0 = *(const bf16x8*)(Vl + row * 64 + ((lg * 2) ^ rs7) * 8);
            bf16x8 vf1 = *(const bf16x8*)(Vl + row * 64 + ((lg * 2 + 1) ^ rs7) * 8);
            oacc[ht] = MFMA16(pa0, vf0, oacc[ht]);
            oacc[ht] = MFMA16(pa1, vf1, oacc[ht]);
        }
        __builtin_amdgcn_s_setprio(0);
    }

    int n0 = q0 + w * 16 + lg * 4;
    #pragma unroll
    for (int ht = 0; ht < 4; ++ht) {
        int hd = ht * 16 + lr;
        ushort4 o4;
        o4.x = f2bf(oacc[ht][0]);
        o4.y = f2bf(oacc[ht][1]);
        o4.z = f2bf(oacc[ht][2]);
        o4.w = f2bf(oacc[ht][3]);
        *(ushort4*)&Opart[(((size_t)chunk * BB + b) * 64 + hd) * NN + n0] = o4;
    }
    if (lg == 0) {
        int n = q0 + w * 16 + lr;
        ml[((size_t)b * NN + n) * 16 + chunk * 2]     = m_;
        ml[((size_t)b * NN + n) * 16 + chunk * 2 + 1] = l_;
    }
}

// ---------------- combine: x2 = sum_c O_c*w_c + x; fused stats partials ----------------
__global__ __launch_bounds__(256) void combine_kernel(const ushort* __restrict__ Opart,
                                                      const float* __restrict__ ml,
                                                      const float* __restrict__ x,
                                                      float* __restrict__ x2,
                                                      float* __restrict__ part2) {
    int i = blockIdx.x * 256 + threadIdx.x;   // 262144
    int n4 = i & 1023;
    int hd = (i >> 10) & 63;
    int b = i >> 16;
    int n0 = n4 << 2;
    float wgt[4][NCH];
    const float* mlp = ml + ((size_t)b * NN + n0) * 16;
    #pragma unroll
    for (int tk = 0; tk < 4; ++tk) {
        float m[NCH], l[NCH];
        const float4* p4 = (const float4*)(mlp + tk * 16);
        #pragma unroll
        for (int q = 0; q < 4; ++q) {
            float4 v = p4[q];
            m[q * 2] = v.x; l[q * 2] = v.y; m[q * 2 + 1] = v.z; l[q * 2 + 1] = v.w;
        }
        float M = m[0];
        #pragma unroll
        for (int c = 1; c < NCH; ++c) M = fmaxf(M, m[c]);
        float e[NCH], L = 0.f;
        #pragma unroll
        for (int c = 0; c < NCH; ++c) { e[c] = exp2f(m[c] - M); L += l[c] * e[c]; }
        float inv = 1.f / L;
        #pragma unroll
        for (int c = 0; c < NCH; ++c) wgt[tk][c] = e[c] * inv;
    }
    float4 acc = {0.f, 0.f, 0.f, 0.f};
    #pragma unroll
    for (int c = 0; c < NCH; ++c) {
        ushort4 o4 = *(const ushort4*)&Opart[(((size_t)c * BB + b) * 64 + hd) * NN + n0];
        acc.x += bf2f(o4.x) * wgt[0][c];
        acc.y += bf2f(o4.y) * wgt[1][c];
        acc.z += bf2f(o4.z) * wgt[2][c];
        acc.w += bf2f(o4.w) * wgt[3][c];
    }
    size_t off = ((size_t)b * 64 + hd) * NN + n0;
    float4 xv = *(const float4*)&x[off];
    acc.x += xv.x; acc.y += xv.y; acc.z += xv.z; acc.w += xv.w;
    *(float4*)&x2[off] = acc;

    float s = acc.x + acc.y + acc.z + acc.w;
    float s2 = acc.x * acc.x + acc.y * acc.y + acc.z * acc.z + acc.w * acc.w;
    #pragma unroll
    for (int off2 = 32; off2 > 0; off2 >>= 1) {
        s  += __shfl_xor(s, off2);
        s2 += __shfl_xor(s2, off2);
    }
    __shared__ float shs[4], shs2[4];
    int wid = threadIdx.x >> 6, lane = threadIdx.x & 63;
    if (lane == 0) { shs[wid] = s; shs2[wid] = s2; }
    __syncthreads();
    if (threadIdx.x == 0) {
        part2[blockIdx.x * 2]     = shs[0] + shs[1] + shs[2] + shs[3];
        part2[blockIdx.x * 2 + 1] = shs2[0] + shs2[1] + shs2[2] + shs2[3];
    }
}

// ---------------- fc1 MFMA: inline slot-2 stats; h1 = gelu(bn1(fc1w @ gn2(x2))) -> bf16 ----------------
__global__ __launch_bounds__(256) void fc1_mfma(const float* __restrict__ x2,
                                                const ushort* __restrict__ fc1wb,
                                                const float* __restrict__ n2g,
                                                const float* __restrict__ n2b,
                                                const float* __restrict__ bn1g,
                                                const float* __restrict__ bn1b,
                                                const float* __restrict__ part2,
                                                ushort* __restrict__ h1) {
    int b = blockIdx.y;
    int tok0 = (blockIdx.x >> 1) * 64;
    int half = blockIdx.x & 1;
    int tid = threadIdx.x;
    int w = tid >> 6;
    int lr = tid & 15;
    int lg = (tid & 63) >> 4;
    __shared__ ushort Xt[64][64];     // [tok][chan], chunk-swizzled
    __shared__ float red[8];
    __shared__ float fmr[2];
    {
        float s  = part2[(b * 256 + tid) * 2];
        float s2 = part2[(b * 256 + tid) * 2 + 1];
        #pragma unroll
        for (int off = 32; off > 0; off >>= 1) {
            s  += __shfl_xor(s, off);
            s2 += __shfl_xor(s2, off);
        }
        if ((tid & 63) == 0) { red[(tid >> 6) * 2] = s; red[(tid >> 6) * 2 + 1] = s2; }
        __syncthreads();
        if (tid == 0) {
            float S = red[0] + red[2] + red[4] + red[6];
            float S2 = red[1] + red[3] + red[5] + red[7];
            float mu = S / (float)CNT;
            float var = S2 / (float)CNT - mu * mu;
            fmr[0] = mu;
            fmr[1] = rsqrtf(var + EPSV);
        }
        __syncthreads();
    }
    float mu = fmr[0];
    float rs = fmr[1];
    for (int k = 0; k < 16; ++k) {
        int e = tid + k * 256;
        int c = e >> 6, t = e & 63;
        float v = (x2[((size_t)(b * 64 + c)) * NN + tok0 + t] - mu) * rs * n2g[c] + n2b[c];
        Xt[t][((c >> 3) ^ (t & 7)) * 8 + (c & 7)] = f2bf(v);
    }
    __syncthreads();
    int brow = w * 16 + lr;
    bf16x8 bf0 = *(const bf16x8*)&Xt[brow][((0 + lg) ^ (lr & 7)) * 8];
    bf16x8 bf1 = *(const bf16x8*)&Xt[brow][((4 + lg) ^ (lr & 7)) * 8];
    f32x4 acc[8];
    #pragma unroll
    for (int mt = 0; mt < 8; ++mt) acc[mt] = (f32x4){0.f, 0.f, 0.f, 0.f};
    const ushort* wb = fc1wb + (size_t)(half * 128) * 64;
    #pragma unroll
    for (int mt = 0; mt < 8; ++mt) {
        bf16x8 a0 = *(const bf16x8*)&wb[(mt * 16 + lr) * 64 + lg * 8];
        bf16x8 a1 = *(const bf16x8*)&wb[(mt * 16 + lr) * 64 + 32 + lg * 8];
        acc[mt] = MFMA16(a0, bf0, acc[mt]);
        acc[mt] = MFMA16(a1, bf1, acc[mt]);
    }
    const float sb = rsqrtf(1.f + EPSV);
    int tok = tok0 + w * 16 + lr;
    #pragma unroll
    for (int mt = 0; mt < 8; ++mt) {
        #pragma unroll
        for (int r = 0; r < 4; ++r) {
            int o = half * 128 + mt * 16 + lg * 4 + r;
            float vv = acc[mt][r] * bn1g[o] * sb + bn1b[o];
            h1[((size_t)b * HID + o) * NN + tok] = f2bf(gelu_exact(vv));
        }
    }
}

// ---------------- mixer v2: register sliding-window; 32-row half planes ----------------
__global__ __launch_bounds__(256) void mixer_kernel(const ushort* __restrict__ h1,
                                                    const float* __restrict__ dw1w, const float* __restrict__ dw1b,
                                                    const float* __restrict__ dw3w, const float* __restrict__ dw3b,
                                                    const float* __restrict__ dw5w, const float* __restrict__ dw5b,
                                                    const float* __restrict__ dw7w, const float* __restrict__ dw7b,
                                                    const float* __restrict__ fftw,
                                                    const float* __restrict__ bnmg, const float* __restrict__ bnmb,
                                                    ushort* __restrict__ h2) {
    int c = blockIdx.x >> 1;
    int r0 = (blockIdx.x & 1) * 32;
    int b = blockIdx.y;
    int tid = threadIdx.x;
    __shared__ ushort ls[38][80];      // 6080 B
    uint* lz = (uint*)&ls[0][0];
    #pragma unroll
    for (int k = 0; k < 6; ++k) {
        int i = tid + k * 256;
        if (i < 1520) lz[i] = 0;
    }
    __syncthreads();
    const ushort* plane = h1 + (((size_t)b * HID + c) << 12);
    for (int e = tid; e < 304; e += 256) {
        int i = e >> 3, xc = e & 7;
        int gr = r0 + i - 3;
        if (gr >= 0 && gr < 64) {
            bf16x8 v = *(const bf16x8*)&plane[(gr << 6) + xc * 8];
            bf16x4 lo = {v[0], v[1], v[2], v[3]};
            bf16x4 hi = {v[4], v[5], v[6], v[7]};
            *(bf16x4*)&ls[i][xc * 8 + 4] = lo;
            *(bf16x4*)&ls[i][xc * 8 + 8] = hi;
        }
    }
    __syncthreads();

    int yy = tid >> 3;
    int x0 = (tid & 7) * 8;
    const float sb = rsqrtf(1.f + EPSV);
    float fw = fftw[c];
    float bg = bnmg[c] * sb, bb2 = bnmb[c];
    float acc[8], ctr[8];
    #pragma unroll
    for (int j = 0; j < 8; ++j) acc[j] = 0.f;

    if (c < 64) {
        float w0 = dw1w[c], b0 = dw1b[c];
        uint4 ua = *(const uint4*)&ls[yy + 3][x0];
        uint4 ub = *(const uint4*)&ls[yy + 3][x0 + 8];
        float wv[16];
        unpack2(ua.x, wv[0], wv[1]); unpack2(ua.y, wv[2], wv[3]);
        unpack2(ua.z, wv[4], wv[5]); unpack2(ua.w, wv[6], wv[7]);
        unpack2(ub.x, wv[8], wv[9]); unpack2(ub.y, wv[10], wv[11]);
        unpack2(ub.z, wv[12], wv[13]); unpack2(ub.w, wv[14], wv[15]);
        #pragma unroll
        for (int j = 0; j < 8; ++j) { ctr[j] = wv[j + 4]; acc[j] = w0 * ctr[j] + b0; }
    } else if (c < 128) {
        int lc = c - 64;
        float b0 = dw3b[lc];
        #pragma unroll
        for (int j = 0; j < 8; ++j) acc[j] = b0;
        #pragma unroll
        for (int dy = 0; dy < 3; ++dy) {
            int i = yy + dy + 2;
            uint4 ua = *(const uint4*)&ls[i][x0];
            uint4 ub = *(const uint4*)&ls[i][x0 + 8];
            float wv[16];
            unpack2(ua.x, wv[0], wv[1]); unpack2(ua.y, wv[2], wv[3]);
            unpack2(ua.z, wv[4], wv[5]); unpack2(ua.w, wv[6], wv[7]);
            unpack2(ub.x, wv[8], wv[9]); unpack2(ub.y, wv[10], wv[11]);
            unpack2(ub.z, wv[12], wv[13]); unpack2(ub.w, wv[14], wv[15]);
            if (dy == 1) {
                #pragma unroll
                for (int j = 0; j < 8; ++j) ctr[j] = wv[j + 4];
            }
            #pragma unroll
            for (int dx = 0; dx < 3; ++dx) {
                float wt = dw3w[lc * 9 + dy * 3 + dx];
                #pragma unroll
                for (int j = 0; j < 8; ++j) acc[j] += wt * wv[j + dx + 3];
            }
        }
    } else if (c < 192) {
        int lc = c - 128;
        float b0 = dw5b[lc];
        #pragma unroll
        for (int j = 0; j < 8; ++j) acc[j] = b0;
        #pragma unroll
        for (int dy = 0; dy < 5; ++dy) {
            int i = yy + dy + 1;
            uint4 ua = *(const uint4*)&ls[i][x0];
            uint4 ub = *(const uint4*)&ls[i][x0 + 8];
            float wv[16];
            unpack2(ua.x, wv[0], wv[1]); unpack2(ua.y, wv[2], wv[3]);
            unpack2(ua.z, wv[4], wv[5]); unpack2(ua.w, wv[6], wv[7]);
            unpack2(ub.x, wv[8], wv[9]); unpack2(ub.y, wv[10], wv[11]);
            unpack2(ub.z, wv[12], wv[13]); unpack2(ub.w, wv[14], wv[15]);
            if (dy == 2) {
                #pragma unroll
                for (int j = 0; j < 8; ++j) ctr[j] = wv[j + 4];
            }
            #pragma unroll
            for (int dx = 0; dx < 5; ++dx) {
                float wt = dw5w[lc * 25 + dy * 5 + dx];
                #pragma unroll
                for (int j = 0; j < 8; ++j) acc[j] += wt * wv[j + dx + 2];
            }
        }
    } else {
        int lc = c - 192;
        float b0 = dw7b[lc];
        #pragma unroll
        for (int j = 0; j < 8; ++j) acc[j] = b0;
        #pragma unroll
        for (int dy = 0; dy < 7; ++dy) {
            int i = yy + dy;
            uint4 ua = *(const uint4*)&ls[i][x0];
            uint4 ub = *(const uint4*)&ls[i][x0 + 8];
            float wv[16];
            unpack2(ua.x, wv[0], wv[1]); unpack2(ua.y, wv[2], wv[3]);
            unpack2(ua.z, wv[4], wv[5]); unpack2(ua.w, wv[6], wv[7]);
            unpack2(ub.x, wv[8], wv[9]); unpack2(ub.y, wv[10], wv[11]);
            unpack2(ub.z, wv[12], wv[13]); unpack2(ub.w, wv[14], wv[15]);
            if (dy == 3) {
                #pragma unroll
                for (int j = 0; j < 8; ++j) ctr[j] = wv[j + 4];
            }
            #pragma unroll
            for (int dx = 0; dx < 7; ++dx) {
                float wt = dw7w[lc * 49 + dy * 7 + dx];
                #pragma unroll
                for (int j = 0; j < 8; ++j) acc[j] += wt * wv[j + dx + 1];
            }
        }
    }

    bf16x8 o;
    #pragma unroll
    for (int j = 0; j < 8; ++j) {
        float val = fw * acc[j] + ctr[j];
        o[j] = (short)f2bf(gelu_exact(val) * bg + bb2);
    }
    ushort* outp = h2 + (((size_t)b * HID + c) << 12);
    *(bf16x8*)&outp[((r0 + yy) << 6) + x0] = o;
}

// ---------------- fc2 MFMA: out = bn2(fc2w @ h2) + x2 ----------------
__global__ __launch_bounds__(256) void fc2_mfma(const ushort* __restrict__ h2,
                                                const ushort* __restrict__ fc2wb,
                                                const float* __restrict__ bn2g,
                                                const float* __restrict__ bn2b,
                                                const float* __restrict__ x2,
                                                float* __restrict__ out) {
    int b = blockIdx.y;
    int tok0 = blockIdx.x * 64;
    int tid = threadIdx.x;
    int w = tid >> 6;
    int lr = tid & 15;
    int lg = (tid & 63) >> 4;
    __shared__ ushort Xt[64][256];    // [tok][chan], chunk-swizzled (32 KB)
    for (int k = 0; k < 8; ++k) {
        int e = tid + k * 256;        // 2048 chunks of 8 toks
        int c = e >> 3, t8 = (e & 7) * 8;
        bf16x8 v = *(const bf16x8*)&h2[((size_t)(b * 256 + c)) * NN + tok0 + t8];
        #pragma unroll
        for (int j = 0; j < 8; ++j) {
            int t = t8 + j;
            Xt[t][((c >> 3) ^ (t & 7)) * 8 + (c & 7)] = (ushort)v[j];
        }
    }
    __syncthreads();
    int brow = w * 16 + lr;
    f32x4 acc[4];
    #pragma unroll
    for (int mt = 0; mt < 4; ++mt) acc[mt] = (f32x4){0.f, 0.f, 0.f, 0.f};
    #pragma unroll
    for (int ks = 0; ks < 8; ++ks) {
        bf16x8 bfr = *(const bf16x8*)&Xt[brow][(((ks * 4 + lg) & 7) ^ (lr & 7)) * 8 + ((ks * 4 + lg) & ~7) * 8];
        #pragma unroll
        for (int mt = 0; mt < 4; ++mt) {
            bf16x8 a = *(const bf16x8*)&fc2wb[(mt * 16 + lr) * 256 + ks * 32 + lg * 8];
            acc[mt] = MFMA16(a, bfr, acc[mt]);
        }
    }
    const float sb = rsqrtf(1.f + EPSV);
    int tok = tok0 + w * 16 + lr;
    #pragma unroll
    for (int mt = 0; mt < 4; ++mt) {
        #pragma unroll
        for (int r = 0; r < 4; ++r) {
            int o = mt * 16 + lg * 4 + r;
            size_t off = ((size_t)b * 64 + o) * NN + tok;
            out[off] = acc[mt][r] * bn2g[o] * sb + bn2b[o] + x2[off];
        }
    }
}

extern "C" void kernel_launch(void* const* d_in, const int* in_sizes, int n_in,
                              void* d_out, int out_size, void* d_ws, size_t ws_size,
                              hipStream_t stream) {
    const float* x    = (const float*)d_in[0];
    const float* cnn  = (const float*)d_in[1];
    const float* n1g  = (const float*)d_in[2];
    const float* n1b  = (const float*)d_in[3];
    const float* n2g  = (const float*)d_in[4];
    const float* n2b  = (const float*)d_in[5];
    const float* n3g  = (const float*)d_in[6];
    const float* n3b  = (const float*)d_in[7];
    const float* qw   = (const float*)d_in[8];
    const float* qb   = (const float*)d_in[9];
    const float* kvw  = (const float*)d_in[10];
    const float* kvb  = (const float*)d_in[11];
    const float* lcw  = (const float*)d_in[12];
    const float* lcb  = (const float*)d_in[13];
    const float* fc1w = (const float*)d_in[14];
    const float* bn1g = (const float*)d_in[15];
    const float* bn1b = (const float*)d_in[16];
    const float* dw1w = (const float*)d_in[17];
    const float* dw1b = (const float*)d_in[18];
    const float* dw3w = (const float*)d_in[19];
    const float* dw3b = (const float*)d_in[20];
    const float* dw5w = (const float*)d_in[21];
    const float* dw5b = (const float*)d_in[22];
    const float* dw7w = (const float*)d_in[23];
    const float* dw7b = (const float*)d_in[24];
    const float* bnmg = (const float*)d_in[25];
    const float* bnmb = (const float*)d_in[26];
    const float* fftw = (const float*)d_in[27];
    const float* fc2w = (const float*)d_in[28];
    const float* bn2g = (const float*)d_in[29];
    const float* bn2b = (const float*)d_in[30];

    float* ws = (float*)d_ws;
    float* part  = ws;                     // 1024
    float* part2 = ws + 1024;              // 2048
    float* base  = ws + 3200;
    const size_t M = 1048576;
    float* x2     = base;                              // [0, 1M)
    ushort* qr_bf = (ushort*)(base + M);               // [1M, 1.5M)
    ushort* kr_bf = (ushort*)(base + M + M / 2);       // [1.5M, 2M)
    ushort* vt_bf = (ushort*)(base + 2 * M);           // [2M, 2.5M)
    float* kvin   = base + 5 * M / 2;                  // [2.5M, 3.5M)
    ushort* Opart = (ushort*)(base + 7 * M / 2);       // [3.5M, 7.5M)
    float* ml     = base + 15 * M / 2;                 // [7.5M, 7.75M)
    ushort* h1 = (ushort*)(base + M);                  // overlay qr/kr/vt/kvin (dead post-attn)
    ushort* h2 = (ushort*)(base + 7 * M / 2);          // overlay Opart head (dead post-combine)
    ushort* fc1wb = (ushort*)(base + 8 * M);           // 16384 ushorts
    ushort* fc2wb = fc1wb + 16384;
    ushort* qwb   = fc2wb + 16384;                     // 4096
    ushort* kvwb  = qwb + 4096;                        // 8192
    float* outp = (float*)d_out;

    stats_wprep_kernel<<<dim3(108, 4), 256, 0, stream>>>(x, cnn, part, fc1w, fc2w, qw, kvw,
                                                         fc1wb, fc2wb, qwb, kvwb);
    dw3k_kernel<<<4096, 256, 0, stream>>>(cnn, n3g, n3b, lcw, lcb, part, kvin);
    qkv_mfma<<<dim3(128, 4), 256, 0, stream>>>(x, n1g, n1b, qwb, qb, kvin, kvwb, kvb,
                                               part, qr_bf, kr_bf, vt_bf);
    attn_kernel<<<dim3(64, 4, NCH), 256, 0, stream>>>(qr_bf, kr_bf, vt_bf, Opart, ml);
    combine_kernel<<<1024, 256, 0, stream>>>(Opart, ml, x, x2, part2);
    fc1_mfma<<<dim3(128, 4), 256, 0, stream>>>(x2, fc1wb, n2g, n2b, bn1g, bn1b, part2, h1);
    mixer_kernel<<<dim3(512, 4), 256, 0, stream>>>(h1, dw1w, dw1b, dw3w, dw3b, dw5w, dw5b,
                                                   dw7w, dw7b, fftw, bnmg, bnmb, h2);
    fc2_mfma<<<dim3(64, 4), 256, 0, stream>>>(h2, fc2wb, bn2g, bn2b, x2, outp);
}